// Round 1
// baseline (4394.427 us; speedup 1.0000x reference)
//
#include <hip/hip_runtime.h>
#include <math.h>

#define BB 8
#define EE 2000
#define FF 6000
#define QQ 20
#define DD 256
#define NENT 400000
#define NWORD 60000
#define NNZ_ 96000
#define VNEG  (-1e11f)
#define VSMALL 1e-10f

// ---------------------------------------------------------------------------
// Tiled fp32 GEMM: out[m,n] = act( sum_k A(m,k)*W[n,wk(k)] + bias )
//   GATHER:  A row = table[idx[m]] (table ld = K)
//   CONCAT2: K=512, k<256 from A1 (ld 256), k>=256 from A2*3 (ld 256),
//            W columns k>=256 map to W[n, 512 + (k-256)] (ldw=768),
//            bias indexed per (row-batch, n): bias[(m/EE)*256 + n]
// 64x64 tile, 256 threads, 4x4 per thread, K-chunks of 16, LDS transposed.
// ---------------------------------------------------------------------------
template<int GATHER, int RELU, int CONCAT2>
__global__ __launch_bounds__(256) void gemm_k(
    const float* __restrict__ A1, const int* __restrict__ idx,
    const float* __restrict__ A2,
    const float* __restrict__ W, int ldw,
    const float* __restrict__ bias,
    float* __restrict__ out, int M, int N, int K)
{
    __shared__ float As[16][68];
    __shared__ float Bs[16][68];
    const int tid = threadIdx.x;
    const int row0 = blockIdx.y * 64, col0 = blockIdx.x * 64;
    const int tx = tid & 15, ty = tid >> 4;
    const int lrow = tid >> 2, lk4 = (tid & 3) << 2;
    float acc[4][4] = {{0.f}};
    for (int k0 = 0; k0 < K; k0 += 16) {
        // stage A (64 rows x 16 k), transposed into As[k][m]
        {
            int gr = row0 + lrow;
            float4 av = make_float4(0.f, 0.f, 0.f, 0.f);
            if (gr < M) {
                const float* ap;
                if (CONCAT2) {
                    if (k0 < 256) ap = A1 + (size_t)gr * 256 + k0 + lk4;
                    else          ap = A2 + (size_t)gr * 256 + (k0 - 256) + lk4;
                } else if (GATHER) {
                    ap = A1 + (size_t)idx[gr] * K + k0 + lk4;
                } else {
                    ap = A1 + (size_t)gr * K + k0 + lk4;
                }
                av = *(const float4*)ap;
                if (CONCAT2 && k0 >= 256) { av.x *= 3.f; av.y *= 3.f; av.z *= 3.f; av.w *= 3.f; }
            }
            As[lk4 + 0][lrow] = av.x; As[lk4 + 1][lrow] = av.y;
            As[lk4 + 2][lrow] = av.z; As[lk4 + 3][lrow] = av.w;
        }
        // stage W (64 cols x 16 k), transposed into Bs[k][n]
        {
            int wk = (CONCAT2 && k0 >= 256) ? (k0 + 256 + lk4) : (k0 + lk4);
            float4 bv = *(const float4*)(W + (size_t)(col0 + lrow) * ldw + wk);
            Bs[lk4 + 0][lrow] = bv.x; Bs[lk4 + 1][lrow] = bv.y;
            Bs[lk4 + 2][lrow] = bv.z; Bs[lk4 + 3][lrow] = bv.w;
        }
        __syncthreads();
        #pragma unroll
        for (int kk = 0; kk < 16; ++kk) {
            float4 a = *(const float4*)&As[kk][ty << 2];
            float4 b = *(const float4*)&Bs[kk][tx << 2];
            acc[0][0] += a.x * b.x; acc[0][1] += a.x * b.y; acc[0][2] += a.x * b.z; acc[0][3] += a.x * b.w;
            acc[1][0] += a.y * b.x; acc[1][1] += a.y * b.y; acc[1][2] += a.y * b.z; acc[1][3] += a.y * b.w;
            acc[2][0] += a.z * b.x; acc[2][1] += a.z * b.y; acc[2][2] += a.z * b.z; acc[2][3] += a.z * b.w;
            acc[3][0] += a.w * b.x; acc[3][1] += a.w * b.y; acc[3][2] += a.w * b.z; acc[3][3] += a.w * b.w;
        }
        __syncthreads();
    }
    #pragma unroll
    for (int i = 0; i < 4; ++i) {
        int r = row0 + (ty << 2) + i;
        if (r >= M) break;
        float* orow = out + (size_t)r * N + col0 + (tx << 2);
        const float* bp = CONCAT2 ? (bias + (size_t)(r / EE) * 256 + col0 + (tx << 2))
                                  : (bias + col0 + (tx << 2));
        #pragma unroll
        for (int j = 0; j < 4; ++j) {
            float v = acc[i][j] + bp[j];
            if (RELU) v = fmaxf(v, 0.f);
            orow[j] = v;
        }
    }
}

// ---------------------------------------------------------------------------
// LSTM: 1 block per batch, 1024 threads; Xg = x@Wih.T + bih precomputed.
// ---------------------------------------------------------------------------
__global__ __launch_bounds__(1024) void lstm_k(
    const float* __restrict__ Xg, const float* __restrict__ Whh,
    const float* __restrict__ bhh, float* __restrict__ qh, float* __restrict__ qne)
{
    __shared__ float h[DD], c[DD], g[4 * DD];
    const int b = blockIdx.x, t = threadIdx.x;
    if (t < DD) { h[t] = 0.f; c[t] = 0.f; }
    __syncthreads();
    const float bb_ = bhh[t];
    const float* wr = Whh + (size_t)t * DD;
    for (int step = 0; step < QQ; ++step) {
        float acc = Xg[((size_t)b * QQ + step) * 1024 + t] + bb_;
        #pragma unroll 8
        for (int k = 0; k < DD; ++k) acc += h[k] * wr[k];
        g[t] = acc;
        __syncthreads();
        if (t < DD) {
            float gi = g[t], gf = g[DD + t], gg = g[2 * DD + t], go = g[3 * DD + t];
            float si = 1.f / (1.f + expf(-gi));
            float sf = 1.f / (1.f + expf(-gf));
            float so = 1.f / (1.f + expf(-go));
            float cc = sf * c[t] + si * tanhf(gg);
            c[t] = cc;
            float hh = so * tanhf(cc);
            h[t] = hh;
            qh[((size_t)b * QQ + step) * DD + t] = hh;
        }
        __syncthreads();
    }
    if (t < DD) qne[(size_t)b * DD + t] = h[t];
}

// ---------------------------------------------------------------------------
// Fused sim -> softmax(over q) -> Wt[b,f] = sum_q softmax*pre (att eliminated)
// ---------------------------------------------------------------------------
__global__ __launch_bounds__(256) void simwt_k(
    const float* __restrict__ qhid, const int* __restrict__ qtext,
    const float* __restrict__ lfe, float* __restrict__ Wt)
{
    __shared__ float qs[QQ * DD];
    __shared__ float qmn[QQ];
    const int b = blockIdx.y;
    const int f = blockIdx.x * 256 + threadIdx.x;
    for (int i = threadIdx.x; i < QQ * DD; i += 256) qs[i] = qhid[(size_t)b * QQ * DD + i];
    if (threadIdx.x < QQ)
        qmn[threadIdx.x] = (qtext[b * QQ + threadIdx.x] != NWORD) ? 0.f : VNEG;
    __syncthreads();
    if (f >= FF) return;
    float acc[QQ];
    #pragma unroll
    for (int q = 0; q < QQ; ++q) acc[q] = 0.f;
    const float* lr = lfe + ((size_t)b * FF + f) * DD;
    for (int d = 0; d < DD; d += 4) {
        float4 x = *(const float4*)(lr + d);
        #pragma unroll
        for (int q = 0; q < QQ; ++q) {
            float4 y = *(const float4*)&qs[q * DD + d];
            acc[q] += x.x * y.x + x.y * y.y + x.z * y.z + x.w * y.w;
        }
    }
    const float inv = 0.0625f;  // 1/sqrt(256)
    float pre[QQ], m = -INFINITY;
    #pragma unroll
    for (int q = 0; q < QQ; ++q) { pre[q] = acc[q] * inv + qmn[q]; m = fmaxf(m, pre[q]); }
    float s = 0.f;
    #pragma unroll
    for (int q = 0; q < QQ; ++q) s += expf(pre[q] - m);
    float wt = 0.f;
    #pragma unroll
    for (int q = 0; q < QQ; ++q) wt += (expf(pre[q] - m) / s) * (acc[q] * inv);
    Wt[(size_t)b * FF + f] = wt;
}

__global__ void rowmax_k(const float* __restrict__ Wt, float* __restrict__ WtMax)
{
    __shared__ float red[256];
    int b = blockIdx.x;
    float m = -INFINITY;
    for (int f = threadIdx.x; f < FF; f += 256) m = fmaxf(m, Wt[b * FF + f]);
    red[threadIdx.x] = m; __syncthreads();
    for (int s = 128; s > 0; s >>= 1) {
        if (threadIdx.x < s) red[threadIdx.x] = fmaxf(red[threadIdx.x], red[threadIdx.x + s]);
        __syncthreads();
    }
    if (threadIdx.x == 0) WtMax[b] = red[0];
}

__global__ void wtil_k(const float* __restrict__ Wt, const float* __restrict__ WtMax,
                       float* __restrict__ Wtil)
{
    int i = blockIdx.x * 256 + threadIdx.x;
    if (i >= BB * FF) return;
    Wtil[i] = expf(Wt[i] - WtMax[i / FF]);
}

// dst[b*nr + r] += val * src[b*nc + c]; SWAP chooses which idx row is r.
template<int SWAP>
__global__ void scatter_scalar_k(const int* __restrict__ idx, const float* __restrict__ val,
                                 const float* __restrict__ src, float* __restrict__ dst,
                                 int nr, int nc)
{
    int k = blockIdx.x * 256 + threadIdx.x;
    if (k >= NNZ_) return;
    int b = idx[k];
    int r = SWAP ? idx[2 * NNZ_ + k] : idx[NNZ_ + k];
    int c = SWAP ? idx[NNZ_ + k]     : idx[2 * NNZ_ + k];
    atomicAdd(&dst[(size_t)b * nr + r], val[k] * src[(size_t)b * nc + c]);
}

// dst row (b*nrd + r) += val * src row (b*ncs + c); one wave per nnz, D=256.
__global__ __launch_bounds__(256) void scatter_rows_k(
    const int* __restrict__ idx, const float* __restrict__ val,
    const float* __restrict__ src, float* __restrict__ dst, int nrd, int ncs)
{
    int gid = blockIdx.x * 256 + threadIdx.x;
    int k = gid >> 6, lane = gid & 63;
    if (k >= NNZ_) return;
    int b = idx[k], r = idx[NNZ_ + k], c = idx[2 * NNZ_ + k];
    const float* s = src + ((size_t)b * ncs + c) * DD + (lane << 2);
    float* p = dst + ((size_t)b * nrd + r) * DD + (lane << 2);
    float v = val[k];
    float4 x = *(const float4*)s;
    atomicAdd(p + 0, v * x.x); atomicAdd(p + 1, v * x.y);
    atomicAdd(p + 2, v * x.z); atomicAdd(p + 3, v * x.w);
}

__global__ void prdiv_k(const float* __restrict__ pr, const float* __restrict__ sm,
                        float* __restrict__ out)
{
    int i = blockIdx.x * 256 + threadIdx.x;
    if (i >= BB * EE) return;
    out[i] = pr[i] / fmaxf(sm[i], VSMALL);
}

__global__ void e2fnorm_k(const float* __restrict__ Wtil, const float* __restrict__ nacc,
                          float* __restrict__ out)
{
    int i = blockIdx.x * 256 + threadIdx.x;
    if (i >= BB * FF) return;
    out[i] = Wtil[i] * nacc[i];
}

__global__ void scale_relu_k(float* __restrict__ x, const float* __restrict__ nrm)
{
    int gid = blockIdx.x * 256 + threadIdx.x;
    int row = gid >> 6, d = (gid & 63) << 2;
    if (row >= BB * FF) return;
    float s = nrm[row];
    float4* p = (float4*)(x + (size_t)row * DD + d);
    float4 v = *p;
    v.x = fmaxf(v.x, 0.f) * s; v.y = fmaxf(v.y, 0.f) * s;
    v.z = fmaxf(v.z, 0.f) * s; v.w = fmaxf(v.w, 0.f) * s;
    *p = v;
}

__global__ void relu_k(float* __restrict__ x, int n4)
{
    int i = blockIdx.x * 256 + threadIdx.x;
    if (i >= n4) return;
    float4* p = (float4*)x + i;
    float4 v = *p;
    v.x = fmaxf(v.x, 0.f); v.y = fmaxf(v.y, 0.f);
    v.z = fmaxf(v.z, 0.f); v.w = fmaxf(v.w, 0.f);
    *p = v;
}

__global__ void prupd_k(float* __restrict__ pr, const float* __restrict__ pracc)
{
    int i = blockIdx.x * 256 + threadIdx.x;
    if (i >= BB * EE) return;
    pr[i] = 0.8f * pracc[i] + 0.2f * pr[i];
}

// out[b,j] = bias[j] + sum_k x[b,k] * W[j*ldw + woff + k]
__global__ __launch_bounds__(256) void matvec_k(
    const float* __restrict__ x, const float* __restrict__ W, int ldw, int woff,
    const float* __restrict__ bias, float* __restrict__ out)
{
    __shared__ float xs[DD];
    int b = blockIdx.x, j = threadIdx.x;
    xs[j] = x[b * DD + j];
    __syncthreads();
    float acc = bias[j];
    const float* wr = W + (size_t)j * ldw + woff;
    #pragma unroll 4
    for (int k = 0; k < DD; ++k) acc += xs[k] * wr[k];
    out[b * DD + j] = acc;
}

// vlee[b,k] = sum_e pr[b,e]*lee[b,e,k]; vf2e likewise; sumpr[b] = sum_e pr.
__global__ __launch_bounds__(256) void vreduce_k(
    const float* __restrict__ pr, const float* __restrict__ lee,
    const float* __restrict__ f2e, float* __restrict__ vlee,
    float* __restrict__ vf2e, float* __restrict__ sumpr)
{
    int b = blockIdx.x, k = threadIdx.x;
    float a1 = 0.f, a2 = 0.f;
    for (int e = 0; e < EE; ++e) {
        float p = pr[b * EE + e];
        a1 += p * lee[((size_t)b * EE + e) * DD + k];
        a2 += p * f2e[((size_t)b * EE + e) * DD + k];
    }
    vlee[b * DD + k] = a1;
    vf2e[b * DD + k] = a2;
    float sp = 0.f;
    for (int e = k; e < EE; e += 256) sp += pr[b * EE + e];
    __shared__ float red[256];
    red[k] = sp; __syncthreads();
    for (int s = 128; s > 0; s >>= 1) {
        if (k < s) red[k] += red[k + s];
        __syncthreads();
    }
    if (k == 0) sumpr[b] = red[0];
}

// qne[b,j] = sumpr*b_j + sum_k vlee*W[j,k] + sumpr*qlin*W[j,256+k] + 3*vf2e*W[j,512+k]
__global__ __launch_bounds__(256) void qneupd_k(
    const float* __restrict__ vlee, const float* __restrict__ vf2e,
    const float* __restrict__ qlin, const float* __restrict__ sumpr,
    const float* __restrict__ W, const float* __restrict__ bias, float* __restrict__ qne)
{
    __shared__ float s1[DD], s2[DD], s3[DD];
    int b = blockIdx.x, j = threadIdx.x;
    s1[j] = vlee[b * DD + j]; s2[j] = qlin[b * DD + j]; s3[j] = vf2e[b * DD + j];
    __syncthreads();
    float sp = sumpr[b];
    float acc = sp * bias[j];
    const float* wr = W + (size_t)j * 768;
    #pragma unroll 4
    for (int k = 0; k < DD; ++k)
        acc += s1[k] * wr[k] + sp * s2[k] * wr[256 + k] + 3.f * s3[k] * wr[512 + k];
    qne[b * DD + j] = acc;
}

__global__ void score_k(const float* __restrict__ lee, const float* __restrict__ sw,
                        const float* __restrict__ sb, float* __restrict__ score)
{
    int r = blockIdx.x * 256 + threadIdx.x;
    if (r >= BB * EE) return;
    float acc = sb[0];
    const float* a = lee + (size_t)r * DD;
    for (int k = 0; k < DD; k += 4) {
        float4 v = *(const float4*)(a + k);
        acc += v.x * sw[k] + v.y * sw[k + 1] + v.z * sw[k + 2] + v.w * sw[k + 3];
    }
    score[r] = acc;
}

// per-batch: pred_dist, argmax(pred), loss partial
__global__ __launch_bounds__(256) void final_k(
    const float* __restrict__ score, const int* __restrict__ local_entity,
    const float* __restrict__ ans, float* __restrict__ out, float* __restrict__ losspart)
{
    int b = blockIdx.x, t = threadIdx.x;
    float lsum = 0.f, bm = -INFINITY;
    int bi = EE;
    for (int e = t; e < EE; e += 256) {
        float s = score[b * EE + e];
        float mask = (local_entity[b * EE + e] != NENT) ? 1.f : 0.f;
        float smv = s + (1.f - mask) * VNEG;
        float sig;
        if (smv >= 0.f) sig = 1.f / (1.f + expf(-smv));
        else { float es = expf(smv); sig = es / (1.f + es); }
        out[1 + BB + b * EE + e] = sig * mask;
        lsum += fmaxf(s, 0.f) - s * ans[b * EE + e] + log1pf(expf(-fabsf(s)));
        if (smv > bm) { bm = smv; bi = e; }
    }
    __shared__ float rv[256]; __shared__ int ri[256]; __shared__ float rl[256];
    rv[t] = bm; ri[t] = bi; rl[t] = lsum;
    __syncthreads();
    for (int s = 128; s > 0; s >>= 1) {
        if (t < s) {
            rl[t] += rl[t + s];
            if (rv[t + s] > rv[t] || (rv[t + s] == rv[t] && ri[t + s] < ri[t])) {
                rv[t] = rv[t + s]; ri[t] = ri[t + s];
            }
        }
        __syncthreads();
    }
    if (t == 0) { losspart[b] = rl[0]; out[1 + b] = (float)ri[0]; }
}

__global__ void loss_k(const float* __restrict__ losspart, float* __restrict__ out)
{
    if (threadIdx.x == 0) {
        float s = 0.f;
        for (int b = 0; b < BB; ++b) s += losspart[b];
        out[0] = s / (float)(BB * EE);
    }
}

// ---------------------------------------------------------------------------
extern "C" void kernel_launch(void* const* d_in, const int* in_sizes, int n_in,
                              void* d_out, int out_size, void* d_ws, size_t ws_size,
                              hipStream_t stream)
{
    (void)in_sizes; (void)n_in; (void)out_size; (void)ws_size;
    const int*   local_entity = (const int*)d_in[0];
    const float* q2e_adj      = (const float*)d_in[1];
    const int*   kb_fact_rel  = (const int*)d_in[2];
    const int*   query_text   = (const int*)d_in[3];
    const float* answer_dist  = (const float*)d_in[4];
    const int*   e2f_idx      = (const int*)d_in[5];
    const float* e2f_val      = (const float*)d_in[6];
    const int*   f2e_idx      = (const int*)d_in[7];
    const float* f2e_val      = (const float*)d_in[8];
    const float* entity_table = (const float*)d_in[9];
    const float* ent_W        = (const float*)d_in[10];
    const float* ent_b        = (const float*)d_in[11];
    const float* rel_table    = (const float*)d_in[12];
    const float* rel_W        = (const float*)d_in[13];
    const float* rel_b        = (const float*)d_in[14];
    const float* word_table   = (const float*)d_in[15];
    const float* Wih          = (const float*)d_in[16];
    const float* Whh          = (const float*)d_in[17];
    const float* bih          = (const float*)d_in[18];
    const float* bhh          = (const float*)d_in[19];
    const float* q2e_W        = (const float*)d_in[20];
    const float* q2e_b        = (const float*)d_in[21];
    const float* e2q_W        = (const float*)d_in[22];
    const float* e2q_b        = (const float*)d_in[23];
    const float* e2e_W        = (const float*)d_in[24];
    const float* e2e_b        = (const float*)d_in[25];
    const float* head_W       = (const float*)d_in[26];
    const float* head_b       = (const float*)d_in[27];
    const float* tail_W       = (const float*)d_in[28];
    const float* tail_b       = (const float*)d_in[29];
    const float* self_W       = (const float*)d_in[30];
    const float* self_b       = (const float*)d_in[31];
    const float* score_W      = (const float*)d_in[32];
    const float* score_b      = (const float*)d_in[33];

    float* ws = (float*)d_ws;
    size_t off = 0;
    auto alloc = [&](size_t n) { float* p = ws + off; off += n; return p; };
    float* Xg      = alloc((size_t)BB * QQ * 1024);
    float* qh      = alloc((size_t)BB * QQ * DD);
    float* qne     = alloc(BB * DD);
    float* lfe     = alloc((size_t)BB * FF * DD);
    float* lee     = alloc((size_t)BB * EE * DD);
    float* lee2    = alloc((size_t)BB * EE * DD);
    float* Wt      = alloc(BB * FF);
    float* WtMax   = alloc(8);
    float* Wtil    = alloc(BB * FF);
    float* e2fsm   = alloc(BB * EE);
    float* pr      = alloc(BB * EE);
    float* prd     = alloc(BB * EE);
    float* qlin    = alloc(BB * DD);
    float* ebias   = alloc(BB * DD);
    float* normacc = alloc(BB * FF);
    float* e2fnrm  = alloc(BB * FF);
    float* pracc   = alloc(BB * EE);
    float* vlee    = alloc(BB * DD);
    float* vf2e    = alloc(BB * DD);
    float* sumpr   = alloc(8);
    float* scoreb  = alloc(BB * EE);
    float* losspart= alloc(8);
    float* bufC    = alloc((size_t)BB * FF * DD);   // headlin / taillin (time-shared)
    float* e2fT    = alloc((size_t)BB * FF * DD);   // e2f_emb
    float* f2eT    = alloc((size_t)BB * EE * DD);   // f2e_emb

    float* outp = (float*)d_out;

    // LSTM input gates (x part): Xg = word_table[query_text] @ Wih.T + bih
    gemm_k<1, 0, 0><<<dim3(1024 / 64, (BB * QQ + 63) / 64), 256, 0, stream>>>(
        word_table, query_text, nullptr, Wih, 256, bih, Xg, BB * QQ, 1024, 256);
    lstm_k<<<BB, 1024, 0, stream>>>(Xg, Whh, bhh, qh, qne);

    // local_fact_emb / local_entity_emb (gathered GEMMs)
    gemm_k<1, 0, 0><<<dim3(4, (BB * FF + 63) / 64), 256, 0, stream>>>(
        rel_table, kb_fact_rel, nullptr, rel_W, 256, rel_b, lfe, BB * FF, 256, 256);
    gemm_k<1, 0, 0><<<dim3(4, (BB * EE + 63) / 64), 256, 0, stream>>>(
        entity_table, local_entity, nullptr, ent_W, 256, ent_b, lee, BB * EE, 256, 256);

    // attention -> W_tilde
    simwt_k<<<dim3((FF + 255) / 256, BB), 256, 0, stream>>>(qh, query_text, lfe, Wt);
    rowmax_k<<<BB, 256, 0, stream>>>(Wt, WtMax);
    wtil_k<<<(BB * FF + 255) / 256, 256, 0, stream>>>(Wt, WtMax, Wtil);

    // e2f_softmax
    hipMemsetAsync(e2fsm, 0, BB * EE * sizeof(float), stream);
    scatter_scalar_k<1><<<(NNZ_ + 255) / 256, 256, 0, stream>>>(
        e2f_idx, e2f_val, Wtil, e2fsm, EE, FF);

    // pagerank init
    hipMemcpyAsync(pr, q2e_adj, BB * EE * sizeof(float), hipMemcpyDeviceToDevice, stream);

    for (int i = 0; i < 3; ++i) {
        const float* q2eWi  = q2e_W  + (size_t)i * DD * DD;
        const float* q2ebi  = q2e_b  + i * DD;
        const float* e2qWi  = e2q_W  + (size_t)i * DD * 3 * DD;
        const float* e2qbi  = e2q_b  + i * DD;
        const float* e2eWi  = e2e_W  + (size_t)i * DD * 3 * DD;
        const float* e2ebi  = e2e_b  + i * DD;
        const float* headWi = head_W + (size_t)i * DD * DD;
        const float* headbi = head_b + i * DD;
        const float* tailWi = tail_W + (size_t)i * DD * DD;
        const float* tailbi = tail_b + i * DD;
        const float* selfWi = self_W + (size_t)i * DD * DD;
        const float* selfbi = self_b + i * DD;

        // q2e_lin from entering query_node_emb
        matvec_k<<<BB, 256, 0, stream>>>(qne, q2eWi, 256, 0, q2ebi, qlin);

        // e2f_norm = W_tilde * scatter(pagerank/e2f_softmax)
        prdiv_k<<<(BB * EE + 255) / 256, 256, 0, stream>>>(pr, e2fsm, prd);
        hipMemsetAsync(normacc, 0, BB * FF * sizeof(float), stream);
        scatter_scalar_k<0><<<(NNZ_ + 255) / 256, 256, 0, stream>>>(
            e2f_idx, e2f_val, prd, normacc, FF, EE);
        e2fnorm_k<<<(BB * FF + 255) / 256, 256, 0, stream>>>(Wtil, normacc, e2fnrm);

        // e2f_emb = relu(self(lfe) + scatter(head(lee))) * e2f_norm
        gemm_k<0, 0, 0><<<dim3(4, (BB * EE + 63) / 64), 256, 0, stream>>>(
            lee, nullptr, nullptr, headWi, 256, headbi, bufC, BB * EE, 256, 256);
        gemm_k<0, 0, 0><<<dim3(4, (BB * FF + 63) / 64), 256, 0, stream>>>(
            lfe, nullptr, nullptr, selfWi, 256, selfbi, e2fT, BB * FF, 256, 256);
        scatter_rows_k<<<(NNZ_ * 64) / 256, 256, 0, stream>>>(
            e2f_idx, e2f_val, bufC, e2fT, FF, EE);
        scale_relu_k<<<(BB * FF * 64 + 255) / 256, 256, 0, stream>>>(e2fT, e2fnrm);

        // f2e_emb = relu(self(lee) + scatter(tail(e2f_emb)))
        gemm_k<0, 0, 0><<<dim3(4, (BB * FF + 63) / 64), 256, 0, stream>>>(
            e2fT, nullptr, nullptr, tailWi, 256, tailbi, bufC, BB * FF, 256, 256);
        gemm_k<0, 0, 0><<<dim3(4, (BB * EE + 63) / 64), 256, 0, stream>>>(
            lee, nullptr, nullptr, selfWi, 256, selfbi, f2eT, BB * EE, 256, 256);
        scatter_rows_k<<<(NNZ_ * 64) / 256, 256, 0, stream>>>(
            f2e_idx, f2e_val, bufC, f2eT, EE, FF);
        relu_k<<<(BB * EE * 64 + 255) / 256, 256, 0, stream>>>(f2eT, BB * EE * 64);

        // pagerank update (before query_node_emb, per reference)
        hipMemsetAsync(pracc, 0, BB * EE * sizeof(float), stream);
        scatter_scalar_k<0><<<(NNZ_ + 255) / 256, 256, 0, stream>>>(
            f2e_idx, f2e_val, e2fnrm, pracc, EE, FF);
        prupd_k<<<(BB * EE + 255) / 256, 256, 0, stream>>>(pr, pracc);

        // query_node_emb update via linearity of the e2q einsum
        vreduce_k<<<BB, 256, 0, stream>>>(pr, lee, f2eT, vlee, vf2e, sumpr);
        qneupd_k<<<BB, 256, 0, stream>>>(vlee, vf2e, qlin, sumpr, e2qWi, e2qbi, qne);

        // local_entity_emb = relu(e2e(nxt)) with q2e block folded into ebias
        matvec_k<<<BB, 256, 0, stream>>>(qlin, e2eWi, 768, 256, e2ebi, ebias);
        gemm_k<0, 1, 1><<<dim3(4, (BB * EE + 63) / 64), 256, 0, stream>>>(
            lee, nullptr, f2eT, e2eWi, 768, ebias, lee2, BB * EE, 256, 512);
        { float* t = lee; lee = lee2; lee2 = t; }
    }

    score_k<<<(BB * EE + 255) / 256, 256, 0, stream>>>(lee, score_W, score_b, scoreb);
    final_k<<<BB, 256, 0, stream>>>(scoreb, local_entity, answer_dist, outp, losspart);
    loss_k<<<1, 64, 0, stream>>>(losspart, outp);
}

// Round 2
// 3989.492 us; speedup vs baseline: 1.1015x; 1.1015x over previous
//
#include <hip/hip_runtime.h>
#include <math.h>

#define BB 8
#define EE 2000
#define FF 6000
#define QQ 20
#define DD 256
#define NENT 400000
#define NWORD 60000
#define NNZ_ 96000
#define VNEG  (-1e11f)
#define VSMALL 1e-10f

// ---------------------------------------------------------------------------
// Tiled fp32 GEMM with register prefetch (2-phase pipeline, single LDS buf):
//   out[m,n] = act( sum_k A(m,k)*W[n,wk(k)] + bias )
//   GATHER:  A row = table[idx[m]] (table ld = K)
//   CONCAT2: K=512, k<256 from A1 (ld 256), k>=256 from A2*3 (ld 256),
//            W columns k>=256 map to W[n, 512 + (k-256)] (ldw=768),
//            bias indexed per (row-batch, n): bias[(m/EE)*256 + n]
// 64x64 tile, 256 threads, 4x4 per thread, K-chunks of 16, LDS transposed.
// ---------------------------------------------------------------------------
template<int GATHER, int RELU, int CONCAT2>
__global__ __launch_bounds__(256) void gemm_k(
    const float* __restrict__ A1, const int* __restrict__ idx,
    const float* __restrict__ A2,
    const float* __restrict__ W, int ldw,
    const float* __restrict__ bias,
    float* __restrict__ out, int M, int N, int K)
{
    __shared__ float As[16][68];
    __shared__ float Bs[16][68];
    const int tid = threadIdx.x;
    const int row0 = blockIdx.y * 64, col0 = blockIdx.x * 64;
    const int tx = tid & 15, ty = tid >> 4;
    const int lrow = tid >> 2, lk4 = (tid & 3) << 2;
    const int gr = row0 + lrow;
    const bool rvalid = (gr < M);
    const float* aRow = nullptr;
    if (rvalid) {
        if (GATHER)       aRow = A1 + (size_t)idx[gr] * K;
        else if (CONCAT2) aRow = A1 + (size_t)gr * 256;
        else              aRow = A1 + (size_t)gr * K;
    }
    const float* bRow = W + (size_t)(col0 + lrow) * ldw;

    float acc[4][4] = {{0.f}};
    const int nk = K >> 4;

    float4 av = make_float4(0.f, 0.f, 0.f, 0.f), bv;
    auto fetch = [&](int ch, float4& a, float4& b2) {
        const int k0 = ch << 4;
        if (rvalid) {
            if (CONCAT2 && k0 >= 256)
                a = *(const float4*)(A2 + (size_t)gr * 256 + (k0 - 256) + lk4);
            else
                a = *(const float4*)(aRow + k0 + lk4);
        }
        const int wk = (CONCAT2 && k0 >= 256) ? (k0 + 256 + lk4) : (k0 + lk4);
        b2 = *(const float4*)(bRow + wk);
    };

    fetch(0, av, bv);
    for (int ch = 0; ch < nk; ++ch) {
        const float s3 = (CONCAT2 && ch >= 16) ? 3.f : 1.f;
        As[lk4 + 0][lrow] = av.x * s3; As[lk4 + 1][lrow] = av.y * s3;
        As[lk4 + 2][lrow] = av.z * s3; As[lk4 + 3][lrow] = av.w * s3;
        Bs[lk4 + 0][lrow] = bv.x; Bs[lk4 + 1][lrow] = bv.y;
        Bs[lk4 + 2][lrow] = bv.z; Bs[lk4 + 3][lrow] = bv.w;
        __syncthreads();
        if (ch + 1 < nk) fetch(ch + 1, av, bv);   // prefetch hides under compute
        #pragma unroll
        for (int kk = 0; kk < 16; ++kk) {
            float4 a = *(const float4*)&As[kk][ty << 2];
            float4 b = *(const float4*)&Bs[kk][tx << 2];
            acc[0][0] += a.x * b.x; acc[0][1] += a.x * b.y; acc[0][2] += a.x * b.z; acc[0][3] += a.x * b.w;
            acc[1][0] += a.y * b.x; acc[1][1] += a.y * b.y; acc[1][2] += a.y * b.z; acc[1][3] += a.y * b.w;
            acc[2][0] += a.z * b.x; acc[2][1] += a.z * b.y; acc[2][2] += a.z * b.z; acc[2][3] += a.z * b.w;
            acc[3][0] += a.w * b.x; acc[3][1] += a.w * b.y; acc[3][2] += a.w * b.z; acc[3][3] += a.w * b.w;
        }
        __syncthreads();
    }
    #pragma unroll
    for (int i = 0; i < 4; ++i) {
        int r = row0 + (ty << 2) + i;
        if (r >= M) break;
        float* orow = out + (size_t)r * N + col0 + (tx << 2);
        const float* bp = CONCAT2 ? (bias + (size_t)(r / EE) * 256 + col0 + (tx << 2))
                                  : (bias + col0 + (tx << 2));
        #pragma unroll
        for (int j = 0; j < 4; ++j) {
            float v = acc[i][j] + bp[j];
            if (RELU) v = fmaxf(v, 0.f);
            orow[j] = v;
        }
    }
}

// ---------------------------------------------------------------------------
// Whh transpose: WhhT[k][j] = Whh[j][k]   (1024x256 -> 256x1024)
// ---------------------------------------------------------------------------
__global__ void transpose_whh_k(const float* __restrict__ Whh, float* __restrict__ WhhT)
{
    int i = blockIdx.x * 256 + threadIdx.x;   // i = k*1024 + j
    int k = i >> 10, j = i & 1023;
    WhhT[i] = Whh[(size_t)j * 256 + k];
}

// ---------------------------------------------------------------------------
// LSTM: 1 block/batch, 256 threads; thread t computes gate rows 4t..4t+3 via
// coalesced float4 loads of transposed Whh; 4 independent FMA chains; c in reg.
// ---------------------------------------------------------------------------
__global__ __launch_bounds__(256) void lstm_k(
    const float* __restrict__ Xg, const float* __restrict__ WhhT,
    const float* __restrict__ bhh, float* __restrict__ qh, float* __restrict__ qne)
{
    __shared__ float h[DD];
    __shared__ float gs[4 * DD];
    const int b = blockIdx.x, t = threadIdx.x;
    h[t] = 0.f;
    float c = 0.f;
    const float4 bb4 = *(const float4*)(bhh + 4 * t);
    const float4* wt4 = (const float4*)WhhT + t;   // [k][t] float4 granules
    __syncthreads();
    for (int step = 0; step < QQ; ++step) {
        float a0 = 0.f, a1 = 0.f, a2 = 0.f, a3 = 0.f;
        #pragma unroll 16
        for (int k = 0; k < DD; ++k) {
            float4 w = wt4[k * 256];
            float hk = h[k];
            a0 += w.x * hk; a1 += w.y * hk; a2 += w.z * hk; a3 += w.w * hk;
        }
        float4 xg = *(const float4*)(Xg + ((size_t)b * QQ + step) * 1024 + 4 * t);
        float4 g4 = make_float4(a0 + xg.x + bb4.x, a1 + xg.y + bb4.y,
                                a2 + xg.z + bb4.z, a3 + xg.w + bb4.w);
        *(float4*)(gs + 4 * t) = g4;
        __syncthreads();
        float gi = gs[t], gf = gs[DD + t], gg = gs[2 * DD + t], go = gs[3 * DD + t];
        float si = 1.f / (1.f + expf(-gi));
        float sf = 1.f / (1.f + expf(-gf));
        float so = 1.f / (1.f + expf(-go));
        c = sf * c + si * tanhf(gg);
        float hh = so * tanhf(c);
        h[t] = hh;
        qh[((size_t)b * QQ + step) * DD + t] = hh;
        __syncthreads();
    }
    qne[(size_t)b * DD + t] = h[t];
}

// ---------------------------------------------------------------------------
// Fused sim -> softmax(over q) -> Wt[b,f] = sum_q softmax*pre (att eliminated)
// ---------------------------------------------------------------------------
__global__ __launch_bounds__(256) void simwt_k(
    const float* __restrict__ qhid, const int* __restrict__ qtext,
    const float* __restrict__ lfe, float* __restrict__ Wt)
{
    __shared__ float qs[QQ * DD];
    __shared__ float qmn[QQ];
    const int b = blockIdx.y;
    const int f = blockIdx.x * 256 + threadIdx.x;
    for (int i = threadIdx.x; i < QQ * DD; i += 256) qs[i] = qhid[(size_t)b * QQ * DD + i];
    if (threadIdx.x < QQ)
        qmn[threadIdx.x] = (qtext[b * QQ + threadIdx.x] != NWORD) ? 0.f : VNEG;
    __syncthreads();
    if (f >= FF) return;
    float acc[QQ];
    #pragma unroll
    for (int q = 0; q < QQ; ++q) acc[q] = 0.f;
    const float* lr = lfe + ((size_t)b * FF + f) * DD;
    for (int d = 0; d < DD; d += 4) {
        float4 x = *(const float4*)(lr + d);
        #pragma unroll
        for (int q = 0; q < QQ; ++q) {
            float4 y = *(const float4*)&qs[q * DD + d];
            acc[q] += x.x * y.x + x.y * y.y + x.z * y.z + x.w * y.w;
        }
    }
    const float inv = 0.0625f;  // 1/sqrt(256)
    float pre[QQ], m = -INFINITY;
    #pragma unroll
    for (int q = 0; q < QQ; ++q) { pre[q] = acc[q] * inv + qmn[q]; m = fmaxf(m, pre[q]); }
    float s = 0.f;
    #pragma unroll
    for (int q = 0; q < QQ; ++q) s += expf(pre[q] - m);
    float wt = 0.f;
    #pragma unroll
    for (int q = 0; q < QQ; ++q) wt += (expf(pre[q] - m) / s) * (acc[q] * inv);
    Wt[(size_t)b * FF + f] = wt;
}

__global__ void rowmax_k(const float* __restrict__ Wt, float* __restrict__ WtMax)
{
    __shared__ float red[256];
    int b = blockIdx.x;
    float m = -INFINITY;
    for (int f = threadIdx.x; f < FF; f += 256) m = fmaxf(m, Wt[b * FF + f]);
    red[threadIdx.x] = m; __syncthreads();
    for (int s = 128; s > 0; s >>= 1) {
        if (threadIdx.x < s) red[threadIdx.x] = fmaxf(red[threadIdx.x], red[threadIdx.x + s]);
        __syncthreads();
    }
    if (threadIdx.x == 0) WtMax[b] = red[0];
}

__global__ void wtil_k(const float* __restrict__ Wt, const float* __restrict__ WtMax,
                       float* __restrict__ Wtil)
{
    int i = blockIdx.x * 256 + threadIdx.x;
    if (i >= BB * FF) return;
    Wtil[i] = expf(Wt[i] - WtMax[i / FF]);
}

// dst[b*nr + r] += val * f(src[b*nc + c]); SWAP picks which idx row is r.
// DIV: f(x) = x / max(sm, VSMALL)
template<int SWAP, int DIV>
__global__ void scatter_scalar_k(const int* __restrict__ idx, const float* __restrict__ val,
                                 const float* __restrict__ src, const float* __restrict__ sm,
                                 float* __restrict__ dst, int nr, int nc)
{
    int k = blockIdx.x * 256 + threadIdx.x;
    if (k >= NNZ_) return;
    int b = idx[k];
    int r = SWAP ? idx[2 * NNZ_ + k] : idx[NNZ_ + k];
    int c = SWAP ? idx[NNZ_ + k]     : idx[2 * NNZ_ + k];
    float x = src[(size_t)b * nc + c];
    if (DIV) x = x / fmaxf(sm[(size_t)b * nc + c], VSMALL);
    atomicAdd(&dst[(size_t)b * nr + r], val[k] * x);
}

// dst row (b*nrd + r) += val * src row (b*ncs + c); one wave per nnz, D=256.
__global__ __launch_bounds__(256) void scatter_rows_k(
    const int* __restrict__ idx, const float* __restrict__ val,
    const float* __restrict__ src, float* __restrict__ dst, int nrd, int ncs)
{
    int gid = blockIdx.x * 256 + threadIdx.x;
    int k = gid >> 6, lane = gid & 63;
    if (k >= NNZ_) return;
    int b = idx[k], r = idx[NNZ_ + k], c = idx[2 * NNZ_ + k];
    const float* s = src + ((size_t)b * ncs + c) * DD + (lane << 2);
    float* p = dst + ((size_t)b * nrd + r) * DD + (lane << 2);
    float v = val[k];
    float4 x = *(const float4*)s;
    atomicAdd(p + 0, v * x.x); atomicAdd(p + 1, v * x.y);
    atomicAdd(p + 2, v * x.z); atomicAdd(p + 3, v * x.w);
}

__global__ void e2fnorm_k(const float* __restrict__ Wtil, const float* __restrict__ nacc,
                          float* __restrict__ out)
{
    int i = blockIdx.x * 256 + threadIdx.x;
    if (i >= BB * FF) return;
    out[i] = Wtil[i] * nacc[i];
}

__global__ void scale_relu_k(float* __restrict__ x, const float* __restrict__ nrm)
{
    int gid = blockIdx.x * 256 + threadIdx.x;
    int row = gid >> 6, d = (gid & 63) << 2;
    if (row >= BB * FF) return;
    float s = nrm[row];
    float4* p = (float4*)(x + (size_t)row * DD + d);
    float4 v = *p;
    v.x = fmaxf(v.x, 0.f) * s; v.y = fmaxf(v.y, 0.f) * s;
    v.z = fmaxf(v.z, 0.f) * s; v.w = fmaxf(v.w, 0.f) * s;
    *p = v;
}

__global__ void relu_k(float* __restrict__ x, int n4)
{
    int i = blockIdx.x * 256 + threadIdx.x;
    if (i >= n4) return;
    float4* p = (float4*)x + i;
    float4 v = *p;
    v.x = fmaxf(v.x, 0.f); v.y = fmaxf(v.y, 0.f);
    v.z = fmaxf(v.z, 0.f); v.w = fmaxf(v.w, 0.f);
    *p = v;
}

__global__ void prupd_k(float* __restrict__ pr, const float* __restrict__ pracc)
{
    int i = blockIdx.x * 256 + threadIdx.x;
    if (i >= BB * EE) return;
    pr[i] = 0.8f * pracc[i] + 0.2f * pr[i];
}

// out[b,j] = bias[j] + sum_k x[b,k] * W[j*ldw + woff + k]
__global__ __launch_bounds__(256) void matvec_k(
    const float* __restrict__ x, const float* __restrict__ W, int ldw, int woff,
    const float* __restrict__ bias, float* __restrict__ out)
{
    __shared__ float xs[DD];
    int b = blockIdx.x, j = threadIdx.x;
    xs[j] = x[b * DD + j];
    __syncthreads();
    float acc = bias[j];
    const float* wr = W + (size_t)j * ldw + woff;
    #pragma unroll 4
    for (int k = 0; k < DD; ++k) acc += xs[k] * wr[k];
    out[b * DD + j] = acc;
}

// vlee[b,k] = sum_e pr[b,e]*lee[b,e,k]; vf2e likewise; sumpr[b] = sum_e pr.
__global__ __launch_bounds__(256) void vreduce_k(
    const float* __restrict__ pr, const float* __restrict__ lee,
    const float* __restrict__ f2e, float* __restrict__ vlee,
    float* __restrict__ vf2e, float* __restrict__ sumpr)
{
    int b = blockIdx.x, k = threadIdx.x;
    float a1 = 0.f, a2 = 0.f;
    for (int e = 0; e < EE; ++e) {
        float p = pr[b * EE + e];
        a1 += p * lee[((size_t)b * EE + e) * DD + k];
        a2 += p * f2e[((size_t)b * EE + e) * DD + k];
    }
    vlee[b * DD + k] = a1;
    vf2e[b * DD + k] = a2;
    float sp = 0.f;
    for (int e = k; e < EE; e += 256) sp += pr[b * EE + e];
    __shared__ float red[256];
    red[k] = sp; __syncthreads();
    for (int s = 128; s > 0; s >>= 1) {
        if (k < s) red[k] += red[k + s];
        __syncthreads();
    }
    if (k == 0) sumpr[b] = red[0];
}

// qne[b,j] = sumpr*b_j + sum_k vlee*W[j,k] + sumpr*qlin*W[j,256+k] + 3*vf2e*W[j,512+k]
__global__ __launch_bounds__(256) void qneupd_k(
    const float* __restrict__ vlee, const float* __restrict__ vf2e,
    const float* __restrict__ qlin, const float* __restrict__ sumpr,
    const float* __restrict__ W, const float* __restrict__ bias, float* __restrict__ qne)
{
    __shared__ float s1[DD], s2[DD], s3[DD];
    int b = blockIdx.x, j = threadIdx.x;
    s1[j] = vlee[b * DD + j]; s2[j] = qlin[b * DD + j]; s3[j] = vf2e[b * DD + j];
    __syncthreads();
    float sp = sumpr[b];
    float acc = sp * bias[j];
    const float* wr = W + (size_t)j * 768;
    #pragma unroll 4
    for (int k = 0; k < DD; ++k)
        acc += s1[k] * wr[k] + sp * s2[k] * wr[256 + k] + 3.f * s3[k] * wr[512 + k];
    qne[b * DD + j] = acc;
}

__global__ void score_k(const float* __restrict__ lee, const float* __restrict__ sw,
                        const float* __restrict__ sb, float* __restrict__ score)
{
    int r = blockIdx.x * 256 + threadIdx.x;
    if (r >= BB * EE) return;
    float acc = sb[0];
    const float* a = lee + (size_t)r * DD;
    for (int k = 0; k < DD; k += 4) {
        float4 v = *(const float4*)(a + k);
        acc += v.x * sw[k] + v.y * sw[k + 1] + v.z * sw[k + 2] + v.w * sw[k + 3];
    }
    score[r] = acc;
}

// per-batch: pred_dist, argmax(pred), loss partial
__global__ __launch_bounds__(256) void final_k(
    const float* __restrict__ score, const int* __restrict__ local_entity,
    const float* __restrict__ ans, float* __restrict__ out, float* __restrict__ losspart)
{
    int b = blockIdx.x, t = threadIdx.x;
    float lsum = 0.f, bm = -INFINITY;
    int bi = EE;
    for (int e = t; e < EE; e += 256) {
        float s = score[b * EE + e];
        float mask = (local_entity[b * EE + e] != NENT) ? 1.f : 0.f;
        float smv = s + (1.f - mask) * VNEG;
        float sig;
        if (smv >= 0.f) sig = 1.f / (1.f + expf(-smv));
        else { float es = expf(smv); sig = es / (1.f + es); }
        out[1 + BB + b * EE + e] = sig * mask;
        lsum += fmaxf(s, 0.f) - s * ans[b * EE + e] + log1pf(expf(-fabsf(s)));
        if (smv > bm) { bm = smv; bi = e; }
    }
    __shared__ float rv[256]; __shared__ int ri[256]; __shared__ float rl[256];
    rv[t] = bm; ri[t] = bi; rl[t] = lsum;
    __syncthreads();
    for (int s = 128; s > 0; s >>= 1) {
        if (t < s) {
            rl[t] += rl[t + s];
            if (rv[t + s] > rv[t] || (rv[t + s] == rv[t] && ri[t + s] < ri[t])) {
                rv[t] = rv[t + s]; ri[t] = ri[t + s];
            }
        }
        __syncthreads();
    }
    if (t == 0) { losspart[b] = rl[0]; out[1 + b] = (float)ri[0]; }
}

__global__ void loss_k(const float* __restrict__ losspart, float* __restrict__ out)
{
    if (threadIdx.x == 0) {
        float s = 0.f;
        for (int b = 0; b < BB; ++b) s += losspart[b];
        out[0] = s / (float)(BB * EE);
    }
}

// ---------------------------------------------------------------------------
extern "C" void kernel_launch(void* const* d_in, const int* in_sizes, int n_in,
                              void* d_out, int out_size, void* d_ws, size_t ws_size,
                              hipStream_t stream)
{
    (void)in_sizes; (void)n_in; (void)out_size; (void)ws_size;
    const int*   local_entity = (const int*)d_in[0];
    const float* q2e_adj      = (const float*)d_in[1];
    const int*   kb_fact_rel  = (const int*)d_in[2];
    const int*   query_text   = (const int*)d_in[3];
    const float* answer_dist  = (const float*)d_in[4];
    const int*   e2f_idx      = (const int*)d_in[5];
    const float* e2f_val      = (const float*)d_in[6];
    const int*   f2e_idx      = (const int*)d_in[7];
    const float* f2e_val      = (const float*)d_in[8];
    const float* entity_table = (const float*)d_in[9];
    const float* ent_W        = (const float*)d_in[10];
    const float* ent_b        = (const float*)d_in[11];
    const float* rel_table    = (const float*)d_in[12];
    const float* rel_W        = (const float*)d_in[13];
    const float* rel_b        = (const float*)d_in[14];
    const float* word_table   = (const float*)d_in[15];
    const float* Wih          = (const float*)d_in[16];
    const float* Whh          = (const float*)d_in[17];
    const float* bih          = (const float*)d_in[18];
    const float* bhh          = (const float*)d_in[19];
    const float* q2e_W        = (const float*)d_in[20];
    const float* q2e_b        = (const float*)d_in[21];
    const float* e2q_W        = (const float*)d_in[22];
    const float* e2q_b        = (const float*)d_in[23];
    const float* e2e_W        = (const float*)d_in[24];
    const float* e2e_b        = (const float*)d_in[25];
    const float* head_W       = (const float*)d_in[26];
    const float* head_b       = (const float*)d_in[27];
    const float* tail_W       = (const float*)d_in[28];
    const float* tail_b       = (const float*)d_in[29];
    const float* self_W       = (const float*)d_in[30];
    const float* self_b       = (const float*)d_in[31];
    const float* score_W      = (const float*)d_in[32];
    const float* score_b      = (const float*)d_in[33];

    float* ws = (float*)d_ws;
    size_t off = 0;
    auto alloc = [&](size_t n) { float* p = ws + off; off += n; return p; };
    float* Xg      = alloc((size_t)BB * QQ * 1024);
    float* WhhT    = alloc((size_t)1024 * DD);
    float* qh      = alloc((size_t)BB * QQ * DD);
    float* qne     = alloc(BB * DD);
    float* lfe     = alloc((size_t)BB * FF * DD);
    float* lee     = alloc((size_t)BB * EE * DD);
    float* lee2    = alloc((size_t)BB * EE * DD);
    float* Wt      = alloc(BB * FF);
    float* WtMax   = alloc(8);
    float* Wtil    = alloc(BB * FF);
    float* e2fsm   = alloc(BB * EE);
    float* pr      = alloc(BB * EE);
    float* qlin    = alloc(BB * DD);
    float* ebias   = alloc(BB * DD);
    float* normacc = alloc(BB * FF);
    float* e2fnrm  = alloc(BB * FF);
    float* pracc   = alloc(BB * EE);
    float* vlee    = alloc(BB * DD);
    float* vf2e    = alloc(BB * DD);
    float* sumpr   = alloc(8);
    float* scoreb  = alloc(BB * EE);
    float* losspart= alloc(8);
    float* bufC    = alloc((size_t)BB * FF * DD);   // headlin / taillin (time-shared)
    float* e2fT    = alloc((size_t)BB * FF * DD);   // e2f_emb
    float* f2eT    = alloc((size_t)BB * EE * DD);   // f2e_emb

    float* outp = (float*)d_out;

    // LSTM input gates (x part): Xg = word_table[query_text] @ Wih.T + bih
    gemm_k<1, 0, 0><<<dim3(1024 / 64, (BB * QQ + 63) / 64), 256, 0, stream>>>(
        word_table, query_text, nullptr, Wih, 256, bih, Xg, BB * QQ, 1024, 256);
    transpose_whh_k<<<1024, 256, 0, stream>>>(Whh, WhhT);
    lstm_k<<<BB, 256, 0, stream>>>(Xg, WhhT, bhh, qh, qne);

    // local_fact_emb / local_entity_emb (gathered GEMMs)
    gemm_k<1, 0, 0><<<dim3(4, (BB * FF + 63) / 64), 256, 0, stream>>>(
        rel_table, kb_fact_rel, nullptr, rel_W, 256, rel_b, lfe, BB * FF, 256, 256);
    gemm_k<1, 0, 0><<<dim3(4, (BB * EE + 63) / 64), 256, 0, stream>>>(
        entity_table, local_entity, nullptr, ent_W, 256, ent_b, lee, BB * EE, 256, 256);

    // attention -> W_tilde
    simwt_k<<<dim3((FF + 255) / 256, BB), 256, 0, stream>>>(qh, query_text, lfe, Wt);
    rowmax_k<<<BB, 256, 0, stream>>>(Wt, WtMax);
    wtil_k<<<(BB * FF + 255) / 256, 256, 0, stream>>>(Wt, WtMax, Wtil);

    // e2f_softmax
    hipMemsetAsync(e2fsm, 0, BB * EE * sizeof(float), stream);
    scatter_scalar_k<1, 0><<<(NNZ_ + 255) / 256, 256, 0, stream>>>(
        e2f_idx, e2f_val, Wtil, nullptr, e2fsm, EE, FF);

    // pagerank init
    hipMemcpyAsync(pr, q2e_adj, BB * EE * sizeof(float), hipMemcpyDeviceToDevice, stream);

    for (int i = 0; i < 3; ++i) {
        const float* q2eWi  = q2e_W  + (size_t)i * DD * DD;
        const float* q2ebi  = q2e_b  + i * DD;
        const float* e2qWi  = e2q_W  + (size_t)i * DD * 3 * DD;
        const float* e2qbi  = e2q_b  + i * DD;
        const float* e2eWi  = e2e_W  + (size_t)i * DD * 3 * DD;
        const float* e2ebi  = e2e_b  + i * DD;
        const float* headWi = head_W + (size_t)i * DD * DD;
        const float* headbi = head_b + i * DD;
        const float* tailWi = tail_W + (size_t)i * DD * DD;
        const float* tailbi = tail_b + i * DD;
        const float* selfWi = self_W + (size_t)i * DD * DD;
        const float* selfbi = self_b + i * DD;

        // q2e_lin from entering query_node_emb
        matvec_k<<<BB, 256, 0, stream>>>(qne, q2eWi, 256, 0, q2ebi, qlin);

        // e2f_norm = W_tilde * scatter(pagerank/e2f_softmax)  [div fused in scatter]
        hipMemsetAsync(normacc, 0, BB * FF * sizeof(float), stream);
        scatter_scalar_k<0, 1><<<(NNZ_ + 255) / 256, 256, 0, stream>>>(
            e2f_idx, e2f_val, pr, e2fsm, normacc, FF, EE);
        e2fnorm_k<<<(BB * FF + 255) / 256, 256, 0, stream>>>(Wtil, normacc, e2fnrm);

        // e2f_emb = relu(self(lfe) + scatter(head(lee))) * e2f_norm
        gemm_k<0, 0, 0><<<dim3(4, (BB * EE + 63) / 64), 256, 0, stream>>>(
            lee, nullptr, nullptr, headWi, 256, headbi, bufC, BB * EE, 256, 256);
        gemm_k<0, 0, 0><<<dim3(4, (BB * FF + 63) / 64), 256, 0, stream>>>(
            lfe, nullptr, nullptr, selfWi, 256, selfbi, e2fT, BB * FF, 256, 256);
        scatter_rows_k<<<(NNZ_ * 64) / 256, 256, 0, stream>>>(
            e2f_idx, e2f_val, bufC, e2fT, FF, EE);
        scale_relu_k<<<(BB * FF * 64 + 255) / 256, 256, 0, stream>>>(e2fT, e2fnrm);

        // f2e_emb = relu(self(lee) + scatter(tail(e2f_emb)))
        gemm_k<0, 0, 0><<<dim3(4, (BB * FF + 63) / 64), 256, 0, stream>>>(
            e2fT, nullptr, nullptr, tailWi, 256, tailbi, bufC, BB * FF, 256, 256);
        gemm_k<0, 0, 0><<<dim3(4, (BB * EE + 63) / 64), 256, 0, stream>>>(
            lee, nullptr, nullptr, selfWi, 256, selfbi, f2eT, BB * EE, 256, 256);
        scatter_rows_k<<<(NNZ_ * 64) / 256, 256, 0, stream>>>(
            f2e_idx, f2e_val, bufC, f2eT, EE, FF);
        relu_k<<<(BB * EE * 64 + 255) / 256, 256, 0, stream>>>(f2eT, BB * EE * 64);

        // pagerank update (before query_node_emb, per reference)
        hipMemsetAsync(pracc, 0, BB * EE * sizeof(float), stream);
        scatter_scalar_k<0, 0><<<(NNZ_ + 255) / 256, 256, 0, stream>>>(
            f2e_idx, f2e_val, e2fnrm, nullptr, pracc, EE, FF);
        prupd_k<<<(BB * EE + 255) / 256, 256, 0, stream>>>(pr, pracc);

        // query_node_emb update via linearity of the e2q einsum
        vreduce_k<<<BB, 256, 0, stream>>>(pr, lee, f2eT, vlee, vf2e, sumpr);
        qneupd_k<<<BB, 256, 0, stream>>>(vlee, vf2e, qlin, sumpr, e2qWi, e2qbi, qne);

        // local_entity_emb = relu(e2e(nxt)) with q2e block folded into ebias
        matvec_k<<<BB, 256, 0, stream>>>(qlin, e2eWi, 768, 256, e2ebi, ebias);
        gemm_k<0, 1, 1><<<dim3(4, (BB * EE + 63) / 64), 256, 0, stream>>>(
            lee, nullptr, f2eT, e2eWi, 768, ebias, lee2, BB * EE, 256, 512);
        { float* t = lee; lee = lee2; lee2 = t; }
    }

    score_k<<<(BB * EE + 255) / 256, 256, 0, stream>>>(lee, score_W, score_b, scoreb);
    final_k<<<BB, 256, 0, stream>>>(scoreb, local_entity, answer_dist, outp, losspart);
    loss_k<<<1, 64, 0, stream>>>(losspart, outp);
}

// Round 3
// 1929.799 us; speedup vs baseline: 2.2771x; 2.0673x over previous
//
#include <hip/hip_runtime.h>
#include <math.h>

#define BB 8
#define EE 2000
#define FF 6000
#define QQ 20
#define DD 256
#define NENT 400000
#define NWORD 60000
#define NNZ_ 96000
#define VNEG  (-1e11f)
#define VSMALL 1e-10f

// ---------------------------------------------------------------------------
// Tiled fp32 GEMM with register prefetch (2-phase pipeline, single LDS buf).
// ---------------------------------------------------------------------------
template<int GATHER, int RELU, int CONCAT2>
__global__ __launch_bounds__(256) void gemm_k(
    const float* __restrict__ A1, const int* __restrict__ idx,
    const float* __restrict__ A2,
    const float* __restrict__ W, int ldw,
    const float* __restrict__ bias,
    float* __restrict__ out, int M, int N, int K)
{
    __shared__ float As[16][68];
    __shared__ float Bs[16][68];
    const int tid = threadIdx.x;
    const int row0 = blockIdx.y * 64, col0 = blockIdx.x * 64;
    const int tx = tid & 15, ty = tid >> 4;
    const int lrow = tid >> 2, lk4 = (tid & 3) << 2;
    const int gr = row0 + lrow;
    const bool rvalid = (gr < M);
    const float* aRow = nullptr;
    if (rvalid) {
        if (GATHER)       aRow = A1 + (size_t)idx[gr] * K;
        else if (CONCAT2) aRow = A1 + (size_t)gr * 256;
        else              aRow = A1 + (size_t)gr * K;
    }
    const float* bRow = W + (size_t)(col0 + lrow) * ldw;

    float acc[4][4] = {{0.f}};
    const int nk = K >> 4;

    float4 av = make_float4(0.f, 0.f, 0.f, 0.f), bv;
    auto fetch = [&](int ch, float4& a, float4& b2) {
        const int k0 = ch << 4;
        if (rvalid) {
            if (CONCAT2 && k0 >= 256)
                a = *(const float4*)(A2 + (size_t)gr * 256 + (k0 - 256) + lk4);
            else
                a = *(const float4*)(aRow + k0 + lk4);
        }
        const int wk = (CONCAT2 && k0 >= 256) ? (k0 + 256 + lk4) : (k0 + lk4);
        b2 = *(const float4*)(bRow + wk);
    };

    fetch(0, av, bv);
    for (int ch = 0; ch < nk; ++ch) {
        const float s3 = (CONCAT2 && ch >= 16) ? 3.f : 1.f;
        As[lk4 + 0][lrow] = av.x * s3; As[lk4 + 1][lrow] = av.y * s3;
        As[lk4 + 2][lrow] = av.z * s3; As[lk4 + 3][lrow] = av.w * s3;
        Bs[lk4 + 0][lrow] = bv.x; Bs[lk4 + 1][lrow] = bv.y;
        Bs[lk4 + 2][lrow] = bv.z; Bs[lk4 + 3][lrow] = bv.w;
        __syncthreads();
        if (ch + 1 < nk) fetch(ch + 1, av, bv);
        #pragma unroll
        for (int kk = 0; kk < 16; ++kk) {
            float4 a = *(const float4*)&As[kk][ty << 2];
            float4 b = *(const float4*)&Bs[kk][tx << 2];
            acc[0][0] += a.x * b.x; acc[0][1] += a.x * b.y; acc[0][2] += a.x * b.z; acc[0][3] += a.x * b.w;
            acc[1][0] += a.y * b.x; acc[1][1] += a.y * b.y; acc[1][2] += a.y * b.z; acc[1][3] += a.y * b.w;
            acc[2][0] += a.z * b.x; acc[2][1] += a.z * b.y; acc[2][2] += a.z * b.z; acc[2][3] += a.z * b.w;
            acc[3][0] += a.w * b.x; acc[3][1] += a.w * b.y; acc[3][2] += a.w * b.z; acc[3][3] += a.w * b.w;
        }
        __syncthreads();
    }
    #pragma unroll
    for (int i = 0; i < 4; ++i) {
        int r = row0 + (ty << 2) + i;
        if (r >= M) break;
        float* orow = out + (size_t)r * N + col0 + (tx << 2);
        const float* bp = CONCAT2 ? (bias + (size_t)(r / EE) * 256 + col0 + (tx << 2))
                                  : (bias + col0 + (tx << 2));
        #pragma unroll
        for (int j = 0; j < 4; ++j) {
            float v = acc[i][j] + bp[j];
            if (RELU) v = fmaxf(v, 0.f);
            orow[j] = v;
        }
    }
}

// ---------------------------------------------------------------------------
// CSR build: count -> scan -> fill  (per-call, deterministic inputs)
// ---------------------------------------------------------------------------
__global__ void csr_count_k(const int* __restrict__ idx, int* __restrict__ cnt, int nrPerB)
{
    int k = blockIdx.x * 256 + threadIdx.x;
    if (k >= NNZ_) return;
    atomicAdd(&cnt[idx[k] * nrPerB + idx[NNZ_ + k]], 1);
}

__global__ __launch_bounds__(1024) void scan_k(const int* __restrict__ cnt,
                                               int* __restrict__ rowptr, int n)
{
    __shared__ int sums[1024];
    int t = threadIdx.x;
    int chunk = (n + 1023) / 1024;
    int lo = t * chunk, hi = lo + chunk;
    if (lo > n) lo = n;
    if (hi > n) hi = n;
    int s = 0;
    for (int i = lo; i < hi; ++i) s += cnt[i];
    sums[t] = s;
    __syncthreads();
    for (int off = 1; off < 1024; off <<= 1) {
        int v = (t >= off) ? sums[t - off] : 0;
        __syncthreads();
        sums[t] += v;
        __syncthreads();
    }
    int run = (t == 0) ? 0 : sums[t - 1];
    for (int i = lo; i < hi; ++i) { rowptr[i] = run; run += cnt[i]; }
    if (hi == n) rowptr[n] = run;
}

__global__ void csr_fill_k(const int* __restrict__ idx, const float* __restrict__ val,
                           int* __restrict__ cur, int* __restrict__ col,
                           float* __restrict__ valp, int nrPerB)
{
    int k = blockIdx.x * 256 + threadIdx.x;
    if (k >= NNZ_) return;
    int row = idx[k] * nrPerB + idx[NNZ_ + k];
    int p = atomicAdd(&cur[row], 1);
    col[p] = idx[2 * NNZ_ + k];
    valp[p] = val[k];
}

// ---------------------------------------------------------------------------
// Row gather (replaces atomic scatter_rows): one wave per dest row.
// dst[row] = act(dst[row] + sum_j val[j]*src[b*ncs+col[j]]); MODE1: *nrm[row]
// ---------------------------------------------------------------------------
template<int MODE>  // 0: relu (f2e), 1: relu then *nrm (e2f)
__global__ __launch_bounds__(256) void gather_rows_k(
    const int* __restrict__ rowptr, const int* __restrict__ col,
    const float* __restrict__ valp, const float* __restrict__ src,
    const float* __restrict__ nrm, float* __restrict__ dst, int nrows,
    int nrPerB, int ncs)
{
    int gid = blockIdx.x * 256 + threadIdx.x;
    int row = gid >> 6, lane = gid & 63;
    if (row >= nrows) return;
    int b = row / nrPerB;
    float4* dp = (float4*)(dst + (size_t)row * DD + (lane << 2));
    float4 acc = *dp;
    int j0 = rowptr[row], j1 = rowptr[row + 1];
    for (int j = j0; j < j1; ++j) {
        int c = col[j];
        float v = valp[j];
        float4 x = *(const float4*)(src + ((size_t)b * ncs + c) * DD + (lane << 2));
        acc.x += v * x.x; acc.y += v * x.y; acc.z += v * x.z; acc.w += v * x.w;
    }
    acc.x = fmaxf(acc.x, 0.f); acc.y = fmaxf(acc.y, 0.f);
    acc.z = fmaxf(acc.z, 0.f); acc.w = fmaxf(acc.w, 0.f);
    if (MODE == 1) {
        float s = nrm[row];
        acc.x *= s; acc.y *= s; acc.z *= s; acc.w *= s;
    }
    *dp = acc;
}

// e2fnrm[b,f] = Wtil[b,f] * sum_j val[j] * pr[b,c]/max(sm[b,c],eps)
__global__ void gather_norm_k(const int* __restrict__ rowptr, const int* __restrict__ col,
                              const float* __restrict__ valp, const float* __restrict__ pr,
                              const float* __restrict__ sm, const float* __restrict__ Wtil,
                              float* __restrict__ e2fnrm, int nrows)
{
    int row = blockIdx.x * 256 + threadIdx.x;
    if (row >= nrows) return;
    int b = row / FF;
    float s = 0.f;
    for (int j = rowptr[row]; j < rowptr[row + 1]; ++j) {
        int c = col[j];
        s += valp[j] * (pr[(size_t)b * EE + c] / fmaxf(sm[(size_t)b * EE + c], VSMALL));
    }
    e2fnrm[row] = Wtil[row] * s;
}

// pr[b,e] = 0.8 * sum_j val[j]*e2fnrm[b,c] + 0.2*pr[b,e]
__global__ void gather_pr_k(const int* __restrict__ rowptr, const int* __restrict__ col,
                            const float* __restrict__ valp, const float* __restrict__ e2fnrm,
                            float* __restrict__ pr, int nrows)
{
    int row = blockIdx.x * 256 + threadIdx.x;
    if (row >= nrows) return;
    int b = row / EE;
    float s = 0.f;
    for (int j = rowptr[row]; j < rowptr[row + 1]; ++j)
        s += valp[j] * e2fnrm[(size_t)b * FF + col[j]];
    pr[row] = 0.8f * s + 0.2f * pr[row];
}

// ---------------------------------------------------------------------------
// Whh transpose + LSTM (coalesced float4, 4 independent chains)
// ---------------------------------------------------------------------------
__global__ void transpose_whh_k(const float* __restrict__ Whh, float* __restrict__ WhhT)
{
    int i = blockIdx.x * 256 + threadIdx.x;
    int k = i >> 10, j = i & 1023;
    WhhT[i] = Whh[(size_t)j * 256 + k];
}

__global__ __launch_bounds__(256) void lstm_k(
    const float* __restrict__ Xg, const float* __restrict__ WhhT,
    const float* __restrict__ bhh, float* __restrict__ qh, float* __restrict__ qne)
{
    __shared__ float h[DD];
    __shared__ float gs[4 * DD];
    const int b = blockIdx.x, t = threadIdx.x;
    h[t] = 0.f;
    float c = 0.f;
    const float4 bb4 = *(const float4*)(bhh + 4 * t);
    const float4* wt4 = (const float4*)WhhT + t;
    __syncthreads();
    for (int step = 0; step < QQ; ++step) {
        float a0 = 0.f, a1 = 0.f, a2 = 0.f, a3 = 0.f;
        #pragma unroll 16
        for (int k = 0; k < DD; ++k) {
            float4 w = wt4[k * 256];
            float hk = h[k];
            a0 += w.x * hk; a1 += w.y * hk; a2 += w.z * hk; a3 += w.w * hk;
        }
        float4 xg = *(const float4*)(Xg + ((size_t)b * QQ + step) * 1024 + 4 * t);
        float4 g4 = make_float4(a0 + xg.x + bb4.x, a1 + xg.y + bb4.y,
                                a2 + xg.z + bb4.z, a3 + xg.w + bb4.w);
        *(float4*)(gs + 4 * t) = g4;
        __syncthreads();
        float gi = gs[t], gf = gs[DD + t], gg = gs[2 * DD + t], go = gs[3 * DD + t];
        float si = 1.f / (1.f + expf(-gi));
        float sf = 1.f / (1.f + expf(-gf));
        float so = 1.f / (1.f + expf(-go));
        c = sf * c + si * tanhf(gg);
        float hh = so * tanhf(c);
        h[t] = hh;
        qh[((size_t)b * QQ + step) * DD + t] = hh;
        __syncthreads();
    }
    qne[(size_t)b * DD + t] = h[t];
}

// ---------------------------------------------------------------------------
// sim -> softmax -> Wt (att eliminated)
// ---------------------------------------------------------------------------
__global__ __launch_bounds__(256) void simwt_k(
    const float* __restrict__ qhid, const int* __restrict__ qtext,
    const float* __restrict__ lfe, float* __restrict__ Wt)
{
    __shared__ float qs[QQ * DD];
    __shared__ float qmn[QQ];
    const int b = blockIdx.y;
    const int f = blockIdx.x * 256 + threadIdx.x;
    for (int i = threadIdx.x; i < QQ * DD; i += 256) qs[i] = qhid[(size_t)b * QQ * DD + i];
    if (threadIdx.x < QQ)
        qmn[threadIdx.x] = (qtext[b * QQ + threadIdx.x] != NWORD) ? 0.f : VNEG;
    __syncthreads();
    if (f >= FF) return;
    float acc[QQ];
    #pragma unroll
    for (int q = 0; q < QQ; ++q) acc[q] = 0.f;
    const float* lr = lfe + ((size_t)b * FF + f) * DD;
    for (int d = 0; d < DD; d += 4) {
        float4 x = *(const float4*)(lr + d);
        #pragma unroll
        for (int q = 0; q < QQ; ++q) {
            float4 y = *(const float4*)&qs[q * DD + d];
            acc[q] += x.x * y.x + x.y * y.y + x.z * y.z + x.w * y.w;
        }
    }
    const float inv = 0.0625f;
    float pre[QQ], m = -INFINITY;
    #pragma unroll
    for (int q = 0; q < QQ; ++q) { pre[q] = acc[q] * inv + qmn[q]; m = fmaxf(m, pre[q]); }
    float s = 0.f;
    #pragma unroll
    for (int q = 0; q < QQ; ++q) s += expf(pre[q] - m);
    float wt = 0.f;
    #pragma unroll
    for (int q = 0; q < QQ; ++q) wt += (expf(pre[q] - m) / s) * (acc[q] * inv);
    Wt[(size_t)b * FF + f] = wt;
}

__global__ void rowmax_k(const float* __restrict__ Wt, float* __restrict__ WtMax)
{
    __shared__ float red[256];
    int b = blockIdx.x;
    float m = -INFINITY;
    for (int f = threadIdx.x; f < FF; f += 256) m = fmaxf(m, Wt[b * FF + f]);
    red[threadIdx.x] = m; __syncthreads();
    for (int s = 128; s > 0; s >>= 1) {
        if (threadIdx.x < s) red[threadIdx.x] = fmaxf(red[threadIdx.x], red[threadIdx.x + s]);
        __syncthreads();
    }
    if (threadIdx.x == 0) WtMax[b] = red[0];
}

__global__ void wtil_k(const float* __restrict__ Wt, const float* __restrict__ WtMax,
                       float* __restrict__ Wtil)
{
    int i = blockIdx.x * 256 + threadIdx.x;
    if (i >= BB * FF) return;
    Wtil[i] = expf(Wt[i] - WtMax[i / FF]);
}

// e2f_softmax: one-shot atomic scalar scatter (dest = entity rows, transposed idx)
__global__ void scatter_sm_k(const int* __restrict__ idx, const float* __restrict__ val,
                             const float* __restrict__ Wtil, float* __restrict__ dst)
{
    int k = blockIdx.x * 256 + threadIdx.x;
    if (k >= NNZ_) return;
    int b = idx[k], e = idx[2 * NNZ_ + k], f = idx[NNZ_ + k];
    atomicAdd(&dst[(size_t)b * EE + e], val[k] * Wtil[(size_t)b * FF + f]);
}

// ---------------------------------------------------------------------------
// matvec + qne update helpers
// ---------------------------------------------------------------------------
__global__ __launch_bounds__(256) void matvec_k(
    const float* __restrict__ x, const float* __restrict__ W, int ldw, int woff,
    const float* __restrict__ bias, float* __restrict__ out)
{
    __shared__ float xs[DD];
    int b = blockIdx.x, j = threadIdx.x;
    xs[j] = x[b * DD + j];
    __syncthreads();
    float acc = bias[j];
    const float* wr = W + (size_t)j * ldw + woff;
    #pragma unroll 4
    for (int k = 0; k < DD; ++k) acc += xs[k] * wr[k];
    out[b * DD + j] = acc;
}

#define VCH 80  // entity rows per vreduce block (25 chunks x 8 batches)
__global__ __launch_bounds__(256) void vreduce_k(
    const float* __restrict__ pr, const float* __restrict__ lee,
    const float* __restrict__ f2e, float* __restrict__ vlee,
    float* __restrict__ vf2e, float* __restrict__ sumpr)
{
    int b = blockIdx.y, ch = blockIdx.x, k = threadIdx.x;
    int e0 = ch * VCH, e1 = e0 + VCH;
    if (e1 > EE) e1 = EE;
    float a1 = 0.f, a2 = 0.f;
    for (int e = e0; e < e1; ++e) {
        float p = pr[b * EE + e];
        a1 += p * lee[((size_t)b * EE + e) * DD + k];
        a2 += p * f2e[((size_t)b * EE + e) * DD + k];
    }
    atomicAdd(&vlee[b * DD + k], a1);
    atomicAdd(&vf2e[b * DD + k], a2);
    float sp = 0.f;
    for (int e = e0 + k; e < e1; e += 256) sp += pr[b * EE + e];
    __shared__ float red[256];
    red[k] = sp; __syncthreads();
    for (int s = 128; s > 0; s >>= 1) {
        if (k < s) red[k] += red[k + s];
        __syncthreads();
    }
    if (k == 0) atomicAdd(&sumpr[b], red[0]);
}

__global__ __launch_bounds__(256) void qneupd_k(
    const float* __restrict__ vlee, const float* __restrict__ vf2e,
    const float* __restrict__ qlin, const float* __restrict__ sumpr,
    const float* __restrict__ W, const float* __restrict__ bias, float* __restrict__ qne)
{
    __shared__ float s1[DD], s2[DD], s3[DD];
    int b = blockIdx.x, j = threadIdx.x;
    s1[j] = vlee[b * DD + j]; s2[j] = qlin[b * DD + j]; s3[j] = vf2e[b * DD + j];
    __syncthreads();
    float sp = sumpr[b];
    float acc = sp * bias[j];
    const float* wr = W + (size_t)j * 768;
    #pragma unroll 4
    for (int k = 0; k < DD; ++k)
        acc += s1[k] * wr[k] + sp * s2[k] * wr[256 + k] + 3.f * s3[k] * wr[512 + k];
    qne[b * DD + j] = acc;
}

__global__ void score_k(const float* __restrict__ lee, const float* __restrict__ sw,
                        const float* __restrict__ sb, float* __restrict__ score)
{
    int r = blockIdx.x * 256 + threadIdx.x;
    if (r >= BB * EE) return;
    float acc = sb[0];
    const float* a = lee + (size_t)r * DD;
    for (int k = 0; k < DD; k += 4) {
        float4 v = *(const float4*)(a + k);
        acc += v.x * sw[k] + v.y * sw[k + 1] + v.z * sw[k + 2] + v.w * sw[k + 3];
    }
    score[r] = acc;
}

__global__ __launch_bounds__(256) void final_k(
    const float* __restrict__ score, const int* __restrict__ local_entity,
    const float* __restrict__ ans, float* __restrict__ out, float* __restrict__ losspart)
{
    int b = blockIdx.x, t = threadIdx.x;
    float lsum = 0.f, bm = -INFINITY;
    int bi = EE;
    for (int e = t; e < EE; e += 256) {
        float s = score[b * EE + e];
        float mask = (local_entity[b * EE + e] != NENT) ? 1.f : 0.f;
        float smv = s + (1.f - mask) * VNEG;
        float sig;
        if (smv >= 0.f) sig = 1.f / (1.f + expf(-smv));
        else { float es = expf(smv); sig = es / (1.f + es); }
        out[1 + BB + b * EE + e] = sig * mask;
        lsum += fmaxf(s, 0.f) - s * ans[b * EE + e] + log1pf(expf(-fabsf(s)));
        if (smv > bm) { bm = smv; bi = e; }
    }
    __shared__ float rv[256]; __shared__ int ri[256]; __shared__ float rl[256];
    rv[t] = bm; ri[t] = bi; rl[t] = lsum;
    __syncthreads();
    for (int s = 128; s > 0; s >>= 1) {
        if (t < s) {
            rl[t] += rl[t + s];
            if (rv[t + s] > rv[t] || (rv[t + s] == rv[t] && ri[t + s] < ri[t])) {
                rv[t] = rv[t + s]; ri[t] = ri[t + s];
            }
        }
        __syncthreads();
    }
    if (t == 0) { losspart[b] = rl[0]; out[1 + b] = (float)ri[0]; }
}

__global__ void loss_k(const float* __restrict__ losspart, float* __restrict__ out)
{
    if (threadIdx.x == 0) {
        float s = 0.f;
        for (int b = 0; b < BB; ++b) s += losspart[b];
        out[0] = s / (float)(BB * EE);
    }
}

// ---------------------------------------------------------------------------
extern "C" void kernel_launch(void* const* d_in, const int* in_sizes, int n_in,
                              void* d_out, int out_size, void* d_ws, size_t ws_size,
                              hipStream_t stream)
{
    (void)in_sizes; (void)n_in; (void)out_size; (void)ws_size;
    const int*   local_entity = (const int*)d_in[0];
    const float* q2e_adj      = (const float*)d_in[1];
    const int*   kb_fact_rel  = (const int*)d_in[2];
    const int*   query_text   = (const int*)d_in[3];
    const float* answer_dist  = (const float*)d_in[4];
    const int*   e2f_idx      = (const int*)d_in[5];
    const float* e2f_val      = (const float*)d_in[6];
    const int*   f2e_idx      = (const int*)d_in[7];
    const float* f2e_val      = (const float*)d_in[8];
    const float* entity_table = (const float*)d_in[9];
    const float* ent_W        = (const float*)d_in[10];
    const float* ent_b        = (const float*)d_in[11];
    const float* rel_table    = (const float*)d_in[12];
    const float* rel_W        = (const float*)d_in[13];
    const float* rel_b        = (const float*)d_in[14];
    const float* word_table   = (const float*)d_in[15];
    const float* Wih          = (const float*)d_in[16];
    const float* Whh          = (const float*)d_in[17];
    const float* bih          = (const float*)d_in[18];
    const float* bhh          = (const float*)d_in[19];
    const float* q2e_W        = (const float*)d_in[20];
    const float* q2e_b        = (const float*)d_in[21];
    const float* e2q_W        = (const float*)d_in[22];
    const float* e2q_b        = (const float*)d_in[23];
    const float* e2e_W        = (const float*)d_in[24];
    const float* e2e_b        = (const float*)d_in[25];
    const float* head_W       = (const float*)d_in[26];
    const float* head_b       = (const float*)d_in[27];
    const float* tail_W       = (const float*)d_in[28];
    const float* tail_b       = (const float*)d_in[29];
    const float* self_W       = (const float*)d_in[30];
    const float* self_b       = (const float*)d_in[31];
    const float* score_W      = (const float*)d_in[32];
    const float* score_b      = (const float*)d_in[33];

    const int NR1 = BB * FF;   // e2f dest rows (48000)
    const int NR2 = BB * EE;   // f2e dest rows (16000)

    float* ws = (float*)d_ws;
    size_t off = 0;
    auto alloc = [&](size_t n) { float* p = ws + off; off += n; return p; };
    float* Xg      = alloc((size_t)BB * QQ * 1024);
    float* WhhT    = alloc((size_t)1024 * DD);
    float* qh      = alloc((size_t)BB * QQ * DD);
    float* qne     = alloc(BB * DD);
    float* lfe     = alloc((size_t)BB * FF * DD);
    float* lee     = alloc((size_t)BB * EE * DD);
    float* lee2    = alloc((size_t)BB * EE * DD);
    float* Wt      = alloc(BB * FF);
    float* WtMax   = alloc(8);
    float* Wtil    = alloc(BB * FF);
    float* e2fsm   = alloc(BB * EE);
    float* pr      = alloc(BB * EE);
    float* qlin    = alloc(BB * DD);
    float* ebias   = alloc(BB * DD);
    float* e2fnrm  = alloc(BB * FF);
    float* vlee    = alloc(BB * DD);
    float* vf2e    = alloc(BB * DD);
    float* sumpr   = alloc(8);
    float* scoreb  = alloc(BB * EE);
    float* losspart= alloc(8);
    float* bufC    = alloc((size_t)BB * FF * DD);
    float* e2fT    = alloc((size_t)BB * FF * DD);
    float* f2eT    = alloc((size_t)BB * EE * DD);
    float* e2f_vp  = alloc(NNZ_);
    float* f2e_vp  = alloc(NNZ_);
    int* ib = (int*)(ws + off);
    size_t ioff = 0;
    auto ialloc = [&](size_t n) { int* p = ib + ioff; ioff += n; return p; };
    int* e2f_rp  = ialloc(NR1 + 1);
    int* e2f_cur = ialloc(NR1);
    int* e2f_col = ialloc(NNZ_);
    int* f2e_rp  = ialloc(NR2 + 1);
    int* f2e_cur = ialloc(NR2);
    int* f2e_col = ialloc(NNZ_);

    float* outp = (float*)d_out;
    const int SCB = (NNZ_ + 255) / 256;

    // ---- CSR builds (e2f: dest F-rows; f2e: dest E-rows) ----
    hipMemsetAsync(e2f_cur, 0, NR1 * sizeof(int), stream);
    csr_count_k<<<SCB, 256, 0, stream>>>(e2f_idx, e2f_cur, FF);
    scan_k<<<1, 1024, 0, stream>>>(e2f_cur, e2f_rp, NR1);
    hipMemcpyAsync(e2f_cur, e2f_rp, NR1 * sizeof(int), hipMemcpyDeviceToDevice, stream);
    csr_fill_k<<<SCB, 256, 0, stream>>>(e2f_idx, e2f_val, e2f_cur, e2f_col, e2f_vp, FF);

    hipMemsetAsync(f2e_cur, 0, NR2 * sizeof(int), stream);
    csr_count_k<<<SCB, 256, 0, stream>>>(f2e_idx, f2e_cur, EE);
    scan_k<<<1, 1024, 0, stream>>>(f2e_cur, f2e_rp, NR2);
    hipMemcpyAsync(f2e_cur, f2e_rp, NR2 * sizeof(int), hipMemcpyDeviceToDevice, stream);
    csr_fill_k<<<SCB, 256, 0, stream>>>(f2e_idx, f2e_val, f2e_cur, f2e_col, f2e_vp, EE);

    // ---- LSTM ----
    gemm_k<1, 0, 0><<<dim3(1024 / 64, (BB * QQ + 63) / 64), 256, 0, stream>>>(
        word_table, query_text, nullptr, Wih, 256, bih, Xg, BB * QQ, 1024, 256);
    transpose_whh_k<<<1024, 256, 0, stream>>>(Whh, WhhT);
    lstm_k<<<BB, 256, 0, stream>>>(Xg, WhhT, bhh, qh, qne);

    // ---- embeddings ----
    gemm_k<1, 0, 0><<<dim3(4, (BB * FF + 63) / 64), 256, 0, stream>>>(
        rel_table, kb_fact_rel, nullptr, rel_W, 256, rel_b, lfe, BB * FF, 256, 256);
    gemm_k<1, 0, 0><<<dim3(4, (BB * EE + 63) / 64), 256, 0, stream>>>(
        entity_table, local_entity, nullptr, ent_W, 256, ent_b, lee, BB * EE, 256, 256);

    // ---- attention -> W_tilde ----
    simwt_k<<<dim3((FF + 255) / 256, BB), 256, 0, stream>>>(qh, query_text, lfe, Wt);
    rowmax_k<<<BB, 256, 0, stream>>>(Wt, WtMax);
    wtil_k<<<(BB * FF + 255) / 256, 256, 0, stream>>>(Wt, WtMax, Wtil);

    // ---- e2f_softmax (one-shot) ----
    hipMemsetAsync(e2fsm, 0, BB * EE * sizeof(float), stream);
    scatter_sm_k<<<SCB, 256, 0, stream>>>(e2f_idx, e2f_val, Wtil, e2fsm);

    // ---- pagerank init ----
    hipMemcpyAsync(pr, q2e_adj, BB * EE * sizeof(float), hipMemcpyDeviceToDevice, stream);

    for (int i = 0; i < 3; ++i) {
        const float* q2eWi  = q2e_W  + (size_t)i * DD * DD;
        const float* q2ebi  = q2e_b  + i * DD;
        const float* e2qWi  = e2q_W  + (size_t)i * DD * 3 * DD;
        const float* e2qbi  = e2q_b  + i * DD;
        const float* e2eWi  = e2e_W  + (size_t)i * DD * 3 * DD;
        const float* e2ebi  = e2e_b  + i * DD;
        const float* headWi = head_W + (size_t)i * DD * DD;
        const float* headbi = head_b + i * DD;
        const float* tailWi = tail_W + (size_t)i * DD * DD;
        const float* tailbi = tail_b + i * DD;
        const float* selfWi = self_W + (size_t)i * DD * DD;
        const float* selfbi = self_b + i * DD;

        matvec_k<<<BB, 256, 0, stream>>>(qne, q2eWi, 256, 0, q2ebi, qlin);

        // e2f_norm (gather; div fused per-edge)
        gather_norm_k<<<(NR1 + 255) / 256, 256, 0, stream>>>(
            e2f_rp, e2f_col, e2f_vp, pr, e2fsm, Wtil, e2fnrm, NR1);

        // e2f_emb = relu(self(lfe) + gather(head(lee))) * e2f_norm
        gemm_k<0, 0, 0><<<dim3(4, (BB * EE + 63) / 64), 256, 0, stream>>>(
            lee, nullptr, nullptr, headWi, 256, headbi, bufC, BB * EE, 256, 256);
        gemm_k<0, 0, 0><<<dim3(4, (BB * FF + 63) / 64), 256, 0, stream>>>(
            lfe, nullptr, nullptr, selfWi, 256, selfbi, e2fT, BB * FF, 256, 256);
        gather_rows_k<1><<<(NR1 * 64 + 255) / 256, 256, 0, stream>>>(
            e2f_rp, e2f_col, e2f_vp, bufC, e2fnrm, e2fT, NR1, FF, EE);

        // f2e_emb = relu(self(lee) + gather(tail(e2f_emb)))
        gemm_k<0, 0, 0><<<dim3(4, (BB * FF + 63) / 64), 256, 0, stream>>>(
            e2fT, nullptr, nullptr, tailWi, 256, tailbi, bufC, BB * FF, 256, 256);
        gemm_k<0, 0, 0><<<dim3(4, (BB * EE + 63) / 64), 256, 0, stream>>>(
            lee, nullptr, nullptr, selfWi, 256, selfbi, f2eT, BB * EE, 256, 256);
        gather_rows_k<0><<<(NR2 * 64 + 255) / 256, 256, 0, stream>>>(
            f2e_rp, f2e_col, f2e_vp, bufC, nullptr, f2eT, NR2, EE, FF);

        // pagerank update (gather, fused 0.8/0.2 blend)
        gather_pr_k<<<(NR2 + 255) / 256, 256, 0, stream>>>(
            f2e_rp, f2e_col, f2e_vp, e2fnrm, pr, NR2);

        // query_node_emb update
        hipMemsetAsync(vlee, 0, BB * DD * sizeof(float), stream);
        hipMemsetAsync(vf2e, 0, BB * DD * sizeof(float), stream);
        hipMemsetAsync(sumpr, 0, 8 * sizeof(float), stream);
        vreduce_k<<<dim3((EE + VCH - 1) / VCH, BB), 256, 0, stream>>>(
            pr, lee, f2eT, vlee, vf2e, sumpr);
        qneupd_k<<<BB, 256, 0, stream>>>(vlee, vf2e, qlin, sumpr, e2qWi, e2qbi, qne);

        // local_entity_emb = relu(e2e(nxt)), q2e block folded into ebias
        matvec_k<<<BB, 256, 0, stream>>>(qlin, e2eWi, 768, 256, e2ebi, ebias);
        gemm_k<0, 1, 1><<<dim3(4, (BB * EE + 63) / 64), 256, 0, stream>>>(
            lee, nullptr, f2eT, e2eWi, 768, ebias, lee2, BB * EE, 256, 512);
        { float* t = lee; lee = lee2; lee2 = t; }
    }

    score_k<<<(BB * EE + 255) / 256, 256, 0, stream>>>(lee, score_W, score_b, scoreb);
    final_k<<<BB, 256, 0, stream>>>(scoreb, local_entity, answer_dist, outp, losspart);
    loss_k<<<1, 64, 0, stream>>>(losspart, outp);
}

// Round 4
// 1761.774 us; speedup vs baseline: 2.4943x; 1.0954x over previous
//
#include <hip/hip_runtime.h>
#include <math.h>

#define BB 8
#define EE 2000
#define FF 6000
#define QQ 20
#define DD 256
#define NENT 400000
#define NWORD 60000
#define NNZ_ 96000
#define VNEG  (-1e11f)
#define VSMALL 1e-10f

// ---------------------------------------------------------------------------
// 128x128-tile fp32 GEMM, 256 threads, 8x8 per thread, K chunks of 16,
// register prefetch. out[r,c] = act( A(r,:)*W(c,:)^T + bias(r,c) ).
//   GATHER: A1 row via idx[r] (table ld 256)
//   DUALW : K=512: first 256 from A1/W1, second 256 from sA2*A2/W2
//   RS    : bias += rowscale[r]*bias2[c]
//   biasA : indexed biasA[(r/rowsPerB)*N + c]
// ---------------------------------------------------------------------------
template<int GATHER, int DUALW, int RELU, int RS>
__global__ __launch_bounds__(256) void gemm2_k(
    const float* __restrict__ A1, const int* __restrict__ idx,
    const float* __restrict__ A2, float sA2,
    const float* __restrict__ W1, int ldw1,
    const float* __restrict__ W2, int ldw2,
    const float* __restrict__ biasA, int rowsPerB,
    const float* __restrict__ rowscale, const float* __restrict__ bias2,
    float* __restrict__ out, int M, int N)
{
    __shared__ float As[16][132];
    __shared__ float Bs[16][132];
    const int tid = threadIdx.x;
    const int row0 = blockIdx.y * 128, col0 = blockIdx.x * 128;
    const int tx = tid & 15, ty = tid >> 4;
    const int srow = tid >> 1, sk = (tid & 1) << 3;
    const int gr = row0 + srow;
    const bool rvalid = (gr < M);
    const float* aRow1 = nullptr;
    if (rvalid) aRow1 = GATHER ? A1 + (size_t)idx[gr] * 256 : A1 + (size_t)gr * 256;
    const float* aRow2 = (DUALW && rvalid) ? A2 + (size_t)gr * 256 : nullptr;
    const float* wR1 = W1 + (size_t)(col0 + srow) * ldw1;
    const float* wR2 = DUALW ? W2 + (size_t)(col0 + srow) * ldw2 : nullptr;

    float acc[8][8];
    #pragma unroll
    for (int i = 0; i < 8; ++i)
        #pragma unroll
        for (int j = 0; j < 8; ++j) acc[i][j] = 0.f;

    const int nch = DUALW ? 32 : 16;
    float4 a0, a1, b0, b1;
    auto fetch = [&](int ch) {
        const int k0 = ((ch & 15) << 4) + sk;
        const bool hi = DUALW && (ch >= 16);
        const float* ar = hi ? aRow2 : aRow1;
        const float* wr = hi ? wR2 : wR1;
        if (rvalid) {
            a0 = *(const float4*)(ar + k0);
            a1 = *(const float4*)(ar + k0 + 4);
        } else {
            a0 = make_float4(0.f, 0.f, 0.f, 0.f);
            a1 = make_float4(0.f, 0.f, 0.f, 0.f);
        }
        b0 = *(const float4*)(wr + k0);
        b1 = *(const float4*)(wr + k0 + 4);
    };

    fetch(0);
    for (int ch = 0; ch < nch; ++ch) {
        const float s = (DUALW && ch >= 16) ? sA2 : 1.f;
        As[sk + 0][srow] = a0.x * s; As[sk + 1][srow] = a0.y * s;
        As[sk + 2][srow] = a0.z * s; As[sk + 3][srow] = a0.w * s;
        As[sk + 4][srow] = a1.x * s; As[sk + 5][srow] = a1.y * s;
        As[sk + 6][srow] = a1.z * s; As[sk + 7][srow] = a1.w * s;
        Bs[sk + 0][srow] = b0.x; Bs[sk + 1][srow] = b0.y;
        Bs[sk + 2][srow] = b0.z; Bs[sk + 3][srow] = b0.w;
        Bs[sk + 4][srow] = b1.x; Bs[sk + 5][srow] = b1.y;
        Bs[sk + 6][srow] = b1.z; Bs[sk + 7][srow] = b1.w;
        __syncthreads();
        if (ch + 1 < nch) fetch(ch + 1);   // prefetch next chunk under compute
        #pragma unroll
        for (int kk = 0; kk < 16; ++kk) {
            float av_[8], bv_[8];
            *(float4*)&av_[0] = *(const float4*)&As[kk][ty << 2];
            *(float4*)&av_[4] = *(const float4*)&As[kk][(ty << 2) + 64];
            *(float4*)&bv_[0] = *(const float4*)&Bs[kk][tx << 2];
            *(float4*)&bv_[4] = *(const float4*)&Bs[kk][(tx << 2) + 64];
            #pragma unroll
            for (int i = 0; i < 8; ++i)
                #pragma unroll
                for (int j = 0; j < 8; ++j) acc[i][j] += av_[i] * bv_[j];
        }
        __syncthreads();
    }

    #pragma unroll
    for (int i = 0; i < 8; ++i) {
        int r = row0 + ((i >> 2) << 6) + (ty << 2) + (i & 3);
        if (r >= M) continue;
        const float* bA = biasA + (size_t)(r / rowsPerB) * N;
        const float rs = RS ? rowscale[r] : 0.f;
        float* orow = out + (size_t)r * N;
        #pragma unroll
        for (int jh = 0; jh < 2; ++jh) {
            const int c = col0 + (jh << 6) + (tx << 2);
            float4 v;
            v.x = acc[i][jh * 4 + 0] + bA[c + 0];
            v.y = acc[i][jh * 4 + 1] + bA[c + 1];
            v.z = acc[i][jh * 4 + 2] + bA[c + 2];
            v.w = acc[i][jh * 4 + 3] + bA[c + 3];
            if (RS) {
                v.x += rs * bias2[c + 0]; v.y += rs * bias2[c + 1];
                v.z += rs * bias2[c + 2]; v.w += rs * bias2[c + 3];
            }
            if (RELU) {
                v.x = fmaxf(v.x, 0.f); v.y = fmaxf(v.y, 0.f);
                v.z = fmaxf(v.z, 0.f); v.w = fmaxf(v.w, 0.f);
            }
            *(float4*)(orow + c) = v;
        }
    }
}

// ---------------------------------------------------------------------------
// CSR build
// ---------------------------------------------------------------------------
__global__ void csr_count_k(const int* __restrict__ idx, int* __restrict__ cnt, int nrPerB)
{
    int k = blockIdx.x * 256 + threadIdx.x;
    if (k >= NNZ_) return;
    atomicAdd(&cnt[idx[k] * nrPerB + idx[NNZ_ + k]], 1);
}

// one launch scans both CSR count arrays (blockIdx picks), writes rowptr+cur
__global__ __launch_bounds__(1024) void scan2_k(
    const int* __restrict__ cntA, int* __restrict__ rpA, int* __restrict__ curA, int nA,
    const int* __restrict__ cntB, int* __restrict__ rpB, int* __restrict__ curB, int nB)
{
    const int* cnt = blockIdx.x ? cntB : cntA;
    int* rp  = blockIdx.x ? rpB  : rpA;
    int* cur = blockIdx.x ? curB : curA;
    int n    = blockIdx.x ? nB   : nA;
    __shared__ int sums[1024];
    int t = threadIdx.x;
    int chunk = (n + 1023) / 1024;
    int lo = t * chunk, hi = lo + chunk;
    if (lo > n) lo = n;
    if (hi > n) hi = n;
    int s = 0;
    for (int i = lo; i < hi; ++i) s += cnt[i];
    sums[t] = s;
    __syncthreads();
    for (int off = 1; off < 1024; off <<= 1) {
        int v = (t >= off) ? sums[t - off] : 0;
        __syncthreads();
        sums[t] += v;
        __syncthreads();
    }
    int run = (t == 0) ? 0 : sums[t - 1];
    for (int i = lo; i < hi; ++i) { rp[i] = run; cur[i] = run; run += cnt[i]; }
    if (hi == n) rp[n] = run;
}

__global__ void csr_fill_k(const int* __restrict__ idx, const float* __restrict__ val,
                           int* __restrict__ cur, int* __restrict__ col,
                           float* __restrict__ valp, int nrPerB)
{
    int k = blockIdx.x * 256 + threadIdx.x;
    if (k >= NNZ_) return;
    int row = idx[k] * nrPerB + idx[NNZ_ + k];
    int p = atomicAdd(&cur[row], 1);
    col[p] = idx[2 * NNZ_ + k];
    valp[p] = val[k];
}

__global__ void degw_k(const int* __restrict__ rp, const float* __restrict__ vp,
                       float* __restrict__ degw, int n)
{
    int r = blockIdx.x * 256 + threadIdx.x;
    if (r >= n) return;
    float s = 0.f;
    for (int j = rp[r]; j < rp[r + 1]; ++j) s += vp[j];
    degw[r] = s;
}

// ---------------------------------------------------------------------------
// Row gathers (CSR, one wave per dest row)
// ---------------------------------------------------------------------------
// dst[row] = relu(dst[row] + sum val*src[b,c]) * nrm[row]
__global__ __launch_bounds__(256) void gather_relu_nrm_k(
    const int* __restrict__ rowptr, const int* __restrict__ col,
    const float* __restrict__ valp, const float* __restrict__ src,
    const float* __restrict__ nrm, float* __restrict__ dst, int nrows,
    int nrPerB, int ncs)
{
    int gid = blockIdx.x * 256 + threadIdx.x;
    int row = gid >> 6, lane = gid & 63;
    if (row >= nrows) return;
    int b = row / nrPerB;
    float4* dp = (float4*)(dst + (size_t)row * DD + (lane << 2));
    float4 acc = *dp;
    int j0 = rowptr[row], j1 = rowptr[row + 1];
    for (int j = j0; j < j1; ++j) {
        int c = col[j];
        float v = valp[j];
        float4 x = *(const float4*)(src + ((size_t)b * ncs + c) * DD + (lane << 2));
        acc.x += v * x.x; acc.y += v * x.y; acc.z += v * x.z; acc.w += v * x.w;
    }
    float s = nrm[row];
    acc.x = fmaxf(acc.x, 0.f) * s; acc.y = fmaxf(acc.y, 0.f) * s;
    acc.z = fmaxf(acc.z, 0.f) * s; acc.w = fmaxf(acc.w, 0.f) * s;
    *dp = acc;
}

// dst[row] = sum val*src[b,c]   (pure gather, no init)
__global__ __launch_bounds__(256) void gather_sum_k(
    const int* __restrict__ rowptr, const int* __restrict__ col,
    const float* __restrict__ valp, const float* __restrict__ src,
    float* __restrict__ dst, int nrows, int nrPerB, int ncs)
{
    int gid = blockIdx.x * 256 + threadIdx.x;
    int row = gid >> 6, lane = gid & 63;
    if (row >= nrows) return;
    int b = row / nrPerB;
    float4 acc = make_float4(0.f, 0.f, 0.f, 0.f);
    int j0 = rowptr[row], j1 = rowptr[row + 1];
    for (int j = j0; j < j1; ++j) {
        int c = col[j];
        float v = valp[j];
        float4 x = *(const float4*)(src + ((size_t)b * ncs + c) * DD + (lane << 2));
        acc.x += v * x.x; acc.y += v * x.y; acc.z += v * x.z; acc.w += v * x.w;
    }
    *(float4*)(dst + (size_t)row * DD + (lane << 2)) = acc;
}

// e2fnrm[b,f] = Wtil[b,f] * sum val * pr[b,c]/max(sm[b,c],eps)
__global__ void gather_norm_k(const int* __restrict__ rowptr, const int* __restrict__ col,
                              const float* __restrict__ valp, const float* __restrict__ pr,
                              const float* __restrict__ sm, const float* __restrict__ Wtil,
                              float* __restrict__ e2fnrm, int nrows)
{
    int row = blockIdx.x * 256 + threadIdx.x;
    if (row >= nrows) return;
    int b = row / FF;
    float s = 0.f;
    for (int j = rowptr[row]; j < rowptr[row + 1]; ++j) {
        int c = col[j];
        s += valp[j] * (pr[(size_t)b * EE + c] / fmaxf(sm[(size_t)b * EE + c], VSMALL));
    }
    e2fnrm[row] = Wtil[row] * s;
}

// pr[b,e] = 0.8 * sum val*e2fnrm[b,c] + 0.2*pr[b,e]
__global__ void gather_pr_k(const int* __restrict__ rowptr, const int* __restrict__ col,
                            const float* __restrict__ valp, const float* __restrict__ e2fnrm,
                            float* __restrict__ pr, int nrows)
{
    int row = blockIdx.x * 256 + threadIdx.x;
    if (row >= nrows) return;
    int b = row / EE;
    float s = 0.f;
    for (int j = rowptr[row]; j < rowptr[row + 1]; ++j)
        s += valp[j] * e2fnrm[(size_t)b * FF + col[j]];
    pr[row] = 0.8f * s + 0.2f * pr[row];
}

// ---------------------------------------------------------------------------
// LSTM
// ---------------------------------------------------------------------------
__global__ void transpose_whh_k(const float* __restrict__ Whh, float* __restrict__ WhhT)
{
    int i = blockIdx.x * 256 + threadIdx.x;
    int k = i >> 10, j = i & 1023;
    WhhT[i] = Whh[(size_t)j * 256 + k];
}

__global__ __launch_bounds__(256) void lstm_k(
    const float* __restrict__ Xg, const float* __restrict__ WhhT,
    const float* __restrict__ bhh, float* __restrict__ qh, float* __restrict__ qne)
{
    __shared__ float h[DD];
    __shared__ float gs[4 * DD];
    const int b = blockIdx.x, t = threadIdx.x;
    h[t] = 0.f;
    float c = 0.f;
    const float4 bb4 = *(const float4*)(bhh + 4 * t);
    const float4* wt4 = (const float4*)WhhT + t;
    __syncthreads();
    for (int step = 0; step < QQ; ++step) {
        float a0 = 0.f, a1 = 0.f, a2 = 0.f, a3 = 0.f;
        #pragma unroll 16
        for (int k = 0; k < DD; ++k) {
            float4 w = wt4[k * 256];
            float hk = h[k];
            a0 += w.x * hk; a1 += w.y * hk; a2 += w.z * hk; a3 += w.w * hk;
        }
        float4 xg = *(const float4*)(Xg + ((size_t)b * QQ + step) * 1024 + 4 * t);
        float4 g4 = make_float4(a0 + xg.x + bb4.x, a1 + xg.y + bb4.y,
                                a2 + xg.z + bb4.z, a3 + xg.w + bb4.w);
        *(float4*)(gs + 4 * t) = g4;
        __syncthreads();
        float gi = gs[t], gf = gs[DD + t], gg = gs[2 * DD + t], go = gs[3 * DD + t];
        float si = 1.f / (1.f + expf(-gi));
        float sf = 1.f / (1.f + expf(-gf));
        float so = 1.f / (1.f + expf(-go));
        c = sf * c + si * tanhf(gg);
        float hh = so * tanhf(c);
        h[t] = hh;
        qh[((size_t)b * QQ + step) * DD + t] = hh;
        __syncthreads();
    }
    qne[(size_t)b * DD + t] = h[t];
}

// ---------------------------------------------------------------------------
// sim -> softmax -> Wt
// ---------------------------------------------------------------------------
__global__ __launch_bounds__(256) void simwt_k(
    const float* __restrict__ qhid, const int* __restrict__ qtext,
    const float* __restrict__ lfe, float* __restrict__ Wt)
{
    __shared__ float qs[QQ * DD];
    __shared__ float qmn[QQ];
    const int b = blockIdx.y;
    const int f = blockIdx.x * 256 + threadIdx.x;
    for (int i = threadIdx.x; i < QQ * DD; i += 256) qs[i] = qhid[(size_t)b * QQ * DD + i];
    if (threadIdx.x < QQ)
        qmn[threadIdx.x] = (qtext[b * QQ + threadIdx.x] != NWORD) ? 0.f : VNEG;
    __syncthreads();
    if (f >= FF) return;
    float acc[QQ];
    #pragma unroll
    for (int q = 0; q < QQ; ++q) acc[q] = 0.f;
    const float* lr = lfe + ((size_t)b * FF + f) * DD;
    for (int d = 0; d < DD; d += 4) {
        float4 x = *(const float4*)(lr + d);
        #pragma unroll
        for (int q = 0; q < QQ; ++q) {
            float4 y = *(const float4*)&qs[q * DD + d];
            acc[q] += x.x * y.x + x.y * y.y + x.z * y.z + x.w * y.w;
        }
    }
    const float inv = 0.0625f;
    float pre[QQ], m = -INFINITY;
    #pragma unroll
    for (int q = 0; q < QQ; ++q) { pre[q] = acc[q] * inv + qmn[q]; m = fmaxf(m, pre[q]); }
    float s = 0.f;
    #pragma unroll
    for (int q = 0; q < QQ; ++q) s += expf(pre[q] - m);
    float wt = 0.f;
    #pragma unroll
    for (int q = 0; q < QQ; ++q) wt += (expf(pre[q] - m) / s) * (acc[q] * inv);
    Wt[(size_t)b * FF + f] = wt;
}

__global__ void rowmax_k(const float* __restrict__ Wt, float* __restrict__ WtMax)
{
    __shared__ float red[256];
    int b = blockIdx.x;
    float m = -INFINITY;
    for (int f = threadIdx.x; f < FF; f += 256) m = fmaxf(m, Wt[b * FF + f]);
    red[threadIdx.x] = m; __syncthreads();
    for (int s = 128; s > 0; s >>= 1) {
        if (threadIdx.x < s) red[threadIdx.x] = fmaxf(red[threadIdx.x], red[threadIdx.x + s]);
        __syncthreads();
    }
    if (threadIdx.x == 0) WtMax[b] = red[0];
}

__global__ void wtil_k(const float* __restrict__ Wt, const float* __restrict__ WtMax,
                       float* __restrict__ Wtil)
{
    int i = blockIdx.x * 256 + threadIdx.x;
    if (i >= BB * FF) return;
    Wtil[i] = expf(Wt[i] - WtMax[i / FF]);
}

__global__ void scatter_sm_k(const int* __restrict__ idx, const float* __restrict__ val,
                             const float* __restrict__ Wtil, float* __restrict__ dst)
{
    int k = blockIdx.x * 256 + threadIdx.x;
    if (k >= NNZ_) return;
    int b = idx[k], e = idx[2 * NNZ_ + k], f = idx[NNZ_ + k];
    atomicAdd(&dst[(size_t)b * EE + e], val[k] * Wtil[(size_t)b * FF + f]);
}

// ---------------------------------------------------------------------------
// fused qlin + ebias matvecs (per batch)
// ---------------------------------------------------------------------------
__global__ __launch_bounds__(256) void qlin_ebias_k(
    const float* __restrict__ qne, const float* __restrict__ q2eW,
    const float* __restrict__ q2eb, const float* __restrict__ e2eW,
    const float* __restrict__ e2eb, float* __restrict__ qlin, float* __restrict__ ebias)
{
    __shared__ float xs[DD], qs[DD];
    int b = blockIdx.x, j = threadIdx.x;
    xs[j] = qne[b * DD + j];
    __syncthreads();
    float acc = q2eb[j];
    const float* wr = q2eW + (size_t)j * DD;
    #pragma unroll 4
    for (int k = 0; k < DD; ++k) acc += xs[k] * wr[k];
    qlin[b * DD + j] = acc;
    qs[j] = acc;
    __syncthreads();
    float acc2 = e2eb[j];
    const float* wr2 = e2eW + (size_t)j * 768 + 256;
    #pragma unroll 4
    for (int k = 0; k < DD; ++k) acc2 += qs[k] * wr2[k];
    ebias[b * DD + j] = acc2;
}

// ---------------------------------------------------------------------------
// vreduce (partials, no atomics) + qneupd
// ---------------------------------------------------------------------------
#define VCH 80
#define NCHK ((EE + VCH - 1) / VCH)   // 25
__global__ __launch_bounds__(256) void vreduce_k(
    const float* __restrict__ pr, const float* __restrict__ lee,
    const float* __restrict__ f2e, float* __restrict__ vpartL,
    float* __restrict__ vpartF, float* __restrict__ vpartS)
{
    int b = blockIdx.y, ch = blockIdx.x, k = threadIdx.x;
    int e0 = ch * VCH, e1 = e0 + VCH;
    if (e1 > EE) e1 = EE;
    float a1 = 0.f, a2 = 0.f;
    for (int e = e0; e < e1; ++e) {
        float p = pr[b * EE + e];
        a1 += p * lee[((size_t)b * EE + e) * DD + k];
        a2 += p * f2e[((size_t)b * EE + e) * DD + k];
    }
    int pi = ch * BB + b;
    vpartL[(size_t)pi * DD + k] = a1;
    vpartF[(size_t)pi * DD + k] = a2;
    float sp = 0.f;
    for (int e = e0 + k; e < e1; e += 256) sp += pr[b * EE + e];
    __shared__ float red[256];
    red[k] = sp; __syncthreads();
    for (int s = 128; s > 0; s >>= 1) {
        if (k < s) red[k] += red[k + s];
        __syncthreads();
    }
    if (k == 0) vpartS[pi] = red[0];
}

__global__ __launch_bounds__(256) void qneupd_k(
    const float* __restrict__ vpartL, const float* __restrict__ vpartF,
    const float* __restrict__ vpartS, const float* __restrict__ qlin,
    const float* __restrict__ W, const float* __restrict__ bias, float* __restrict__ qne)
{
    __shared__ float s1[DD], s2[DD], s3[DD];
    int b = blockIdx.x, j = threadIdx.x;
    float a1 = 0.f, a3 = 0.f, sp = 0.f;
    for (int ch = 0; ch < NCHK; ++ch) {
        int pi = ch * BB + b;
        a1 += vpartL[(size_t)pi * DD + j];
        a3 += vpartF[(size_t)pi * DD + j];
        sp += vpartS[pi];
    }
    s1[j] = a1; s2[j] = qlin[b * DD + j]; s3[j] = a3;
    __syncthreads();
    float acc = sp * bias[j];
    const float* wr = W + (size_t)j * 768;
    #pragma unroll 4
    for (int k = 0; k < DD; ++k)
        acc += s1[k] * wr[k] + sp * s2[k] * wr[256 + k] + 3.f * s3[k] * wr[512 + k];
    qne[b * DD + j] = acc;
}

// ---------------------------------------------------------------------------
// epilogue
// ---------------------------------------------------------------------------
__global__ void score_k(const float* __restrict__ lee, const float* __restrict__ sw,
                        const float* __restrict__ sb, float* __restrict__ score)
{
    int r = blockIdx.x * 256 + threadIdx.x;
    if (r >= BB * EE) return;
    float acc = sb[0];
    const float* a = lee + (size_t)r * DD;
    for (int k = 0; k < DD; k += 4) {
        float4 v = *(const float4*)(a + k);
        acc += v.x * sw[k] + v.y * sw[k + 1] + v.z * sw[k + 2] + v.w * sw[k + 3];
    }
    score[r] = acc;
}

__global__ __launch_bounds__(256) void final_k(
    const float* __restrict__ score, const int* __restrict__ local_entity,
    const float* __restrict__ ans, float* __restrict__ out, float* __restrict__ losspart)
{
    int b = blockIdx.x, t = threadIdx.x;
    float lsum = 0.f, bm = -INFINITY;
    int bi = EE;
    for (int e = t; e < EE; e += 256) {
        float s = score[b * EE + e];
        float mask = (local_entity[b * EE + e] != NENT) ? 1.f : 0.f;
        float smv = s + (1.f - mask) * VNEG;
        float sig;
        if (smv >= 0.f) sig = 1.f / (1.f + expf(-smv));
        else { float es = expf(smv); sig = es / (1.f + es); }
        out[1 + BB + b * EE + e] = sig * mask;
        lsum += fmaxf(s, 0.f) - s * ans[b * EE + e] + log1pf(expf(-fabsf(s)));
        if (smv > bm) { bm = smv; bi = e; }
    }
    __shared__ float rv[256]; __shared__ int ri[256]; __shared__ float rl[256];
    rv[t] = bm; ri[t] = bi; rl[t] = lsum;
    __syncthreads();
    for (int s = 128; s > 0; s >>= 1) {
        if (t < s) {
            rl[t] += rl[t + s];
            if (rv[t + s] > rv[t] || (rv[t + s] == rv[t] && ri[t + s] < ri[t])) {
                rv[t] = rv[t + s]; ri[t] = ri[t + s];
            }
        }
        __syncthreads();
    }
    if (t == 0) { losspart[b] = rl[0]; out[1 + b] = (float)ri[0]; }
}

__global__ void loss_k(const float* __restrict__ losspart, float* __restrict__ out)
{
    if (threadIdx.x == 0) {
        float s = 0.f;
        for (int b = 0; b < BB; ++b) s += losspart[b];
        out[0] = s / (float)(BB * EE);
    }
}

// ---------------------------------------------------------------------------
extern "C" void kernel_launch(void* const* d_in, const int* in_sizes, int n_in,
                              void* d_out, int out_size, void* d_ws, size_t ws_size,
                              hipStream_t stream)
{
    (void)in_sizes; (void)n_in; (void)out_size; (void)ws_size;
    const int*   local_entity = (const int*)d_in[0];
    const float* q2e_adj      = (const float*)d_in[1];
    const int*   kb_fact_rel  = (const int*)d_in[2];
    const int*   query_text   = (const int*)d_in[3];
    const float* answer_dist  = (const float*)d_in[4];
    const int*   e2f_idx      = (const int*)d_in[5];
    const float* e2f_val      = (const float*)d_in[6];
    const int*   f2e_idx      = (const int*)d_in[7];
    const float* f2e_val      = (const float*)d_in[8];
    const float* entity_table = (const float*)d_in[9];
    const float* ent_W        = (const float*)d_in[10];
    const float* ent_b        = (const float*)d_in[11];
    const float* rel_table    = (const float*)d_in[12];
    const float* rel_W        = (const float*)d_in[13];
    const float* rel_b        = (const float*)d_in[14];
    const float* word_table   = (const float*)d_in[15];
    const float* Wih          = (const float*)d_in[16];
    const float* Whh          = (const float*)d_in[17];
    const float* bih          = (const float*)d_in[18];
    const float* bhh          = (const float*)d_in[19];
    const float* q2e_W        = (const float*)d_in[20];
    const float* q2e_b        = (const float*)d_in[21];
    const float* e2q_W        = (const float*)d_in[22];
    const float* e2q_b        = (const float*)d_in[23];
    const float* e2e_W        = (const float*)d_in[24];
    const float* e2e_b        = (const float*)d_in[25];
    const float* head_W       = (const float*)d_in[26];
    const float* head_b       = (const float*)d_in[27];
    const float* tail_W       = (const float*)d_in[28];
    const float* tail_b       = (const float*)d_in[29];
    const float* self_W       = (const float*)d_in[30];
    const float* self_b       = (const float*)d_in[31];
    const float* score_W      = (const float*)d_in[32];
    const float* score_b      = (const float*)d_in[33];

    const int NR1 = BB * FF;   // 48000 (e2f dest rows)
    const int NR2 = BB * EE;   // 16000 (f2e dest rows)

    float* ws = (float*)d_ws;
    size_t off = 0;
    auto alloc = [&](size_t n) { float* p = ws + off; off += n; return p; };
    float* Xg      = alloc((size_t)BB * QQ * 1024);
    float* WhhT    = alloc((size_t)1024 * DD);
    float* qh      = alloc((size_t)BB * QQ * DD);
    float* qne     = alloc(BB * DD);
    float* lfe     = alloc((size_t)BB * FF * DD);
    float* lee     = alloc((size_t)BB * EE * DD);
    float* lee2    = alloc((size_t)BB * EE * DD);
    float* Wt      = alloc(BB * FF);
    float* WtMax   = alloc(8);
    float* Wtil    = alloc(BB * FF);
    float* e2fsm   = alloc(BB * EE);
    float* pr      = alloc(BB * EE);
    float* qlin    = alloc(BB * DD);
    float* ebias   = alloc(BB * DD);
    float* e2fnrm  = alloc(BB * FF);
    float* scoreb  = alloc(BB * EE);
    float* losspart= alloc(8);
    float* bufC    = alloc((size_t)BB * EE * DD);   // head(lee), 16000 rows
    float* e2fT    = alloc((size_t)BB * FF * DD);   // e2f_emb (48000 rows)
    float* f2eT    = alloc((size_t)BB * EE * DD);   // f2e_emb
    float* tmp     = alloc((size_t)BB * EE * DD);   // gather_f2e(e2fT)
    float* vpartL  = alloc((size_t)NCHK * BB * DD);
    float* vpartF  = alloc((size_t)NCHK * BB * DD);
    float* vpartS  = alloc(NCHK * BB);
    float* degw2   = alloc(NR2);
    float* e2f_vp  = alloc(NNZ_);
    float* f2e_vp  = alloc(NNZ_);
    int* ib = (int*)(ws + off);
    size_t ioff = 0;
    auto ialloc = [&](size_t n) { int* p = ib + ioff; ioff += n; return p; };
    int* e2f_cnt = ialloc(NR1);
    int* e2f_rp  = ialloc(NR1 + 1);
    int* e2f_cur = ialloc(NR1);
    int* e2f_col = ialloc(NNZ_);
    int* f2e_cnt = ialloc(NR2);
    int* f2e_rp  = ialloc(NR2 + 1);
    int* f2e_cur = ialloc(NR2);
    int* f2e_col = ialloc(NNZ_);

    float* outp = (float*)d_out;
    const int SCB = (NNZ_ + 255) / 256;
    const float f0 = 0.f;
    (void)f0;

    // ---- CSR builds ----
    hipMemsetAsync(e2f_cnt, 0, NR1 * sizeof(int), stream);
    hipMemsetAsync(f2e_cnt, 0, NR2 * sizeof(int), stream);
    csr_count_k<<<SCB, 256, 0, stream>>>(e2f_idx, e2f_cnt, FF);
    csr_count_k<<<SCB, 256, 0, stream>>>(f2e_idx, f2e_cnt, EE);
    scan2_k<<<2, 1024, 0, stream>>>(e2f_cnt, e2f_rp, e2f_cur, NR1,
                                    f2e_cnt, f2e_rp, f2e_cur, NR2);
    csr_fill_k<<<SCB, 256, 0, stream>>>(e2f_idx, e2f_val, e2f_cur, e2f_col, e2f_vp, FF);
    csr_fill_k<<<SCB, 256, 0, stream>>>(f2e_idx, f2e_val, f2e_cur, f2e_col, f2e_vp, EE);
    degw_k<<<(NR2 + 255) / 256, 256, 0, stream>>>(f2e_rp, f2e_vp, degw2, NR2);

    // ---- LSTM ----
    gemm2_k<1, 0, 0, 0><<<dim3(8, 2), 256, 0, stream>>>(
        word_table, query_text, nullptr, 1.f, Wih, 256, nullptr, 0,
        bih, BB * QQ, nullptr, nullptr, Xg, BB * QQ, 1024);
    transpose_whh_k<<<1024, 256, 0, stream>>>(Whh, WhhT);
    lstm_k<<<BB, 256, 0, stream>>>(Xg, WhhT, bhh, qh, qne);

    // ---- embeddings ----
    gemm2_k<1, 0, 0, 0><<<dim3(2, 375), 256, 0, stream>>>(
        rel_table, kb_fact_rel, nullptr, 1.f, rel_W, 256, nullptr, 0,
        rel_b, NR1, nullptr, nullptr, lfe, NR1, 256);
    gemm2_k<1, 0, 0, 0><<<dim3(2, 125), 256, 0, stream>>>(
        entity_table, local_entity, nullptr, 1.f, ent_W, 256, nullptr, 0,
        ent_b, NR2, nullptr, nullptr, lee, NR2, 256);

    // ---- attention -> W_tilde ----
    simwt_k<<<dim3((FF + 255) / 256, BB), 256, 0, stream>>>(qh, query_text, lfe, Wt);
    rowmax_k<<<BB, 256, 0, stream>>>(Wt, WtMax);
    wtil_k<<<(BB * FF + 255) / 256, 256, 0, stream>>>(Wt, WtMax, Wtil);

    // ---- e2f_softmax ----
    hipMemsetAsync(e2fsm, 0, BB * EE * sizeof(float), stream);
    scatter_sm_k<<<SCB, 256, 0, stream>>>(e2f_idx, e2f_val, Wtil, e2fsm);

    // ---- pagerank init ----
    hipMemcpyAsync(pr, q2e_adj, BB * EE * sizeof(float), hipMemcpyDeviceToDevice, stream);

    for (int i = 0; i < 3; ++i) {
        const float* q2eWi  = q2e_W  + (size_t)i * DD * DD;
        const float* q2ebi  = q2e_b  + i * DD;
        const float* e2qWi  = e2q_W  + (size_t)i * DD * 3 * DD;
        const float* e2qbi  = e2q_b  + i * DD;
        const float* e2eWi  = e2e_W  + (size_t)i * DD * 3 * DD;
        const float* e2ebi  = e2e_b  + i * DD;
        const float* headWi = head_W + (size_t)i * DD * DD;
        const float* headbi = head_b + i * DD;
        const float* tailWi = tail_W + (size_t)i * DD * DD;
        const float* tailbi = tail_b + i * DD;
        const float* selfWi = self_W + (size_t)i * DD * DD;
        const float* selfbi = self_b + i * DD;

        qlin_ebias_k<<<BB, 256, 0, stream>>>(qne, q2eWi, q2ebi, e2eWi, e2ebi, qlin, ebias);

        // e2f_norm (gather; div fused per-edge)
        gather_norm_k<<<(NR1 + 255) / 256, 256, 0, stream>>>(
            e2f_rp, e2f_col, e2f_vp, pr, e2fsm, Wtil, e2fnrm, NR1);

        // headlin = head(lee)  [16000x256]
        gemm2_k<0, 0, 0, 0><<<dim3(2, 125), 256, 0, stream>>>(
            lee, nullptr, nullptr, 1.f, headWi, 256, nullptr, 0,
            headbi, NR2, nullptr, nullptr, bufC, NR2, 256);
        // e2fT = self(lfe)  [48000x256]
        gemm2_k<0, 0, 0, 0><<<dim3(2, 375), 256, 0, stream>>>(
            lfe, nullptr, nullptr, 1.f, selfWi, 256, nullptr, 0,
            selfbi, NR1, nullptr, nullptr, e2fT, NR1, 256);
        // e2fT = relu(e2fT + gather_e2f(headlin)) * e2fnrm
        gather_relu_nrm_k<<<(NR1 * 64 + 255) / 256, 256, 0, stream>>>(
            e2f_rp, e2f_col, e2f_vp, bufC, e2fnrm, e2fT, NR1, FF, EE);

        // tmp = gather_f2e(e2fT)  [16000x256]  (tail commuted past gather)
        gather_sum_k<<<(NR2 * 64 + 255) / 256, 256, 0, stream>>>(
            f2e_rp, f2e_col, f2e_vp, e2fT, tmp, NR2, EE, FF);
        // f2eT = relu(lee@selfW^T + tmp@tailW^T + selfb + degw*tailb)
        gemm2_k<0, 1, 1, 1><<<dim3(2, 125), 256, 0, stream>>>(
            lee, nullptr, tmp, 1.f, selfWi, 256, tailWi, 256,
            selfbi, NR2, degw2, tailbi, f2eT, NR2, 256);

        // pagerank update
        gather_pr_k<<<(NR2 + 255) / 256, 256, 0, stream>>>(
            f2e_rp, f2e_col, f2e_vp, e2fnrm, pr, NR2);

        // query_node_emb update
        vreduce_k<<<dim3(NCHK, BB), 256, 0, stream>>>(pr, lee, f2eT, vpartL, vpartF, vpartS);
        qneupd_k<<<BB, 256, 0, stream>>>(vpartL, vpartF, vpartS, qlin, e2qWi, e2qbi, qne);

        // lee2 = relu(lee@e2eW[:, :256]^T + 3*f2eT@e2eW[:,512:]^T + ebias[b])
        gemm2_k<0, 1, 1, 0><<<dim3(2, 125), 256, 0, stream>>>(
            lee, nullptr, f2eT, 3.f, e2eWi, 768, e2eWi + 512, 768,
            ebias, EE, nullptr, nullptr, lee2, NR2, 256);
        { float* t = lee; lee = lee2; lee2 = t; }
    }

    score_k<<<(BB * EE + 255) / 256, 256, 0, stream>>>(lee, score_W, score_b, scoreb);
    final_k<<<BB, 256, 0, stream>>>(scoreb, local_entity, answer_dist, outp, losspart);
    loss_k<<<1, 64, 0, stream>>>(losspart, outp);
}

// Round 5
// 1624.967 us; speedup vs baseline: 2.7043x; 1.0842x over previous
//
#include <hip/hip_runtime.h>
#include <math.h>

#define BB 8
#define EE 2000
#define FF 6000
#define QQ 20
#define DD 256
#define NENT 400000
#define NWORD 60000
#define NNZ_ 96000
#define VNEG  (-1e11f)
#define VSMALL 1e-10f

// ---------------------------------------------------------------------------
// 64x128-tile fp32 GEMM body: out[r,c] = act(A(r,:)*W(c,:)^T + bias(r,c))
// 256 threads, 4x8 acc/thread, K chunks of 16, register prefetch.
//   GATHER: A1 row via idx[r] (table ld 256)
//   DUALW : K=512: first 256 from A1/W1, second 256 from sA2*A2/W2
//   RS    : bias += rowscale[r]*bias2[c]
//   biasA : indexed biasA[(r/rowsPerB)*N + c]
// ---------------------------------------------------------------------------
template<int GATHER, int DUALW, int RELU, int RS>
__device__ __forceinline__ void gemm3_body(
    const float* __restrict__ A1, const int* __restrict__ idx,
    const float* __restrict__ A2, float sA2,
    const float* __restrict__ W1, int ldw1,
    const float* __restrict__ W2, int ldw2,
    const float* __restrict__ biasA, int rowsPerB,
    const float* __restrict__ rowscale, const float* __restrict__ bias2,
    float* __restrict__ out, int M, int N, int by, int bx,
    float (*As)[68], float (*Bs)[132])
{
    const int tid = threadIdx.x;
    const int row0 = by * 64, col0 = bx * 128;
    const int tx = tid & 15, ty = tid >> 4;
    const int srA = tid >> 2, skA = (tid & 3) << 2;
    const int srB = tid >> 1, skB = (tid & 1) << 3;
    const int grA = row0 + srA;
    const bool rvalid = (grA < M);
    const float* aRow1 = nullptr;
    const float* aRow2 = nullptr;
    if (rvalid) {
        aRow1 = GATHER ? A1 + (size_t)idx[grA] * 256 : A1 + (size_t)grA * 256;
        if (DUALW) aRow2 = A2 + (size_t)grA * 256;
    }
    const float* wR1 = W1 + (size_t)(col0 + srB) * ldw1;
    const float* wR2 = DUALW ? W2 + (size_t)(col0 + srB) * ldw2 : nullptr;

    float acc[4][8];
    #pragma unroll
    for (int i = 0; i < 4; ++i)
        #pragma unroll
        for (int j = 0; j < 8; ++j) acc[i][j] = 0.f;

    const int nch = DUALW ? 32 : 16;
    float4 a0, b0, b1;
    auto fetch = [&](int ch) {
        const int k0 = (ch & 15) << 4;
        const bool hi = DUALW && (ch >= 16);
        const float* ar = hi ? aRow2 : aRow1;
        if (rvalid) a0 = *(const float4*)(ar + k0 + skA);
        else        a0 = make_float4(0.f, 0.f, 0.f, 0.f);
        const float* wr = hi ? wR2 : wR1;
        b0 = *(const float4*)(wr + k0 + skB);
        b1 = *(const float4*)(wr + k0 + skB + 4);
    };

    fetch(0);
    for (int ch = 0; ch < nch; ++ch) {
        const float s = (DUALW && ch >= 16) ? sA2 : 1.f;
        As[skA + 0][srA] = a0.x * s; As[skA + 1][srA] = a0.y * s;
        As[skA + 2][srA] = a0.z * s; As[skA + 3][srA] = a0.w * s;
        Bs[skB + 0][srB] = b0.x; Bs[skB + 1][srB] = b0.y;
        Bs[skB + 2][srB] = b0.z; Bs[skB + 3][srB] = b0.w;
        Bs[skB + 4][srB] = b1.x; Bs[skB + 5][srB] = b1.y;
        Bs[skB + 6][srB] = b1.z; Bs[skB + 7][srB] = b1.w;
        __syncthreads();
        if (ch + 1 < nch) fetch(ch + 1);
        #pragma unroll
        for (int kk = 0; kk < 16; ++kk) {
            float av[4], bv[8];
            *(float4*)&av[0] = *(const float4*)&As[kk][ty << 2];
            *(float4*)&bv[0] = *(const float4*)&Bs[kk][tx << 2];
            *(float4*)&bv[4] = *(const float4*)&Bs[kk][(tx << 2) + 64];
            #pragma unroll
            for (int i = 0; i < 4; ++i)
                #pragma unroll
                for (int j = 0; j < 8; ++j) acc[i][j] += av[i] * bv[j];
        }
        __syncthreads();
    }

    #pragma unroll
    for (int i = 0; i < 4; ++i) {
        int r = row0 + (ty << 2) + i;
        if (r >= M) continue;
        const float* bA = biasA + (size_t)(r / rowsPerB) * N;
        const float rs = RS ? rowscale[r] : 0.f;
        float* orow = out + (size_t)r * N;
        #pragma unroll
        for (int jh = 0; jh < 2; ++jh) {
            const int c = col0 + (jh << 6) + (tx << 2);
            float4 v;
            v.x = acc[i][jh * 4 + 0] + bA[c + 0];
            v.y = acc[i][jh * 4 + 1] + bA[c + 1];
            v.z = acc[i][jh * 4 + 2] + bA[c + 2];
            v.w = acc[i][jh * 4 + 3] + bA[c + 3];
            if (RS) {
                v.x += rs * bias2[c + 0]; v.y += rs * bias2[c + 1];
                v.z += rs * bias2[c + 2]; v.w += rs * bias2[c + 3];
            }
            if (RELU) {
                v.x = fmaxf(v.x, 0.f); v.y = fmaxf(v.y, 0.f);
                v.z = fmaxf(v.z, 0.f); v.w = fmaxf(v.w, 0.f);
            }
            *(float4*)(orow + c) = v;
        }
    }
}

template<int GATHER, int DUALW, int RELU, int RS>
__global__ __launch_bounds__(256, 4) void gemm3_k(
    const float* __restrict__ A1, const int* __restrict__ idx,
    const float* __restrict__ A2, float sA2,
    const float* __restrict__ W1, int ldw1,
    const float* __restrict__ W2, int ldw2,
    const float* __restrict__ biasA, int rowsPerB,
    const float* __restrict__ rowscale, const float* __restrict__ bias2,
    float* __restrict__ out, int M, int N)
{
    __shared__ float As[16][68];
    __shared__ float Bs[16][132];
    gemm3_body<GATHER, DUALW, RELU, RS>(A1, idx, A2, sA2, W1, ldw1, W2, ldw2,
        biasA, rowsPerB, rowscale, bias2, out, M, N, blockIdx.y, blockIdx.x, As, Bs);
}

// two independent plain GEMMs in one dispatch (job A: by<nya, job B: rest)
__global__ __launch_bounds__(256, 4) void gemm_pair_k(
    const float* __restrict__ A1a, const float* __restrict__ W1a,
    const float* __restrict__ ba, float* __restrict__ outa, int Ma, int nya,
    const float* __restrict__ A1b, const float* __restrict__ W1b,
    const float* __restrict__ bb, float* __restrict__ outb, int Mb)
{
    __shared__ float As[16][68];
    __shared__ float Bs[16][132];
    const int by = blockIdx.y;
    if (by < nya)
        gemm3_body<0, 0, 0, 0>(A1a, nullptr, nullptr, 1.f, W1a, 256, nullptr, 0,
            ba, Ma, nullptr, nullptr, outa, Ma, 256, by, blockIdx.x, As, Bs);
    else
        gemm3_body<0, 0, 0, 0>(A1b, nullptr, nullptr, 1.f, W1b, 256, nullptr, 0,
            bb, Mb, nullptr, nullptr, outb, Mb, 256, by - nya, blockIdx.x, As, Bs);
}

// ---------------------------------------------------------------------------
// CSR build
// ---------------------------------------------------------------------------
__global__ void csr_count_k(const int* __restrict__ idx, int* __restrict__ cnt, int nrPerB)
{
    int k = blockIdx.x * 256 + threadIdx.x;
    if (k >= NNZ_) return;
    atomicAdd(&cnt[idx[k] * nrPerB + idx[NNZ_ + k]], 1);
}

__global__ __launch_bounds__(1024) void scan2_k(
    const int* __restrict__ cntA, int* __restrict__ rpA, int* __restrict__ curA, int nA,
    const int* __restrict__ cntB, int* __restrict__ rpB, int* __restrict__ curB, int nB)
{
    const int* cnt = blockIdx.x ? cntB : cntA;
    int* rp  = blockIdx.x ? rpB  : rpA;
    int* cur = blockIdx.x ? curB : curA;
    int n    = blockIdx.x ? nB   : nA;
    __shared__ int sums[1024];
    int t = threadIdx.x;
    int chunk = (n + 1023) / 1024;
    int lo = t * chunk, hi = lo + chunk;
    if (lo > n) lo = n;
    if (hi > n) hi = n;
    int s = 0;
    for (int i = lo; i < hi; ++i) s += cnt[i];
    sums[t] = s;
    __syncthreads();
    for (int off = 1; off < 1024; off <<= 1) {
        int v = (t >= off) ? sums[t - off] : 0;
        __syncthreads();
        sums[t] += v;
        __syncthreads();
    }
    int run = (t == 0) ? 0 : sums[t - 1];
    for (int i = lo; i < hi; ++i) { rp[i] = run; cur[i] = run; run += cnt[i]; }
    if (hi == n) rp[n] = run;
}

__global__ void csr_fill_k(const int* __restrict__ idx, const float* __restrict__ val,
                           int* __restrict__ cur, int* __restrict__ col,
                           float* __restrict__ valp, int nrPerB)
{
    int k = blockIdx.x * 256 + threadIdx.x;
    if (k >= NNZ_) return;
    int row = idx[k] * nrPerB + idx[NNZ_ + k];
    int p = atomicAdd(&cur[row], 1);
    col[p] = idx[2 * NNZ_ + k];
    valp[p] = val[k];
}

__global__ void degw_k(const int* __restrict__ rp, const float* __restrict__ vp,
                       float* __restrict__ degw, int n)
{
    int r = blockIdx.x * 256 + threadIdx.x;
    if (r >= n) return;
    float s = 0.f;
    for (int j = rp[r]; j < rp[r + 1]; ++j) s += vp[j];
    degw[r] = s;
}

// ---------------------------------------------------------------------------
// fused e2f gather: dst[row]=relu(dst[row]+sum val*head[b,c]) * nrm,
// nrm = Wtil[row]*sum val*pr[b,c]/max(sm[b,c],eps), also written to e2fnrm.
// ---------------------------------------------------------------------------
__global__ __launch_bounds__(256) void gather_fused_e2f_k(
    const int* __restrict__ rowptr, const int* __restrict__ col,
    const float* __restrict__ valp, const float* __restrict__ headsrc,
    const float* __restrict__ pr, const float* __restrict__ sm,
    const float* __restrict__ Wtil, float* __restrict__ e2fnrm,
    float* __restrict__ dst, int nrows)
{
    int gid = blockIdx.x * 256 + threadIdx.x;
    int row = gid >> 6, lane = gid & 63;
    if (row >= nrows) return;
    int b = row / FF;
    const float* prb = pr + (size_t)b * EE;
    const float* smb = sm + (size_t)b * EE;
    float4* dp = (float4*)(dst + (size_t)row * DD + (lane << 2));
    float4 acc = *dp;
    float ns = 0.f;
    int j0 = rowptr[row], j1 = rowptr[row + 1];
    for (int j = j0; j < j1; ++j) {
        int c = col[j];
        float v = valp[j];
        float4 x = *(const float4*)(headsrc + ((size_t)b * EE + c) * DD + (lane << 2));
        acc.x += v * x.x; acc.y += v * x.y; acc.z += v * x.z; acc.w += v * x.w;
        ns += v * (prb[c] / fmaxf(smb[c], VSMALL));
    }
    float nrm = Wtil[row] * ns;
    if (lane == 0) e2fnrm[row] = nrm;
    acc.x = fmaxf(acc.x, 0.f) * nrm; acc.y = fmaxf(acc.y, 0.f) * nrm;
    acc.z = fmaxf(acc.z, 0.f) * nrm; acc.w = fmaxf(acc.w, 0.f) * nrm;
    *dp = acc;
}

// dst[row] = sum val*src[b,c]  (pure gather)
__global__ __launch_bounds__(256) void gather_sum_k(
    const int* __restrict__ rowptr, const int* __restrict__ col,
    const float* __restrict__ valp, const float* __restrict__ src,
    float* __restrict__ dst, int nrows, int nrPerB, int ncs)
{
    int gid = blockIdx.x * 256 + threadIdx.x;
    int row = gid >> 6, lane = gid & 63;
    if (row >= nrows) return;
    int b = row / nrPerB;
    float4 acc = make_float4(0.f, 0.f, 0.f, 0.f);
    int j0 = rowptr[row], j1 = rowptr[row + 1];
    for (int j = j0; j < j1; ++j) {
        int c = col[j];
        float v = valp[j];
        float4 x = *(const float4*)(src + ((size_t)b * ncs + c) * DD + (lane << 2));
        acc.x += v * x.x; acc.y += v * x.y; acc.z += v * x.z; acc.w += v * x.w;
    }
    *(float4*)(dst + (size_t)row * DD + (lane << 2)) = acc;
}

// ---------------------------------------------------------------------------
// LSTM
// ---------------------------------------------------------------------------
__global__ void transpose_whh_k(const float* __restrict__ Whh, float* __restrict__ WhhT)
{
    int i = blockIdx.x * 256 + threadIdx.x;
    int k = i >> 10, j = i & 1023;
    WhhT[i] = Whh[(size_t)j * 256 + k];
}

__global__ __launch_bounds__(256) void lstm_k(
    const float* __restrict__ Xg, const float* __restrict__ WhhT,
    const float* __restrict__ bhh, float* __restrict__ qh, float* __restrict__ qne)
{
    __shared__ float h[DD];
    __shared__ float gs[4 * DD];
    const int b = blockIdx.x, t = threadIdx.x;
    h[t] = 0.f;
    float c = 0.f;
    const float4 bb4 = *(const float4*)(bhh + 4 * t);
    const float4* wt4 = (const float4*)WhhT + t;
    __syncthreads();
    for (int step = 0; step < QQ; ++step) {
        float a0 = 0.f, a1 = 0.f, a2 = 0.f, a3 = 0.f;
        #pragma unroll 16
        for (int k = 0; k < DD; ++k) {
            float4 w = wt4[k * 256];
            float hk = h[k];
            a0 += w.x * hk; a1 += w.y * hk; a2 += w.z * hk; a3 += w.w * hk;
        }
        float4 xg = *(const float4*)(Xg + ((size_t)b * QQ + step) * 1024 + 4 * t);
        float4 g4 = make_float4(a0 + xg.x + bb4.x, a1 + xg.y + bb4.y,
                                a2 + xg.z + bb4.z, a3 + xg.w + bb4.w);
        *(float4*)(gs + 4 * t) = g4;
        __syncthreads();
        float gi = gs[t], gf = gs[DD + t], gg = gs[2 * DD + t], go = gs[3 * DD + t];
        float si = 1.f / (1.f + expf(-gi));
        float sf = 1.f / (1.f + expf(-gf));
        float so = 1.f / (1.f + expf(-go));
        c = sf * c + si * tanhf(gg);
        float hh = so * tanhf(c);
        h[t] = hh;
        qh[((size_t)b * QQ + step) * DD + t] = hh;
        __syncthreads();
    }
    qne[(size_t)b * DD + t] = h[t];
}

// ---------------------------------------------------------------------------
// sim -> softmax -> Wt
// ---------------------------------------------------------------------------
__global__ __launch_bounds__(256) void simwt_k(
    const float* __restrict__ qhid, const int* __restrict__ qtext,
    const float* __restrict__ lfe, float* __restrict__ Wt)
{
    __shared__ float qs[QQ * DD];
    __shared__ float qmn[QQ];
    const int b = blockIdx.y;
    const int f = blockIdx.x * 256 + threadIdx.x;
    for (int i = threadIdx.x; i < QQ * DD; i += 256) qs[i] = qhid[(size_t)b * QQ * DD + i];
    if (threadIdx.x < QQ)
        qmn[threadIdx.x] = (qtext[b * QQ + threadIdx.x] != NWORD) ? 0.f : VNEG;
    __syncthreads();
    if (f >= FF) return;
    float acc[QQ];
    #pragma unroll
    for (int q = 0; q < QQ; ++q) acc[q] = 0.f;
    const float* lr = lfe + ((size_t)b * FF + f) * DD;
    for (int d = 0; d < DD; d += 4) {
        float4 x = *(const float4*)(lr + d);
        #pragma unroll
        for (int q = 0; q < QQ; ++q) {
            float4 y = *(const float4*)&qs[q * DD + d];
            acc[q] += x.x * y.x + x.y * y.y + x.z * y.z + x.w * y.w;
        }
    }
    const float inv = 0.0625f;
    float pre[QQ], m = -INFINITY;
    #pragma unroll
    for (int q = 0; q < QQ; ++q) { pre[q] = acc[q] * inv + qmn[q]; m = fmaxf(m, pre[q]); }
    float s = 0.f;
    #pragma unroll
    for (int q = 0; q < QQ; ++q) s += expf(pre[q] - m);
    float wt = 0.f;
    #pragma unroll
    for (int q = 0; q < QQ; ++q) wt += (expf(pre[q] - m) / s) * (acc[q] * inv);
    Wt[(size_t)b * FF + f] = wt;
}

__global__ void rowmax_k(const float* __restrict__ Wt, float* __restrict__ WtMax)
{
    __shared__ float red[256];
    int b = blockIdx.x;
    float m = -INFINITY;
    for (int f = threadIdx.x; f < FF; f += 256) m = fmaxf(m, Wt[b * FF + f]);
    red[threadIdx.x] = m; __syncthreads();
    for (int s = 128; s > 0; s >>= 1) {
        if (threadIdx.x < s) red[threadIdx.x] = fmaxf(red[threadIdx.x], red[threadIdx.x + s]);
        __syncthreads();
    }
    if (threadIdx.x == 0) WtMax[b] = red[0];
}

__global__ void wtil_k(const float* __restrict__ Wt, const float* __restrict__ WtMax,
                       float* __restrict__ Wtil)
{
    int i = blockIdx.x * 256 + threadIdx.x;
    if (i >= BB * FF) return;
    Wtil[i] = expf(Wt[i] - WtMax[i / FF]);
}

__global__ void scatter_sm_k(const int* __restrict__ idx, const float* __restrict__ val,
                             const float* __restrict__ Wtil, float* __restrict__ dst)
{
    int k = blockIdx.x * 256 + threadIdx.x;
    if (k >= NNZ_) return;
    int b = idx[k], e = idx[2 * NNZ_ + k], f = idx[NNZ_ + k];
    atomicAdd(&dst[(size_t)b * EE + e], val[k] * Wtil[(size_t)b * FF + f]);
}

// ---------------------------------------------------------------------------
// initial qlin + ebias (per batch)
// ---------------------------------------------------------------------------
__global__ __launch_bounds__(256) void qlin_ebias_k(
    const float* __restrict__ qne, const float* __restrict__ q2eW,
    const float* __restrict__ q2eb, const float* __restrict__ e2eW,
    const float* __restrict__ e2eb, float* __restrict__ qlin, float* __restrict__ ebias)
{
    __shared__ float xs[DD], qs[DD];
    int b = blockIdx.x, j = threadIdx.x;
    xs[j] = qne[b * DD + j];
    __syncthreads();
    float acc = q2eb[j];
    const float* wr = q2eW + (size_t)j * DD;
    #pragma unroll 4
    for (int k = 0; k < DD; ++k) acc += xs[k] * wr[k];
    qlin[b * DD + j] = acc;
    qs[j] = acc;
    __syncthreads();
    float acc2 = e2eb[j];
    const float* wr2 = e2eW + (size_t)j * 768 + 256;
    #pragma unroll 4
    for (int k = 0; k < DD; ++k) acc2 += qs[k] * wr2[k];
    ebias[b * DD + j] = acc2;
}

// ---------------------------------------------------------------------------
// fused pagerank update + vreduce partials
// ---------------------------------------------------------------------------
#define VCH 80
#define NCHK (EE / VCH)   // 25
__global__ __launch_bounds__(256) void vreduce_pr_k(
    const int* __restrict__ f2e_rp, const int* __restrict__ f2e_col,
    const float* __restrict__ f2e_vp, const float* __restrict__ e2fnrm,
    float* __restrict__ pr, const float* __restrict__ lee,
    const float* __restrict__ f2e, float* __restrict__ vpartL,
    float* __restrict__ vpartF, float* __restrict__ vpartS)
{
    int b = blockIdx.y, ch = blockIdx.x, k = threadIdx.x;
    int e0 = ch * VCH;
    __shared__ float prs[VCH];
    if (k < VCH) {
        int row = b * EE + e0 + k;
        float s = 0.f;
        for (int j = f2e_rp[row]; j < f2e_rp[row + 1]; ++j)
            s += f2e_vp[j] * e2fnrm[(size_t)b * FF + f2e_col[j]];
        float v = 0.8f * s + 0.2f * pr[row];
        pr[row] = v;
        prs[k] = v;
    }
    __syncthreads();
    float a1 = 0.f, a2 = 0.f;
    for (int e = 0; e < VCH; ++e) {
        float p = prs[e];
        size_t base = ((size_t)b * EE + e0 + e) * DD + k;
        a1 += p * lee[base];
        a2 += p * f2e[base];
    }
    int pi = ch * BB + b;
    vpartL[(size_t)pi * DD + k] = a1;
    vpartF[(size_t)pi * DD + k] = a2;
    float sp = 0.f;
    for (int e = k; e < VCH; e += 256) sp += prs[e];
    __shared__ float red[256];
    red[k] = sp; __syncthreads();
    for (int s = 128; s > 0; s >>= 1) {
        if (k < s) red[k] += red[k + s];
        __syncthreads();
    }
    if (k == 0) vpartS[pi] = red[0];
}

// ---------------------------------------------------------------------------
// qne update + (optional) next layer's qlin/ebias, fused (per batch)
// ---------------------------------------------------------------------------
__global__ __launch_bounds__(256) void qneupd_qlin_k(
    const float* __restrict__ vpartL, const float* __restrict__ vpartF,
    const float* __restrict__ vpartS, const float* __restrict__ qlinCur,
    const float* __restrict__ W, const float* __restrict__ bias,
    float* __restrict__ qne,
    const float* __restrict__ q2eWn, const float* __restrict__ q2ebn,
    const float* __restrict__ e2eWn, const float* __restrict__ e2ebn,
    float* __restrict__ qlinNext, float* __restrict__ ebiasNext, int hasNext)
{
    __shared__ float s1[DD], s2[DD], s3[DD], qn[DD], qs[DD];
    int b = blockIdx.x, j = threadIdx.x;
    float a1 = 0.f, a3 = 0.f, sp = 0.f;
    for (int ch = 0; ch < NCHK; ++ch) {
        int pi = ch * BB + b;
        a1 += vpartL[(size_t)pi * DD + j];
        a3 += vpartF[(size_t)pi * DD + j];
        sp += vpartS[pi];
    }
    s1[j] = a1; s2[j] = qlinCur[b * DD + j]; s3[j] = a3;
    __syncthreads();
    float acc = sp * bias[j];
    const float* wr = W + (size_t)j * 768;
    #pragma unroll 4
    for (int k = 0; k < DD; ++k)
        acc += s1[k] * wr[k] + sp * s2[k] * wr[256 + k] + 3.f * s3[k] * wr[512 + k];
    qne[b * DD + j] = acc;
    if (!hasNext) return;
    qn[j] = acc;
    __syncthreads();
    float aq = q2ebn[j];
    const float* wq = q2eWn + (size_t)j * DD;
    #pragma unroll 4
    for (int k = 0; k < DD; ++k) aq += qn[k] * wq[k];
    qlinNext[b * DD + j] = aq;
    qs[j] = aq;
    __syncthreads();
    float ae = e2ebn[j];
    const float* we = e2eWn + (size_t)j * 768 + 256;
    #pragma unroll 4
    for (int k = 0; k < DD; ++k) ae += qs[k] * we[k];
    ebiasNext[b * DD + j] = ae;
}

// ---------------------------------------------------------------------------
// epilogue
// ---------------------------------------------------------------------------
__global__ void score_k(const float* __restrict__ lee, const float* __restrict__ sw,
                        const float* __restrict__ sb, float* __restrict__ score)
{
    int r = blockIdx.x * 256 + threadIdx.x;
    if (r >= BB * EE) return;
    float acc = sb[0];
    const float* a = lee + (size_t)r * DD;
    for (int k = 0; k < DD; k += 4) {
        float4 v = *(const float4*)(a + k);
        acc += v.x * sw[k] + v.y * sw[k + 1] + v.z * sw[k + 2] + v.w * sw[k + 3];
    }
    score[r] = acc;
}

__global__ __launch_bounds__(256) void final_k(
    const float* __restrict__ score, const int* __restrict__ local_entity,
    const float* __restrict__ ans, float* __restrict__ out, float* __restrict__ losspart)
{
    int b = blockIdx.x, t = threadIdx.x;
    float lsum = 0.f, bm = -INFINITY;
    int bi = EE;
    for (int e = t; e < EE; e += 256) {
        float s = score[b * EE + e];
        float mask = (local_entity[b * EE + e] != NENT) ? 1.f : 0.f;
        float smv = s + (1.f - mask) * VNEG;
        float sig;
        if (smv >= 0.f) sig = 1.f / (1.f + expf(-smv));
        else { float es = expf(smv); sig = es / (1.f + es); }
        out[1 + BB + b * EE + e] = sig * mask;
        lsum += fmaxf(s, 0.f) - s * ans[b * EE + e] + log1pf(expf(-fabsf(s)));
        if (smv > bm) { bm = smv; bi = e; }
    }
    __shared__ float rv[256]; __shared__ int ri[256]; __shared__ float rl[256];
    rv[t] = bm; ri[t] = bi; rl[t] = lsum;
    __syncthreads();
    for (int s = 128; s > 0; s >>= 1) {
        if (t < s) {
            rl[t] += rl[t + s];
            if (rv[t + s] > rv[t] || (rv[t + s] == rv[t] && ri[t + s] < ri[t])) {
                rv[t] = rv[t + s]; ri[t] = ri[t + s];
            }
        }
        __syncthreads();
    }
    if (t == 0) { losspart[b] = rl[0]; out[1 + b] = (float)ri[0]; }
}

__global__ void loss_k(const float* __restrict__ losspart, float* __restrict__ out)
{
    if (threadIdx.x == 0) {
        float s = 0.f;
        for (int b = 0; b < BB; ++b) s += losspart[b];
        out[0] = s / (float)(BB * EE);
    }
}

// ---------------------------------------------------------------------------
extern "C" void kernel_launch(void* const* d_in, const int* in_sizes, int n_in,
                              void* d_out, int out_size, void* d_ws, size_t ws_size,
                              hipStream_t stream)
{
    (void)in_sizes; (void)n_in; (void)out_size; (void)ws_size;
    const int*   local_entity = (const int*)d_in[0];
    const float* q2e_adj      = (const float*)d_in[1];
    const int*   kb_fact_rel  = (const int*)d_in[2];
    const int*   query_text   = (const int*)d_in[3];
    const float* answer_dist  = (const float*)d_in[4];
    const int*   e2f_idx      = (const int*)d_in[5];
    const float* e2f_val      = (const float*)d_in[6];
    const int*   f2e_idx      = (const int*)d_in[7];
    const float* f2e_val      = (const float*)d_in[8];
    const float* entity_table = (const float*)d_in[9];
    const float* ent_W        = (const float*)d_in[10];
    const float* ent_b        = (const float*)d_in[11];
    const float* rel_table    = (const float*)d_in[12];
    const float* rel_W        = (const float*)d_in[13];
    const float* rel_b        = (const float*)d_in[14];
    const float* word_table   = (const float*)d_in[15];
    const float* Wih          = (const float*)d_in[16];
    const float* Whh          = (const float*)d_in[17];
    const float* bih          = (const float*)d_in[18];
    const float* bhh          = (const float*)d_in[19];
    const float* q2e_W        = (const float*)d_in[20];
    const float* q2e_b        = (const float*)d_in[21];
    const float* e2q_W        = (const float*)d_in[22];
    const float* e2q_b        = (const float*)d_in[23];
    const float* e2e_W        = (const float*)d_in[24];
    const float* e2e_b        = (const float*)d_in[25];
    const float* head_W       = (const float*)d_in[26];
    const float* head_b       = (const float*)d_in[27];
    const float* tail_W       = (const float*)d_in[28];
    const float* tail_b       = (const float*)d_in[29];
    const float* self_W       = (const float*)d_in[30];
    const float* self_b       = (const float*)d_in[31];
    const float* score_W      = (const float*)d_in[32];
    const float* score_b      = (const float*)d_in[33];

    const int NR1 = BB * FF;   // 48000
    const int NR2 = BB * EE;   // 16000

    float* ws = (float*)d_ws;
    size_t off = 0;
    auto alloc = [&](size_t n) { float* p = ws + off; off += n; return p; };
    float* Xg      = alloc((size_t)BB * QQ * 1024);
    float* WhhT    = alloc((size_t)1024 * DD);
    float* qh      = alloc((size_t)BB * QQ * DD);
    float* qne     = alloc(BB * DD);
    float* lfe     = alloc((size_t)NR1 * DD);
    float* lee     = alloc((size_t)NR2 * DD);
    float* lee2    = alloc((size_t)NR2 * DD);
    float* Wt      = alloc(BB * FF);
    float* WtMax   = alloc(8);
    float* Wtil    = alloc(BB * FF);
    float* e2fsm   = alloc(BB * EE);
    float* pr      = alloc(BB * EE);
    float* qlinA   = alloc(BB * DD);
    float* qlinB   = alloc(BB * DD);
    float* ebiasA  = alloc(BB * DD);
    float* ebiasB  = alloc(BB * DD);
    float* e2fnrm  = alloc(BB * FF);
    float* scoreb  = alloc(BB * EE);
    float* losspart= alloc(8);
    float* bufC    = alloc((size_t)NR2 * DD);   // head(lee)
    float* e2fT    = alloc((size_t)NR1 * DD);   // e2f_emb
    float* f2eT    = alloc((size_t)NR2 * DD);   // f2e_emb
    float* tmp     = alloc((size_t)NR2 * DD);   // gather_f2e(e2fT)
    float* vpartL  = alloc((size_t)NCHK * BB * DD);
    float* vpartF  = alloc((size_t)NCHK * BB * DD);
    float* vpartS  = alloc(NCHK * BB);
    float* degw2   = alloc(NR2);
    float* e2f_vp  = alloc(NNZ_);
    float* f2e_vp  = alloc(NNZ_);
    int* ib = (int*)(ws + off);
    size_t ioff = 0;
    auto ialloc = [&](size_t n) { int* p = ib + ioff; ioff += n; return p; };
    int* e2f_cnt = ialloc(NR1);
    int* e2f_rp  = ialloc(NR1 + 1);
    int* e2f_cur = ialloc(NR1);
    int* e2f_col = ialloc(NNZ_);
    int* f2e_cnt = ialloc(NR2);
    int* f2e_rp  = ialloc(NR2 + 1);
    int* f2e_cur = ialloc(NR2);
    int* f2e_col = ialloc(NNZ_);

    float* outp = (float*)d_out;
    const int SCB = (NNZ_ + 255) / 256;

    // ---- CSR builds ----
    hipMemsetAsync(e2f_cnt, 0, NR1 * sizeof(int), stream);
    hipMemsetAsync(f2e_cnt, 0, NR2 * sizeof(int), stream);
    csr_count_k<<<SCB, 256, 0, stream>>>(e2f_idx, e2f_cnt, FF);
    csr_count_k<<<SCB, 256, 0, stream>>>(f2e_idx, f2e_cnt, EE);
    scan2_k<<<2, 1024, 0, stream>>>(e2f_cnt, e2f_rp, e2f_cur, NR1,
                                    f2e_cnt, f2e_rp, f2e_cur, NR2);
    csr_fill_k<<<SCB, 256, 0, stream>>>(e2f_idx, e2f_val, e2f_cur, e2f_col, e2f_vp, FF);
    csr_fill_k<<<SCB, 256, 0, stream>>>(f2e_idx, f2e_val, f2e_cur, f2e_col, f2e_vp, EE);
    degw_k<<<(NR2 + 255) / 256, 256, 0, stream>>>(f2e_rp, f2e_vp, degw2, NR2);

    // ---- LSTM ----
    gemm3_k<1, 0, 0, 0><<<dim3(8, 3), 256, 0, stream>>>(
        word_table, query_text, nullptr, 1.f, Wih, 256, nullptr, 0,
        bih, BB * QQ, nullptr, nullptr, Xg, BB * QQ, 1024);
    transpose_whh_k<<<1024, 256, 0, stream>>>(Whh, WhhT);
    lstm_k<<<BB, 256, 0, stream>>>(Xg, WhhT, bhh, qh, qne);

    // ---- embeddings ----
    gemm3_k<1, 0, 0, 0><<<dim3(2, 750), 256, 0, stream>>>(
        rel_table, kb_fact_rel, nullptr, 1.f, rel_W, 256, nullptr, 0,
        rel_b, NR1, nullptr, nullptr, lfe, NR1, 256);
    gemm3_k<1, 0, 0, 0><<<dim3(2, 250), 256, 0, stream>>>(
        entity_table, local_entity, nullptr, 1.f, ent_W, 256, nullptr, 0,
        ent_b, NR2, nullptr, nullptr, lee, NR2, 256);

    // ---- attention -> W_tilde ----
    simwt_k<<<dim3((FF + 255) / 256, BB), 256, 0, stream>>>(qh, query_text, lfe, Wt);
    rowmax_k<<<BB, 256, 0, stream>>>(Wt, WtMax);
    wtil_k<<<(BB * FF + 255) / 256, 256, 0, stream>>>(Wt, WtMax, Wtil);

    // ---- e2f_softmax ----
    hipMemsetAsync(e2fsm, 0, BB * EE * sizeof(float), stream);
    scatter_sm_k<<<SCB, 256, 0, stream>>>(e2f_idx, e2f_val, Wtil, e2fsm);

    // ---- pagerank init + initial qlin/ebias ----
    hipMemcpyAsync(pr, q2e_adj, BB * EE * sizeof(float), hipMemcpyDeviceToDevice, stream);
    qlin_ebias_k<<<BB, 256, 0, stream>>>(qne, q2e_W, q2e_b, e2e_W, e2e_b, qlinA, ebiasA);

    float* qlinCur = qlinA;  float* qlinNxt = qlinB;
    float* ebiasCur = ebiasA; float* ebiasNxt = ebiasB;

    for (int i = 0; i < 3; ++i) {
        const float* e2qWi  = e2q_W  + (size_t)i * DD * 3 * DD;
        const float* e2qbi  = e2q_b  + i * DD;
        const float* e2eWi  = e2e_W  + (size_t)i * DD * 3 * DD;
        const float* headWi = head_W + (size_t)i * DD * DD;
        const float* headbi = head_b + i * DD;
        const float* tailWi = tail_W + (size_t)i * DD * DD;
        const float* tailbi = tail_b + i * DD;
        const float* selfWi = self_W + (size_t)i * DD * DD;
        const float* selfbi = self_b + i * DD;

        // head(lee) -> bufC  AND  self(lfe) -> e2fT, one dispatch
        gemm_pair_k<<<dim3(2, 250 + 750), 256, 0, stream>>>(
            lee, headWi, headbi, bufC, NR2, 250,
            lfe, selfWi, selfbi, e2fT, NR1);

        // e2fT = relu(e2fT + gather_e2f(bufC)) * nrm ; e2fnrm written
        gather_fused_e2f_k<<<(NR1 * 64) / 256, 256, 0, stream>>>(
            e2f_rp, e2f_col, e2f_vp, bufC, pr, e2fsm, Wtil, e2fnrm, e2fT, NR1);

        // tmp = gather_f2e(e2fT)
        gather_sum_k<<<(NR2 * 64) / 256, 256, 0, stream>>>(
            f2e_rp, f2e_col, f2e_vp, e2fT, tmp, NR2, EE, FF);

        // f2eT = relu(lee@selfW^T + tmp@tailW^T + selfb + degw*tailb)
        gemm3_k<0, 1, 1, 1><<<dim3(2, 250), 256, 0, stream>>>(
            lee, nullptr, tmp, 1.f, selfWi, 256, tailWi, 256,
            selfbi, NR2, degw2, tailbi, f2eT, NR2, 256);

        // pagerank update + vreduce partials (fused)
        vreduce_pr_k<<<dim3(NCHK, BB), 256, 0, stream>>>(
            f2e_rp, f2e_col, f2e_vp, e2fnrm, pr, lee, f2eT, vpartL, vpartF, vpartS);

        // qne update + next layer's qlin/ebias
        int hasNext = (i < 2) ? 1 : 0;
        const float* q2eWn = q2e_W + (size_t)(i + 1) * DD * DD * (hasNext ? 1 : 0);
        const float* q2ebn = q2e_b + (i + 1) * DD * (hasNext ? 1 : 0);
        const float* e2eWn = e2e_W + (size_t)(i + 1) * DD * 3 * DD * (hasNext ? 1 : 0);
        const float* e2ebn = e2e_b + (i + 1) * DD * (hasNext ? 1 : 0);
        qneupd_qlin_k<<<BB, 256, 0, stream>>>(
            vpartL, vpartF, vpartS, qlinCur, e2qWi, e2qbi, qne,
            q2eWn, q2ebn, e2eWn, e2ebn, qlinNxt, ebiasNxt, hasNext);

        // lee2 = relu(lee@e2eW[:, :256]^T + 3*f2eT@e2eW[:,512:]^T + ebias[b])
        gemm3_k<0, 1, 1, 0><<<dim3(2, 250), 256, 0, stream>>>(
            lee, nullptr, f2eT, 3.f, e2eWi, 768, e2eWi + 512, 768,
            ebiasCur, EE, nullptr, nullptr, lee2, NR2, 256);
        { float* t = lee; lee = lee2; lee2 = t; }
        { float* t = qlinCur; qlinCur = qlinNxt; qlinNxt = t; }
        { float* t = ebiasCur; ebiasCur = ebiasNxt; ebiasNxt = t; }
    }

    score_k<<<(BB * EE + 255) / 256, 256, 0, stream>>>(lee, score_W, score_b, scoreb);
    final_k<<<BB, 256, 0, stream>>>(scoreb, local_entity, answer_dist, outp, losspart);
    loss_k<<<1, 64, 0, stream>>>(losspart, outp);
}

// Round 6
// 1295.273 us; speedup vs baseline: 3.3927x; 1.2545x over previous
//
#include <hip/hip_runtime.h>
#include <math.h>

#define BB 8
#define EE 2000
#define FF 6000
#define QQ 20
#define DD 256
#define NENT 400000
#define NWORD 60000
#define NNZ_ 96000
#define VNEG  (-1e11f)
#define VSMALL 1e-10f

typedef __attribute__((ext_vector_type(8))) short short8v;
typedef __attribute__((ext_vector_type(4))) short short4v;
typedef __attribute__((ext_vector_type(4))) float f32x4;

__device__ __forceinline__ unsigned short f2bf_rne(float x)
{
    unsigned u = __float_as_uint(x);
    u += 0x7FFFu + ((u >> 16) & 1u);
    return (unsigned short)(u >> 16);
}
__device__ __forceinline__ float bf2f(unsigned short h)
{
    return __uint_as_float((unsigned)h << 16);
}

// ---------------------------------------------------------------------------
// MFMA split-bf16 GEMM: out[r,c] = act( sum_k A[r,k]*W[c,k] + bias )
// exactness: A,W split to hi+lo bf16; hi*hi + hi*lo + lo*hi (fp32 accum);
// dropped lo*lo ~ 4e-6 relative.
// Block: 128 rows x 64 cols, 256 thr (4 waves 2x2, wave = 64x32).
// K chunks of 64 staged fp32->split->LDS in frag-major order.
//   GATHER: A row via idx[r] (table ld 256)
//   DUALW : second K=256 half from A2*sA2 / W2
//   BIASB : biasA indexed [(r/EE)*256 + c] else [c]
//   RS    : += rowscale[r]*bias2[c]
// M must be a multiple of 128. N = 256. W pre-split, ld 256.
// ---------------------------------------------------------------------------
template<int GATHER, int DUALW, int RELU, int RS, int BIASB>
__device__ __forceinline__ void mgemm_body(
    const float* __restrict__ A1, const int* __restrict__ idx,
    const float* __restrict__ A2, float sA2,
    const short* __restrict__ W1h, const short* __restrict__ W1l,
    const short* __restrict__ W2h, const short* __restrict__ W2l,
    const float* __restrict__ biasA,
    const float* __restrict__ rowscale, const float* __restrict__ bias2,
    float* __restrict__ out, int by, int bx,
    short* __restrict__ Ah, short* __restrict__ Al)
{
    const int tid = threadIdx.x;
    const int lane = tid & 63, wv = tid >> 6;
    const int wrow = wv >> 1, wcol = wv & 1;
    const int row0 = by * 128, col0 = bx * 64;

    // staging: thread -> row (tid>>1), k-half (tid&1)*32 of the 64-chunk
    const int sr = tid >> 1;
    const int sko = (tid & 1) << 5;
    const int grow = row0 + sr;
    const float* aRow1 = GATHER ? A1 + (size_t)idx[grow] * 256 : A1 + (size_t)grow * 256;
    const float* aRow2 = DUALW ? A2 + (size_t)grow * 256 : nullptr;

    f32x4 acc[4][2];
    #pragma unroll
    for (int i = 0; i < 4; ++i)
        #pragma unroll
        for (int j = 0; j < 2; ++j) acc[i][j] = (f32x4){0.f, 0.f, 0.f, 0.f};

    const int nch = DUALW ? 8 : 4;
    for (int ch = 0; ch < nch; ++ch) {
        const bool hi2 = DUALW && (ch >= 4);
        const float* ar = hi2 ? aRow2 : aRow1;
        const int kbase = (ch & 3) << 6;
        // ---- stage: 32 fp32 -> hi/lo bf16 into frag-major LDS ----
        #pragma unroll
        for (int q = 0; q < 8; ++q) {
            const int kc = sko + (q << 2);               // 0..60
            float4 a = *(const float4*)(ar + kbase + kc);
            if (DUALW && hi2) { a.x *= sA2; a.y *= sA2; a.z *= sA2; a.w *= sA2; }
            unsigned short h0 = f2bf_rne(a.x), h1 = f2bf_rne(a.y),
                           h2 = f2bf_rne(a.z), h3 = f2bf_rne(a.w);
            unsigned short l0 = f2bf_rne(a.x - bf2f(h0)), l1 = f2bf_rne(a.y - bf2f(h1)),
                           l2 = f2bf_rne(a.z - bf2f(h2)), l3 = f2bf_rne(a.w - bf2f(h3));
            const int tI = ((sr >> 4) << 1) + (kc >> 5);
            const int off = (tI << 9) + ((((sr & 15)) + (((kc >> 3) & 3) << 4)) << 3) + (kc & 7);
            *(short4v*)(Ah + off) = (short4v){(short)h0, (short)h1, (short)h2, (short)h3};
            *(short4v*)(Al + off) = (short4v){(short)l0, (short)l1, (short)l2, (short)l3};
        }
        __syncthreads();
        // ---- compute ----
        const short* Wh = hi2 ? W2h : W1h;
        const short* Wl = hi2 ? W2l : W1l;
        #pragma unroll
        for (int ks = 0; ks < 2; ++ks) {
            const int kg = kbase + (ks << 5) + ((lane >> 4) << 3);
            short8v bh[2], bl[2];
            #pragma unroll
            for (int ct = 0; ct < 2; ++ct) {
                const int c = col0 + (wcol << 5) + (ct << 4) + (lane & 15);
                bh[ct] = *(const short8v*)(Wh + (size_t)c * 256 + kg);
                bl[ct] = *(const short8v*)(Wl + (size_t)c * 256 + kg);
            }
            #pragma unroll
            for (int rt = 0; rt < 4; ++rt) {
                const int tI = (((wrow << 2) + rt) << 1) + ks;
                const short8v avh = *(const short8v*)(Ah + (tI << 9) + (lane << 3));
                const short8v avl = *(const short8v*)(Al + (tI << 9) + (lane << 3));
                #pragma unroll
                for (int ct = 0; ct < 2; ++ct) {
                    acc[rt][ct] = __builtin_amdgcn_mfma_f32_16x16x32_bf16(avh, bh[ct], acc[rt][ct], 0, 0, 0);
                    acc[rt][ct] = __builtin_amdgcn_mfma_f32_16x16x32_bf16(avh, bl[ct], acc[rt][ct], 0, 0, 0);
                    acc[rt][ct] = __builtin_amdgcn_mfma_f32_16x16x32_bf16(avl, bh[ct], acc[rt][ct], 0, 0, 0);
                }
            }
        }
        __syncthreads();
    }
    // ---- epilogue: C/D layout col=lane&15, row=(lane>>4)*4+reg ----
    #pragma unroll
    for (int rt = 0; rt < 4; ++rt) {
        const int rb = row0 + (wrow << 6) + (rt << 4) + ((lane >> 4) << 2);
        #pragma unroll
        for (int ct = 0; ct < 2; ++ct) {
            const int c = col0 + (wcol << 5) + (ct << 4) + (lane & 15);
            #pragma unroll
            for (int j = 0; j < 4; ++j) {
                const int r = rb + j;
                float v = acc[rt][ct][j];
                v += BIASB ? biasA[(size_t)(r / EE) * 256 + c] : biasA[c];
                if (RS) v += rowscale[r] * bias2[c];
                if (RELU) v = fmaxf(v, 0.f);
                out[(size_t)r * 256 + c] = v;
            }
        }
    }
}

template<int GATHER, int DUALW, int RELU, int RS, int BIASB>
__global__ __launch_bounds__(256, 2) void mgemm_k(
    const float* __restrict__ A1, const int* __restrict__ idx,
    const float* __restrict__ A2, float sA2,
    const short* __restrict__ W1h, const short* __restrict__ W1l,
    const short* __restrict__ W2h, const short* __restrict__ W2l,
    const float* __restrict__ biasA,
    const float* __restrict__ rowscale, const float* __restrict__ bias2,
    float* __restrict__ out)
{
    __shared__ short Ah[16 * 512];
    __shared__ short Al[16 * 512];
    mgemm_body<GATHER, DUALW, RELU, RS, BIASB>(A1, idx, A2, sA2, W1h, W1l, W2h, W2l,
        biasA, rowscale, bias2, out, blockIdx.y, blockIdx.x, Ah, Al);
}

// two plain GEMMs, one dispatch: by<nya -> job A, else job B
__global__ __launch_bounds__(256, 2) void mgemm_pair_k(
    const float* __restrict__ Aa, const short* __restrict__ Wah, const short* __restrict__ Wal,
    const float* __restrict__ ba, float* __restrict__ outa, int nya,
    const float* __restrict__ Ab, const short* __restrict__ Wbh, const short* __restrict__ Wbl,
    const float* __restrict__ bb, float* __restrict__ outb)
{
    __shared__ short Ah[16 * 512];
    __shared__ short Al[16 * 512];
    const int by = blockIdx.y;
    if (by < nya)
        mgemm_body<0, 0, 0, 0, 0>(Aa, nullptr, nullptr, 1.f, Wah, Wal, nullptr, nullptr,
            ba, nullptr, nullptr, outa, by, blockIdx.x, Ah, Al);
    else
        mgemm_body<0, 0, 0, 0, 0>(Ab, nullptr, nullptr, 1.f, Wbh, Wbl, nullptr, nullptr,
            bb, nullptr, nullptr, outb, by - nya, blockIdx.x, Ah, Al);
}

// ---------------------------------------------------------------------------
// weight pre-split: 17 matrices of 256x256 -> bf16 hi/lo
// order: rel(0) ent(1) head(2..4) tail(5..7) self(8..10) e2eA(11..13) e2eB(14..16)
// ---------------------------------------------------------------------------
__global__ void wpack_k(const float* __restrict__ relW, const float* __restrict__ entW,
                        const float* __restrict__ headW, const float* __restrict__ tailW,
                        const float* __restrict__ selfW, const float* __restrict__ e2eW,
                        short* __restrict__ wh, short* __restrict__ wl)
{
    int id = blockIdx.x * 256 + threadIdx.x;
    if (id >= 17 * 65536) return;
    int m = id >> 16, e = id & 65535;
    float x;
    if (m == 0)       x = relW[e];
    else if (m == 1)  x = entW[e];
    else if (m < 5)   x = headW[(size_t)(m - 2) * 65536 + e];
    else if (m < 8)   x = tailW[(size_t)(m - 5) * 65536 + e];
    else if (m < 11)  x = selfW[(size_t)(m - 8) * 65536 + e];
    else if (m < 14)  x = e2eW[(size_t)(m - 11) * 196608 + (size_t)(e >> 8) * 768 + (e & 255)];
    else              x = e2eW[(size_t)(m - 14) * 196608 + (size_t)(e >> 8) * 768 + 512 + (e & 255)];
    unsigned short h = f2bf_rne(x);
    wh[id] = (short)h;
    wl[id] = (short)f2bf_rne(x - bf2f(h));
}

// ---------------------------------------------------------------------------
// fp32 64x128 GEMM (kept only for the tiny Xg GEMM, N=1024)
// ---------------------------------------------------------------------------
template<int GATHER>
__global__ __launch_bounds__(256, 4) void gemm3_k(
    const float* __restrict__ A1, const int* __restrict__ idx,
    const float* __restrict__ W1, int ldw1,
    const float* __restrict__ biasA,
    float* __restrict__ out, int M, int N)
{
    __shared__ float As[16][68];
    __shared__ float Bs[16][132];
    const int tid = threadIdx.x;
    const int row0 = blockIdx.y * 64, col0 = blockIdx.x * 128;
    const int tx = tid & 15, ty = tid >> 4;
    const int srA = tid >> 2, skA = (tid & 3) << 2;
    const int srB = tid >> 1, skB = (tid & 1) << 3;
    const int grA = row0 + srA;
    const bool rvalid = (grA < M);
    const float* aRow1 = nullptr;
    if (rvalid) aRow1 = GATHER ? A1 + (size_t)idx[grA] * 256 : A1 + (size_t)grA * 256;
    const float* wR1 = W1 + (size_t)(col0 + srB) * ldw1;

    float acc[4][8];
    #pragma unroll
    for (int i = 0; i < 4; ++i)
        #pragma unroll
        for (int j = 0; j < 8; ++j) acc[i][j] = 0.f;

    float4 a0, b0, b1;
    auto fetch = [&](int ch) {
        const int k0 = ch << 4;
        if (rvalid) a0 = *(const float4*)(aRow1 + k0 + skA);
        else        a0 = make_float4(0.f, 0.f, 0.f, 0.f);
        b0 = *(const float4*)(wR1 + k0 + skB);
        b1 = *(const float4*)(wR1 + k0 + skB + 4);
    };

    fetch(0);
    for (int ch = 0; ch < 16; ++ch) {
        As[skA + 0][srA] = a0.x; As[skA + 1][srA] = a0.y;
        As[skA + 2][srA] = a0.z; As[skA + 3][srA] = a0.w;
        Bs[skB + 0][srB] = b0.x; Bs[skB + 1][srB] = b0.y;
        Bs[skB + 2][srB] = b0.z; Bs[skB + 3][srB] = b0.w;
        Bs[skB + 4][srB] = b1.x; Bs[skB + 5][srB] = b1.y;
        Bs[skB + 6][srB] = b1.z; Bs[skB + 7][srB] = b1.w;
        __syncthreads();
        if (ch + 1 < 16) fetch(ch + 1);
        #pragma unroll
        for (int kk = 0; kk < 16; ++kk) {
            float av[4], bv[8];
            *(float4*)&av[0] = *(const float4*)&As[kk][ty << 2];
            *(float4*)&bv[0] = *(const float4*)&Bs[kk][tx << 2];
            *(float4*)&bv[4] = *(const float4*)&Bs[kk][(tx << 2) + 64];
            #pragma unroll
            for (int i = 0; i < 4; ++i)
                #pragma unroll
                for (int j = 0; j < 8; ++j) acc[i][j] += av[i] * bv[j];
        }
        __syncthreads();
    }
    #pragma unroll
    for (int i = 0; i < 4; ++i) {
        int r = row0 + (ty << 2) + i;
        if (r >= M) continue;
        float* orow = out + (size_t)r * N;
        #pragma unroll
        for (int jh = 0; jh < 2; ++jh) {
            const int c = col0 + (jh << 6) + (tx << 2);
            float4 v;
            v.x = acc[i][jh * 4 + 0] + biasA[c + 0];
            v.y = acc[i][jh * 4 + 1] + biasA[c + 1];
            v.z = acc[i][jh * 4 + 2] + biasA[c + 2];
            v.w = acc[i][jh * 4 + 3] + biasA[c + 3];
            *(float4*)(orow + c) = v;
        }
    }
}

// ---------------------------------------------------------------------------
// CSR build
// ---------------------------------------------------------------------------
__global__ void csr_count_k(const int* __restrict__ idx, int* __restrict__ cnt, int nrPerB)
{
    int k = blockIdx.x * 256 + threadIdx.x;
    if (k >= NNZ_) return;
    atomicAdd(&cnt[idx[k] * nrPerB + idx[NNZ_ + k]], 1);
}

__global__ __launch_bounds__(1024) void scan2_k(
    const int* __restrict__ cntA, int* __restrict__ rpA, int* __restrict__ curA, int nA,
    const int* __restrict__ cntB, int* __restrict__ rpB, int* __restrict__ curB, int nB)
{
    const int* cnt = blockIdx.x ? cntB : cntA;
    int* rp  = blockIdx.x ? rpB  : rpA;
    int* cur = blockIdx.x ? curB : curA;
    int n    = blockIdx.x ? nB   : nA;
    __shared__ int sums[1024];
    int t = threadIdx.x;
    int chunk = (n + 1023) / 1024;
    int lo = t * chunk, hi = lo + chunk;
    if (lo > n) lo = n;
    if (hi > n) hi = n;
    int s = 0;
    for (int i = lo; i < hi; ++i) s += cnt[i];
    sums[t] = s;
    __syncthreads();
    for (int off = 1; off < 1024; off <<= 1) {
        int v = (t >= off) ? sums[t - off] : 0;
        __syncthreads();
        sums[t] += v;
        __syncthreads();
    }
    int run = (t == 0) ? 0 : sums[t - 1];
    for (int i = lo; i < hi; ++i) { rp[i] = run; cur[i] = run; run += cnt[i]; }
    if (hi == n) rp[n] = run;
}

__global__ void csr_fill_k(const int* __restrict__ idx, const float* __restrict__ val,
                           int* __restrict__ cur, int* __restrict__ col,
                           float* __restrict__ valp, int nrPerB)
{
    int k = blockIdx.x * 256 + threadIdx.x;
    if (k >= NNZ_) return;
    int row = idx[k] * nrPerB + idx[NNZ_ + k];
    int p = atomicAdd(&cur[row], 1);
    col[p] = idx[2 * NNZ_ + k];
    valp[p] = val[k];
}

__global__ void degw_k(const int* __restrict__ rp, const float* __restrict__ vp,
                       float* __restrict__ degw, int n)
{
    int r = blockIdx.x * 256 + threadIdx.x;
    if (r >= n) return;
    float s = 0.f;
    for (int j = rp[r]; j < rp[r + 1]; ++j) s += vp[j];
    degw[r] = s;
}

// ---------------------------------------------------------------------------
// fused e2f gather
// ---------------------------------------------------------------------------
__global__ __launch_bounds__(256) void gather_fused_e2f_k(
    const int* __restrict__ rowptr, const int* __restrict__ col,
    const float* __restrict__ valp, const float* __restrict__ headsrc,
    const float* __restrict__ pr, const float* __restrict__ sm,
    const float* __restrict__ Wtil, float* __restrict__ e2fnrm,
    float* __restrict__ dst, int nrows)
{
    int gid = blockIdx.x * 256 + threadIdx.x;
    int row = gid >> 6, lane = gid & 63;
    if (row >= nrows) return;
    int b = row / FF;
    const float* prb = pr + (size_t)b * EE;
    const float* smb = sm + (size_t)b * EE;
    float4* dp = (float4*)(dst + (size_t)row * DD + (lane << 2));
    float4 acc = *dp;
    float ns = 0.f;
    int j0 = rowptr[row], j1 = rowptr[row + 1];
    for (int j = j0; j < j1; ++j) {
        int c = col[j];
        float v = valp[j];
        float4 x = *(const float4*)(headsrc + ((size_t)b * EE + c) * DD + (lane << 2));
        acc.x += v * x.x; acc.y += v * x.y; acc.z += v * x.z; acc.w += v * x.w;
        ns += v * (prb[c] / fmaxf(smb[c], VSMALL));
    }
    float nrm = Wtil[row] * ns;
    if (lane == 0) e2fnrm[row] = nrm;
    acc.x = fmaxf(acc.x, 0.f) * nrm; acc.y = fmaxf(acc.y, 0.f) * nrm;
    acc.z = fmaxf(acc.z, 0.f) * nrm; acc.w = fmaxf(acc.w, 0.f) * nrm;
    *dp = acc;
}

__global__ __launch_bounds__(256) void gather_sum_k(
    const int* __restrict__ rowptr, const int* __restrict__ col,
    const float* __restrict__ valp, const float* __restrict__ src,
    float* __restrict__ dst, int nrows, int nrPerB, int ncs)
{
    int gid = blockIdx.x * 256 + threadIdx.x;
    int row = gid >> 6, lane = gid & 63;
    if (row >= nrows) return;
    int b = row / nrPerB;
    float4 acc = make_float4(0.f, 0.f, 0.f, 0.f);
    int j0 = rowptr[row], j1 = rowptr[row + 1];
    for (int j = j0; j < j1; ++j) {
        int c = col[j];
        float v = valp[j];
        float4 x = *(const float4*)(src + ((size_t)b * ncs + c) * DD + (lane << 2));
        acc.x += v * x.x; acc.y += v * x.y; acc.z += v * x.z; acc.w += v * x.w;
    }
    *(float4*)(dst + (size_t)row * DD + (lane << 2)) = acc;
}

// ---------------------------------------------------------------------------
// LSTM
// ---------------------------------------------------------------------------
__global__ void transpose_whh_k(const float* __restrict__ Whh, float* __restrict__ WhhT)
{
    int i = blockIdx.x * 256 + threadIdx.x;
    int k = i >> 10, j = i & 1023;
    WhhT[i] = Whh[(size_t)j * 256 + k];
}

__global__ __launch_bounds__(256) void lstm_k(
    const float* __restrict__ Xg, const float* __restrict__ WhhT,
    const float* __restrict__ bhh, float* __restrict__ qh, float* __restrict__ qne)
{
    __shared__ float h[DD];
    __shared__ float gs[4 * DD];
    const int b = blockIdx.x, t = threadIdx.x;
    h[t] = 0.f;
    float c = 0.f;
    const float4 bb4 = *(const float4*)(bhh + 4 * t);
    const float4* wt4 = (const float4*)WhhT + t;
    __syncthreads();
    for (int step = 0; step < QQ; ++step) {
        float a0 = 0.f, a1 = 0.f, a2 = 0.f, a3 = 0.f;
        #pragma unroll 16
        for (int k = 0; k < DD; ++k) {
            float4 w = wt4[k * 256];
            float hk = h[k];
            a0 += w.x * hk; a1 += w.y * hk; a2 += w.z * hk; a3 += w.w * hk;
        }
        float4 xg = *(const float4*)(Xg + ((size_t)b * QQ + step) * 1024 + 4 * t);
        float4 g4 = make_float4(a0 + xg.x + bb4.x, a1 + xg.y + bb4.y,
                                a2 + xg.z + bb4.z, a3 + xg.w + bb4.w);
        *(float4*)(gs + 4 * t) = g4;
        __syncthreads();
        float gi = gs[t], gf = gs[DD + t], gg = gs[2 * DD + t], go = gs[3 * DD + t];
        float si = 1.f / (1.f + expf(-gi));
        float sf = 1.f / (1.f + expf(-gf));
        float so = 1.f / (1.f + expf(-go));
        c = sf * c + si * tanhf(gg);
        float hh = so * tanhf(c);
        h[t] = hh;
        qh[((size_t)b * QQ + step) * DD + t] = hh;
        __syncthreads();
    }
    qne[(size_t)b * DD + t] = h[t];
}

// ---------------------------------------------------------------------------
// sim -> softmax -> Wt
// ---------------------------------------------------------------------------
__global__ __launch_bounds__(256) void simwt_k(
    const float* __restrict__ qhid, const int* __restrict__ qtext,
    const float* __restrict__ lfe, float* __restrict__ Wt)
{
    __shared__ float qs[QQ * DD];
    __shared__ float qmn[QQ];
    const int b = blockIdx.y;
    const int f = blockIdx.x * 256 + threadIdx.x;
    for (int i = threadIdx.x; i < QQ * DD; i += 256) qs[i] = qhid[(size_t)b * QQ * DD + i];
    if (threadIdx.x < QQ)
        qmn[threadIdx.x] = (qtext[b * QQ + threadIdx.x] != NWORD) ? 0.f : VNEG;
    __syncthreads();
    if (f >= FF) return;
    float acc[QQ];
    #pragma unroll
    for (int q = 0; q < QQ; ++q) acc[q] = 0.f;
    const float* lr = lfe + ((size_t)b * FF + f) * DD;
    for (int d = 0; d < DD; d += 4) {
        float4 x = *(const float4*)(lr + d);
        #pragma unroll
        for (int q = 0; q < QQ; ++q) {
            float4 y = *(const float4*)&qs[q * DD + d];
            acc[q] += x.x * y.x + x.y * y.y + x.z * y.z + x.w * y.w;
        }
    }
    const float inv = 0.0625f;
    float pre[QQ], m = -INFINITY;
    #pragma unroll
    for (int q = 0; q < QQ; ++q) { pre[q] = acc[q] * inv + qmn[q]; m = fmaxf(m, pre[q]); }
    float s = 0.f;
    #pragma unroll
    for (int q = 0; q < QQ; ++q) s += expf(pre[q] - m);
    float wt = 0.f;
    #pragma unroll
    for (int q = 0; q < QQ; ++q) wt += (expf(pre[q] - m) / s) * (acc[q] * inv);
    Wt[(size_t)b * FF + f] = wt;
}

__global__ void rowmax_k(const float* __restrict__ Wt, float* __restrict__ WtMax)
{
    __shared__ float red[256];
    int b = blockIdx.x;
    float m = -INFINITY;
    for (int f = threadIdx.x; f < FF; f += 256) m = fmaxf(m, Wt[b * FF + f]);
    red[threadIdx.x] = m; __syncthreads();
    for (int s = 128; s > 0; s >>= 1) {
        if (threadIdx.x < s) red[threadIdx.x] = fmaxf(red[threadIdx.x], red[threadIdx.x + s]);
        __syncthreads();
    }
    if (threadIdx.x == 0) WtMax[b] = red[0];
}

__global__ void wtil_k(const float* __restrict__ Wt, const float* __restrict__ WtMax,
                       float* __restrict__ Wtil)
{
    int i = blockIdx.x * 256 + threadIdx.x;
    if (i >= BB * FF) return;
    Wtil[i] = expf(Wt[i] - WtMax[i / FF]);
}

__global__ void scatter_sm_k(const int* __restrict__ idx, const float* __restrict__ val,
                             const float* __restrict__ Wtil, float* __restrict__ dst)
{
    int k = blockIdx.x * 256 + threadIdx.x;
    if (k >= NNZ_) return;
    int b = idx[k], e = idx[2 * NNZ_ + k], f = idx[NNZ_ + k];
    atomicAdd(&dst[(size_t)b * EE + e], val[k] * Wtil[(size_t)b * FF + f]);
}

// ---------------------------------------------------------------------------
// initial qlin + ebias
// ---------------------------------------------------------------------------
__global__ __launch_bounds__(256) void qlin_ebias_k(
    const float* __restrict__ qne, const float* __restrict__ q2eW,
    const float* __restrict__ q2eb, const float* __restrict__ e2eW,
    const float* __restrict__ e2eb, float* __restrict__ qlin, float* __restrict__ ebias)
{
    __shared__ float xs[DD], qs[DD];
    int b = blockIdx.x, j = threadIdx.x;
    xs[j] = qne[b * DD + j];
    __syncthreads();
    float acc = q2eb[j];
    const float* wr = q2eW + (size_t)j * DD;
    #pragma unroll 4
    for (int k = 0; k < DD; ++k) acc += xs[k] * wr[k];
    qlin[b * DD + j] = acc;
    qs[j] = acc;
    __syncthreads();
    float acc2 = e2eb[j];
    const float* wr2 = e2eW + (size_t)j * 768 + 256;
    #pragma unroll 4
    for (int k = 0; k < DD; ++k) acc2 += qs[k] * wr2[k];
    ebias[b * DD + j] = acc2;
}

// ---------------------------------------------------------------------------
// fused pagerank update + vreduce partials
// ---------------------------------------------------------------------------
#define VCH 80
#define NCHK (EE / VCH)   // 25
__global__ __launch_bounds__(256) void vreduce_pr_k(
    const int* __restrict__ f2e_rp, const int* __restrict__ f2e_col,
    const float* __restrict__ f2e_vp, const float* __restrict__ e2fnrm,
    float* __restrict__ pr, const float* __restrict__ lee,
    const float* __restrict__ f2e, float* __restrict__ vpartL,
    float* __restrict__ vpartF, float* __restrict__ vpartS)
{
    int b = blockIdx.y, ch = blockIdx.x, k = threadIdx.x;
    int e0 = ch * VCH;
    __shared__ float prs[VCH];
    if (k < VCH) {
        int row = b * EE + e0 + k;
        float s = 0.f;
        for (int j = f2e_rp[row]; j < f2e_rp[row + 1]; ++j)
            s += f2e_vp[j] * e2fnrm[(size_t)b * FF + f2e_col[j]];
        float v = 0.8f * s + 0.2f * pr[row];
        pr[row] = v;
        prs[k] = v;
    }
    __syncthreads();
    float a1 = 0.f, a2 = 0.f;
    for (int e = 0; e < VCH; ++e) {
        float p = prs[e];
        size_t base = ((size_t)b * EE + e0 + e) * DD + k;
        a1 += p * lee[base];
        a2 += p * f2e[base];
    }
    int pi = ch * BB + b;
    vpartL[(size_t)pi * DD + k] = a1;
    vpartF[(size_t)pi * DD + k] = a2;
    float sp = 0.f;
    for (int e = k; e < VCH; e += 256) sp += prs[e];
    __shared__ float red[256];
    red[k] = sp; __syncthreads();
    for (int s = 128; s > 0; s >>= 1) {
        if (k < s) red[k] += red[k + s];
        __syncthreads();
    }
    if (k == 0) vpartS[pi] = red[0];
}

// ---------------------------------------------------------------------------
// qne update + next layer's qlin/ebias
// ---------------------------------------------------------------------------
__global__ __launch_bounds__(256) void qneupd_qlin_k(
    const float* __restrict__ vpartL, const float* __restrict__ vpartF,
    const float* __restrict__ vpartS, const float* __restrict__ qlinCur,
    const float* __restrict__ W, const float* __restrict__ bias,
    float* __restrict__ qne,
    const float* __restrict__ q2eWn, const float* __restrict__ q2ebn,
    const float* __restrict__ e2eWn, const float* __restrict__ e2ebn,
    float* __restrict__ qlinNext, float* __restrict__ ebiasNext, int hasNext)
{
    __shared__ float s1[DD], s2[DD], s3[DD], qn[DD], qs[DD];
    int b = blockIdx.x, j = threadIdx.x;
    float a1 = 0.f, a3 = 0.f, sp = 0.f;
    for (int ch = 0; ch < NCHK; ++ch) {
        int pi = ch * BB + b;
        a1 += vpartL[(size_t)pi * DD + j];
        a3 += vpartF[(size_t)pi * DD + j];
        sp += vpartS[pi];
    }
    s1[j] = a1; s2[j] = qlinCur[b * DD + j]; s3[j] = a3;
    __syncthreads();
    float acc = sp * bias[j];
    const float* wr = W + (size_t)j * 768;
    #pragma unroll 4
    for (int k = 0; k < DD; ++k)
        acc += s1[k] * wr[k] + sp * s2[k] * wr[256 + k] + 3.f * s3[k] * wr[512 + k];
    qne[b * DD + j] = acc;
    if (!hasNext) return;
    qn[j] = acc;
    __syncthreads();
    float aq = q2ebn[j];
    const float* wq = q2eWn + (size_t)j * DD;
    #pragma unroll 4
    for (int k = 0; k < DD; ++k) aq += qn[k] * wq[k];
    qlinNext[b * DD + j] = aq;
    qs[j] = aq;
    __syncthreads();
    float ae = e2ebn[j];
    const float* we = e2eWn + (size_t)j * 768 + 256;
    #pragma unroll 4
    for (int k = 0; k < DD; ++k) ae += qs[k] * we[k];
    ebiasNext[b * DD + j] = ae;
}

// ---------------------------------------------------------------------------
// epilogue
// ---------------------------------------------------------------------------
__global__ void score_k(const float* __restrict__ lee, const float* __restrict__ sw,
                        const float* __restrict__ sb, float* __restrict__ score)
{
    int r = blockIdx.x * 256 + threadIdx.x;
    if (r >= BB * EE) return;
    float acc = sb[0];
    const float* a = lee + (size_t)r * DD;
    for (int k = 0; k < DD; k += 4) {
        float4 v = *(const float4*)(a + k);
        acc += v.x * sw[k] + v.y * sw[k + 1] + v.z * sw[k + 2] + v.w * sw[k + 3];
    }
    score[r] = acc;
}

__global__ __launch_bounds__(256) void final_k(
    const float* __restrict__ score, const int* __restrict__ local_entity,
    const float* __restrict__ ans, float* __restrict__ out, float* __restrict__ losspart)
{
    int b = blockIdx.x, t = threadIdx.x;
    float lsum = 0.f, bm = -INFINITY;
    int bi = EE;
    for (int e = t; e < EE; e += 256) {
        float s = score[b * EE + e];
        float mask = (local_entity[b * EE + e] != NENT) ? 1.f : 0.f;
        float smv = s + (1.f - mask) * VNEG;
        float sig;
        if (smv >= 0.f) sig = 1.f / (1.f + expf(-smv));
        else { float es = expf(smv); sig = es / (1.f + es); }
        out[1 + BB + b * EE + e] = sig * mask;
        lsum += fmaxf(s, 0.f) - s * ans[b * EE + e] + log1pf(expf(-fabsf(s)));
        if (smv > bm) { bm = smv; bi = e; }
    }
    __shared__ float rv[256]; __shared__ int ri[256]; __shared__ float rl[256];
    rv[t] = bm; ri[t] = bi; rl[t] = lsum;
    __syncthreads();
    for (int s = 128; s > 0; s >>= 1) {
        if (t < s) {
            rl[t] += rl[t + s];
            if (rv[t + s] > rv[t] || (rv[t + s] == rv[t] && ri[t + s] < ri[t])) {
                rv[t] = rv[t + s]; ri[t] = ri[t + s];
            }
        }
        __syncthreads();
    }
    if (t == 0) { losspart[b] = rl[0]; out[1 + b] = (float)ri[0]; }
}

__global__ void loss_k(const float* __restrict__ losspart, float* __restrict__ out)
{
    if (threadIdx.x == 0) {
        float s = 0.f;
        for (int b = 0; b < BB; ++b) s += losspart[b];
        out[0] = s / (float)(BB * EE);
    }
}

// ---------------------------------------------------------------------------
extern "C" void kernel_launch(void* const* d_in, const int* in_sizes, int n_in,
                              void* d_out, int out_size, void* d_ws, size_t ws_size,
                              hipStream_t stream)
{
    (void)in_sizes; (void)n_in; (void)out_size; (void)ws_size;
    const int*   local_entity = (const int*)d_in[0];
    const float* q2e_adj      = (const float*)d_in[1];
    const int*   kb_fact_rel  = (const int*)d_in[2];
    const int*   query_text   = (const int*)d_in[3];
    const float* answer_dist  = (const float*)d_in[4];
    const int*   e2f_idx      = (const int*)d_in[5];
    const float* e2f_val      = (const float*)d_in[6];
    const int*   f2e_idx      = (const int*)d_in[7];
    const float* f2e_val      = (const float*)d_in[8];
    const float* entity_table = (const float*)d_in[9];
    const float* ent_W        = (const float*)d_in[10];
    const float* ent_b        = (const float*)d_in[11];
    const float* rel_table    = (const float*)d_in[12];
    const float* rel_W        = (const float*)d_in[13];
    const float* rel_b        = (const float*)d_in[14];
    const float* word_table   = (const float*)d_in[15];
    const float* Wih          = (const float*)d_in[16];
    const float* Whh          = (const float*)d_in[17];
    const float* bih          = (const float*)d_in[18];
    const float* bhh          = (const float*)d_in[19];
    const float* q2e_W        = (const float*)d_in[20];
    const float* q2e_b        = (const float*)d_in[21];
    const float* e2q_W        = (const float*)d_in[22];
    const float* e2q_b        = (const float*)d_in[23];
    const float* e2e_W        = (const float*)d_in[24];
    const float* e2e_b        = (const float*)d_in[25];
    const float* head_W       = (const float*)d_in[26];
    const float* head_b       = (const float*)d_in[27];
    const float* tail_W       = (const float*)d_in[28];
    const float* tail_b       = (const float*)d_in[29];
    const float* self_W       = (const float*)d_in[30];
    const float* self_b       = (const float*)d_in[31];
    const float* score_W      = (const float*)d_in[32];
    const float* score_b      = (const float*)d_in[33];

    const int NR1 = BB * FF;   // 48000
    const int NR2 = BB * EE;   // 16000

    float* ws = (float*)d_ws;
    size_t off = 0;
    auto alloc = [&](size_t n) { float* p = ws + off; off += n; return p; };
    float* Xg      = alloc((size_t)BB * QQ * 1024);
    float* WhhT    = alloc((size_t)1024 * DD);
    float* qh      = alloc((size_t)BB * QQ * DD);
    float* qne     = alloc(BB * DD);
    float* lfe     = alloc((size_t)NR1 * DD);
    float* lee     = alloc((size_t)NR2 * DD);
    float* lee2    = alloc((size_t)NR2 * DD);
    float* Wt      = alloc(BB * FF);
    float* WtMax   = alloc(8);
    float* Wtil    = alloc(BB * FF);
    float* e2fsm   = alloc(BB * EE);
    float* pr      = alloc(BB * EE);
    float* qlinA   = alloc(BB * DD);
    float* qlinB   = alloc(BB * DD);
    float* ebiasA  = alloc(BB * DD);
    float* ebiasB  = alloc(BB * DD);
    float* e2fnrm  = alloc(BB * FF);
    float* scoreb  = alloc(BB * EE);
    float* losspart= alloc(8);
    float* bufC    = alloc((size_t)NR2 * DD);
    float* e2fT    = alloc((size_t)NR1 * DD);
    float* f2eT    = alloc((size_t)NR2 * DD);
    float* tmp     = alloc((size_t)NR2 * DD);
    float* vpartL  = alloc((size_t)NCHK * BB * DD);
    float* vpartF  = alloc((size_t)NCHK * BB * DD);
    float* vpartS  = alloc(NCHK * BB);
    float* degw2   = alloc(NR2);
    float* e2f_vp  = alloc(NNZ_);
    float* f2e_vp  = alloc(NNZ_);
    short* wbh = (short*)alloc(17 * 65536 / 2);
    short* wbl = (short*)alloc(17 * 65536 / 2);
    int* ib = (int*)(ws + off);
    size_t ioff = 0;
    auto ialloc = [&](size_t n) { int* p = ib + ioff; ioff += n; return p; };
    int* e2f_cnt = ialloc(NR1);
    int* e2f_rp  = ialloc(NR1 + 1);
    int* e2f_cur = ialloc(NR1);
    int* e2f_col = ialloc(NNZ_);
    int* f2e_cnt = ialloc(NR2);
    int* f2e_rp  = ialloc(NR2 + 1);
    int* f2e_cur = ialloc(NR2);
    int* f2e_col = ialloc(NNZ_);

    // weight matrix slots in the packed buffers
    auto WH = [&](int m) { return wbh + (size_t)m * 65536; };
    auto WL = [&](int m) { return wbl + (size_t)m * 65536; };
    // 0 rel, 1 ent, 2+i head, 5+i tail, 8+i self, 11+i e2eA, 14+i e2eB

    float* outp = (float*)d_out;
    const int SCB = (NNZ_ + 255) / 256;

    // ---- weight pre-split ----
    wpack_k<<<(17 * 65536) / 256, 256, 0, stream>>>(rel_W, ent_W, head_W, tail_W,
                                                    self_W, e2e_W, wbh, wbl);

    // ---- CSR builds ----
    hipMemsetAsync(e2f_cnt, 0, NR1 * sizeof(int), stream);
    hipMemsetAsync(f2e_cnt, 0, NR2 * sizeof(int), stream);
    csr_count_k<<<SCB, 256, 0, stream>>>(e2f_idx, e2f_cnt, FF);
    csr_count_k<<<SCB, 256, 0, stream>>>(f2e_idx, f2e_cnt, EE);
    scan2_k<<<2, 1024, 0, stream>>>(e2f_cnt, e2f_rp, e2f_cur, NR1,
                                    f2e_cnt, f2e_rp, f2e_cur, NR2);
    csr_fill_k<<<SCB, 256, 0, stream>>>(e2f_idx, e2f_val, e2f_cur, e2f_col, e2f_vp, FF);
    csr_fill_k<<<SCB, 256, 0, stream>>>(f2e_idx, f2e_val, f2e_cur, f2e_col, f2e_vp, EE);
    degw_k<<<(NR2 + 255) / 256, 256, 0, stream>>>(f2e_rp, f2e_vp, degw2, NR2);

    // ---- LSTM ----
    gemm3_k<1><<<dim3(8, 3), 256, 0, stream>>>(
        word_table, query_text, Wih, 256, bih, Xg, BB * QQ, 1024);
    transpose_whh_k<<<1024, 256, 0, stream>>>(Whh, WhhT);
    lstm_k<<<BB, 256, 0, stream>>>(Xg, WhhT, bhh, qh, qne);

    // ---- embeddings (MFMA split-bf16) ----
    mgemm_k<1, 0, 0, 0, 0><<<dim3(4, 375), 256, 0, stream>>>(
        rel_table, kb_fact_rel, nullptr, 1.f, WH(0), WL(0), nullptr, nullptr,
        rel_b, nullptr, nullptr, lfe);
    mgemm_k<1, 0, 0, 0, 0><<<dim3(4, 125), 256, 0, stream>>>(
        entity_table, local_entity, nullptr, 1.f, WH(1), WL(1), nullptr, nullptr,
        ent_b, nullptr, nullptr, lee);

    // ---- attention -> W_tilde ----
    simwt_k<<<dim3((FF + 255) / 256, BB), 256, 0, stream>>>(qh, query_text, lfe, Wt);
    rowmax_k<<<BB, 256, 0, stream>>>(Wt, WtMax);
    wtil_k<<<(BB * FF + 255) / 256, 256, 0, stream>>>(Wt, WtMax, Wtil);

    // ---- e2f_softmax ----
    hipMemsetAsync(e2fsm, 0, BB * EE * sizeof(float), stream);
    scatter_sm_k<<<SCB, 256, 0, stream>>>(e2f_idx, e2f_val, Wtil, e2fsm);

    // ---- pagerank init + initial qlin/ebias ----
    hipMemcpyAsync(pr, q2e_adj, BB * EE * sizeof(float), hipMemcpyDeviceToDevice, stream);
    qlin_ebias_k<<<BB, 256, 0, stream>>>(qne, q2e_W, q2e_b, e2e_W, e2e_b, qlinA, ebiasA);

    float* qlinCur = qlinA;  float* qlinNxt = qlinB;
    float* ebiasCur = ebiasA; float* ebiasNxt = ebiasB;

    for (int i = 0; i < 3; ++i) {
        const float* e2qWi  = e2q_W  + (size_t)i * DD * 3 * DD;
        const float* e2qbi  = e2q_b  + i * DD;
        const float* headbi = head_b + i * DD;
        const float* tailbi = tail_b + i * DD;
        const float* selfbi = self_b + i * DD;

        // head(lee) -> bufC  AND  self(lfe) -> e2fT, one MFMA dispatch
        mgemm_pair_k<<<dim3(4, 125 + 375), 256, 0, stream>>>(
            lee, WH(2 + i), WL(2 + i), headbi, bufC, 125,
            lfe, WH(8 + i), WL(8 + i), selfbi, e2fT);

        // e2fT = relu(e2fT + gather_e2f(bufC)) * nrm ; e2fnrm written
        gather_fused_e2f_k<<<(NR1 * 64) / 256, 256, 0, stream>>>(
            e2f_rp, e2f_col, e2f_vp, bufC, pr, e2fsm, Wtil, e2fnrm, e2fT, NR1);

        // tmp = gather_f2e(e2fT)
        gather_sum_k<<<(NR2 * 64) / 256, 256, 0, stream>>>(
            f2e_rp, f2e_col, f2e_vp, e2fT, tmp, NR2, EE, FF);

        // f2eT = relu(lee@selfW^T + tmp@tailW^T + selfb + degw*tailb)
        mgemm_k<0, 1, 1, 1, 0><<<dim3(4, 125), 256, 0, stream>>>(
            lee, nullptr, tmp, 1.f, WH(8 + i), WL(8 + i), WH(5 + i), WL(5 + i),
            selfbi, degw2, tailbi, f2eT);

        // pagerank update + vreduce partials (fused)
        vreduce_pr_k<<<dim3(NCHK, BB), 256, 0, stream>>>(
            f2e_rp, f2e_col, f2e_vp, e2fnrm, pr, lee, f2eT, vpartL, vpartF, vpartS);

        // qne update + next layer's qlin/ebias
        int hasNext = (i < 2) ? 1 : 0;
        const float* q2eWn = q2e_W + (size_t)(i + 1) * DD * DD * (hasNext ? 1 : 0);
        const float* q2ebn = q2e_b + (i + 1) * DD * (hasNext ? 1 : 0);
        const float* e2eWn = e2e_W + (size_t)(i + 1) * DD * 3 * DD * (hasNext ? 1 : 0);
        const float* e2ebn = e2e_b + (i + 1) * DD * (hasNext ? 1 : 0);
        qneupd_qlin_k<<<BB, 256, 0, stream>>>(
            vpartL, vpartF, vpartS, qlinCur, e2qWi, e2qbi, qne,
            q2eWn, q2ebn, e2eWn, e2ebn, qlinNxt, ebiasNxt, hasNext);

        // lee2 = relu(lee@e2eA^T + 3*f2eT@e2eB^T + ebias[b])
        mgemm_k<0, 1, 1, 0, 1><<<dim3(4, 125), 256, 0, stream>>>(
            lee, nullptr, f2eT, 3.f, WH(11 + i), WL(11 + i), WH(14 + i), WL(14 + i),
            ebiasCur, nullptr, nullptr, lee2);
        { float* t = lee; lee = lee2; lee2 = t; }
        { float* t = qlinCur; qlinCur = qlinNxt; qlinNxt = t; }
        { float* t = ebiasCur; ebiasCur = ebiasNxt; ebiasNxt = t; }
    }

    score_k<<<(BB * EE + 255) / 256, 256, 0, stream>>>(lee, score_W, score_b, scoreb);
    final_k<<<BB, 256, 0, stream>>>(scoreb, local_entity, answer_dist, outp, losspart);
    loss_k<<<1, 64, 0, stream>>>(losspart, outp);
}